// Round 1
// baseline (4856.367 us; speedup 1.0000x reference)
//
#include <hip/hip_runtime.h>
#include <hip/hip_bf16.h>

#define Bb 16
#define Ll 512
#define NV 512
#define DM 512
#define DS 16
#define NLAY 2
#define DFF 2048
#define DI 1024
#define DCONV 4
#define DTR 32
#define Hh 96
#define Ss NV
#define MROWS (Bb*Ss)
#define EPSf 1e-5f

// ---------------- RevIN stats ----------------
__global__ void revin_stats(const float* __restrict__ x, float* __restrict__ mu, float* __restrict__ sd) {
    int b = blockIdx.x, n = threadIdx.x;
    const float* xp = x + (size_t)b * Ll * NV + n;
    float s1 = 0.f, s2 = 0.f;
    for (int l = 0; l < Ll; l++) { float v = xp[(size_t)l * NV]; s1 += v; s2 += v * v; }
    float m = s1 / Ll;
    float var = s2 / Ll - m * m;
    mu[b * NV + n] = m;
    sd[b * NV + n] = sqrtf(var + EPSf);
}

// ------------- normalize + transpose: xnT[b,n,l] = (x[b,l,n]-mu)/sd -------------
__global__ void transpose_norm(const float* __restrict__ x, const float* __restrict__ mu,
                               const float* __restrict__ sd, float* __restrict__ xnT) {
    __shared__ float t[32][33];
    int b = blockIdx.z;
    int l0 = blockIdx.x * 32, n0 = blockIdx.y * 32;
    int tx = threadIdx.x, ty = threadIdx.y; // 32x8
    #pragma unroll
    for (int q = 0; q < 4; q++)
        t[ty + q * 8][tx] = x[(size_t)b * Ll * NV + (size_t)(l0 + ty + q * 8) * NV + n0 + tx];
    __syncthreads();
    #pragma unroll
    for (int q = 0; q < 4; q++) {
        int n = n0 + ty + q * 8;
        float m = mu[b * NV + n], s = sd[b * NV + n];
        xnT[(size_t)b * NV * Ll + (size_t)n * Ll + l0 + tx] = (t[tx][ty + q * 8] - m) / s;
    }
}

// ---------------- LayerNorm over rows of DM ----------------
__global__ void ln_rows(const float* __restrict__ in, const float* __restrict__ w,
                        const float* __restrict__ bvec, float* __restrict__ out) {
    int row = blockIdx.x;
    int tid = threadIdx.x;
    float v = in[(size_t)row * DM + tid];
    float s1 = v, s2 = v * v;
    #pragma unroll
    for (int o = 32; o > 0; o >>= 1) { s1 += __shfl_down(s1, o, 64); s2 += __shfl_down(s2, o, 64); }
    __shared__ float l1[8], l2[8];
    int wv = tid >> 6, ln = tid & 63;
    if (ln == 0) { l1[wv] = s1; l2[wv] = s2; }
    __syncthreads();
    if (tid == 0) {
        float a = 0.f, c = 0.f;
        #pragma unroll
        for (int i = 0; i < DM / 64; i++) { a += l1[i]; c += l2[i]; }
        l1[0] = a; l2[0] = c;
    }
    __syncthreads();
    float mean = l1[0] / DM;
    float var = l2[0] / DM - mean * mean;
    float inv = rsqrtf(var + EPSf);
    out[(size_t)row * DM + tid] = (v - mean) * inv * w[tid] + bvec[tid];
}

// ---------------- GEMM: C = A(M,K;lda) @ W(N,K)^T + bias, epilogues ----------------
// EPI: 0=none 1=gelu(tanh) 2=softplus ; ACC: C += r ; REVA/REVC: row reversal within S
template<int EPI, bool ACC, bool REVA, bool REVC>
__global__ __launch_bounds__(256) void gemm_awt(
    const float* __restrict__ A, int lda,
    const float* __restrict__ W,
    const float* __restrict__ bias,
    float* __restrict__ C, int ldc,
    int M, int Nn, int K) {
    __shared__ float As[16][68];
    __shared__ float Ws[16][68];
    int m0 = blockIdx.x * 64;
    int n0 = blockIdx.y * 64;
    int tid = threadIdx.x;
    int tm = (tid / 16) * 4, tn = (tid % 16) * 4;
    float acc[4][4] = {};
    int lr = tid / 4;        // 0..63
    int lk = (tid % 4) * 4;  // 0,4,8,12
    int arow = m0 + lr;
    if (REVA) arow = (arow & ~(Ss - 1)) | ((Ss - 1) - (arow & (Ss - 1)));
    const float* aptr = A + (size_t)arow * lda + lk;
    int wrow = n0 + lr;
    bool wok = wrow < Nn;
    const float* wptr = W + (size_t)wrow * K + lk;
    for (int k0 = 0; k0 < K; k0 += 16) {
        float4 av = *(const float4*)(aptr + k0);
        float4 wv = wok ? *(const float4*)(wptr + k0) : make_float4(0.f, 0.f, 0.f, 0.f);
        As[lk + 0][lr] = av.x; As[lk + 1][lr] = av.y; As[lk + 2][lr] = av.z; As[lk + 3][lr] = av.w;
        Ws[lk + 0][lr] = wv.x; Ws[lk + 1][lr] = wv.y; Ws[lk + 2][lr] = wv.z; Ws[lk + 3][lr] = wv.w;
        __syncthreads();
        #pragma unroll
        for (int kk = 0; kk < 16; kk++) {
            float4 a = *(const float4*)&As[kk][tm];
            float4 w = *(const float4*)&Ws[kk][tn];
            float ar[4] = {a.x, a.y, a.z, a.w};
            float wr[4] = {w.x, w.y, w.z, w.w};
            #pragma unroll
            for (int i = 0; i < 4; i++)
                #pragma unroll
                for (int j = 0; j < 4; j++)
                    acc[i][j] = fmaf(ar[i], wr[j], acc[i][j]);
        }
        __syncthreads();
    }
    #pragma unroll
    for (int i = 0; i < 4; i++) {
        int m = m0 + tm + i;
        int mc = REVC ? ((m & ~(Ss - 1)) | ((Ss - 1) - (m & (Ss - 1)))) : m;
        #pragma unroll
        for (int j = 0; j < 4; j++) {
            int n = n0 + tn + j;
            if (n < Nn) {
                float r = acc[i][j];
                if (bias) r += bias[n];
                if (EPI == 1) {
                    float x3 = r * r * r;
                    r = 0.5f * r * (1.f + tanhf(0.7978845608028654f * (r + 0.044715f * x3)));
                } else if (EPI == 2) {
                    r = fmaxf(r, 0.f) + log1pf(expf(-fabsf(r)));
                }
                if (ACC) C[(size_t)mc * ldc + n] += r;
                else     C[(size_t)mc * ldc + n] = r;
            }
        }
    }
}

// ---------------- causal depthwise conv (k=4) + silu ----------------
__global__ void conv_silu(const float* __restrict__ xz, const float* __restrict__ cw,
                          const float* __restrict__ cb, float* __restrict__ u) {
    int c = blockIdx.x * 256 + threadIdx.x;
    int s0 = blockIdx.y * 16;
    int b = blockIdx.z;
    const float* src = xz + (size_t)b * Ss * (2 * DI) + c;
    float w0 = cw[c * 4 + 0], w1 = cw[c * 4 + 1], w2 = cw[c * 4 + 2], w3 = cw[c * 4 + 3];
    float bias = cb[c];
    float r0 = (s0 - 3 >= 0) ? src[(size_t)(s0 - 3) * (2 * DI)] : 0.f;
    float r1 = (s0 - 2 >= 0) ? src[(size_t)(s0 - 2) * (2 * DI)] : 0.f;
    float r2 = (s0 - 1 >= 0) ? src[(size_t)(s0 - 1) * (2 * DI)] : 0.f;
    for (int i = 0; i < 16; i++) {
        int s = s0 + i;
        float r3 = src[(size_t)s * (2 * DI)];
        float a = fmaf(r0, w0, fmaf(r1, w1, fmaf(r2, w2, fmaf(r3, w3, bias))));
        u[((size_t)b * Ss + s) * DI + c] = a / (1.f + expf(-a));
        r0 = r1; r1 = r2; r2 = r3;
    }
}

// ---------------- selective scan, fused with y=(ys+u*D)*silu(z) ----------------
__global__ __launch_bounds__(256) void scan_fused(
    const float* __restrict__ delta, const float* __restrict__ u,
    const float* __restrict__ xdbl, const float* __restrict__ xz,
    const float* __restrict__ A_log, const float* __restrict__ Dp,
    float* __restrict__ y) {
    int d = blockIdx.x * 256 + threadIdx.x;
    int b = blockIdx.y;
    float Aj[DS], h[DS];
    #pragma unroll
    for (int j = 0; j < DS; j++) { Aj[j] = -expf(A_log[(size_t)d * DS + j]); h[j] = 0.f; }
    float Dd = Dp[d];
    const float* dp = delta + (size_t)b * Ss * DI + d;
    const float* up = u + (size_t)b * Ss * DI + d;
    const float* zp = xz + (size_t)b * Ss * (2 * DI) + DI + d;
    const float* bc = xdbl + (size_t)b * Ss * 64 + DTR;
    float* yp = y + (size_t)b * Ss * DI + d;

    float dl, ut, zz, Bv[DS], Cv[DS];
    // load step 0
    dl = dp[0]; ut = up[0]; zz = zp[0];
    {
        const float* q = bc;
        #pragma unroll
        for (int j = 0; j < DS; j++) { Bv[j] = q[j]; Cv[j] = q[DS + j]; }
    }
    for (int s = 0; s < Ss; s++) {
        // prefetch next step
        int sn = (s + 1 < Ss) ? s + 1 : s;
        float ndl = dp[(size_t)sn * DI];
        float nut = up[(size_t)sn * DI];
        float nzz = zp[(size_t)sn * (2 * DI)];
        float nB[DS], nC[DS];
        const float* q = bc + (size_t)sn * 64;
        #pragma unroll
        for (int j = 0; j < DS; j++) { nB[j] = q[j]; nC[j] = q[DS + j]; }
        // compute current
        float du = dl * ut;
        float acc = 0.f;
        #pragma unroll
        for (int j = 0; j < DS; j++) {
            h[j] = fmaf(expf(dl * Aj[j]), h[j], du * Bv[j]);
            acc = fmaf(h[j], Cv[j], acc);
        }
        float sg = 1.f / (1.f + expf(-zz));
        yp[(size_t)s * DI] = (acc + ut * Dd) * (zz * sg);
        dl = ndl; ut = nut; zz = nzz;
        #pragma unroll
        for (int j = 0; j < DS; j++) { Bv[j] = nB[j]; Cv[j] = nC[j]; }
    }
}

// ---------------- final: out[b,h,n] = pred[b,n,h]*sd + mu ----------------
__global__ void finalize_out(const float* __restrict__ pred, const float* __restrict__ mu,
                             const float* __restrict__ sd, float* __restrict__ out) {
    int n = threadIdx.x;
    int h = blockIdx.x;
    int b = blockIdx.y;
    out[((size_t)b * Hh + h) * NV + n] =
        pred[((size_t)b * NV + n) * Hh + h] * sd[b * NV + n] + mu[b * NV + n];
}

extern "C" void kernel_launch(void* const* d_in, const int* in_sizes, int n_in,
                              void* d_out, int out_size, void* d_ws, size_t ws_size,
                              hipStream_t stream) {
    const float* x     = (const float*)d_in[0];
    const float* tokw  = (const float*)d_in[1];
    const float* tokb  = (const float*)d_in[2];
    const float* in_w  = (const float*)d_in[3];
    const float* in_b  = (const float*)d_in[4];
    const float* convw = (const float*)d_in[5];
    const float* convb = (const float*)d_in[6];
    const float* xpw   = (const float*)d_in[7];
    const float* dtw   = (const float*)d_in[8];
    const float* dtb   = (const float*)d_in[9];
    const float* Alog  = (const float*)d_in[10];
    const float* Dm    = (const float*)d_in[11];
    const float* outw  = (const float*)d_in[12];
    const float* outb  = (const float*)d_in[13];
    const float* mnw   = (const float*)d_in[14];
    const float* mnb   = (const float*)d_in[15];
    const float* fnw   = (const float*)d_in[16];
    const float* fnb   = (const float*)d_in[17];
    const float* fw1   = (const float*)d_in[18];
    const float* fb1   = (const float*)d_in[19];
    const float* fw2   = (const float*)d_in[20];
    const float* fb2   = (const float*)d_in[21];
    const float* nw    = (const float*)d_in[22];
    const float* nb    = (const float*)d_in[23];
    const float* hw    = (const float*)d_in[24];
    const float* hb    = (const float*)d_in[25];

    float* ws = (float*)d_ws;
    float* MU  = ws;                       // B*NV
    float* SD  = MU + Bb * NV;             // B*NV
    float* XNT = SD + Bb * NV;             // B*NV*L
    float* T   = XNT + (size_t)Bb * NV * Ll;   // B*NV*DM
    float* YN  = T + (size_t)Bb * NV * DM;     // B*NV*DM
    float* XZ  = YN + (size_t)Bb * NV * DM;    // MROWS*2DI (also FFN hidden)
    float* U   = XZ + (size_t)MROWS * 2 * DI;  // MROWS*DI
    float* XD  = U + (size_t)MROWS * DI;       // MROWS*64
    float* DEL = XD + (size_t)MROWS * 64;      // MROWS*DI
    float* Y   = DEL + (size_t)MROWS * DI;     // MROWS*DI
    float* PRED = Y + (size_t)MROWS * DI;      // MROWS*H

    revin_stats<<<Bb, NV, 0, stream>>>(x, MU, SD);
    transpose_norm<<<dim3(Ll / 32, NV / 32, Bb), dim3(32, 8), 0, stream>>>(x, MU, SD, XNT);
    // tokenize: T = XNT @ tok_w^T + tok_b
    gemm_awt<0, false, false, false><<<dim3(MROWS / 64, DM / 64), 256, 0, stream>>>(
        XNT, Ll, tokw, tokb, T, DM, MROWS, DM, Ll);

    for (int l = 0; l < NLAY; l++) {
        ln_rows<<<MROWS, DM, 0, stream>>>(T, mnw + l * DM, mnb + l * DM, YN);
        for (int dir = 0; dir < 2; dir++) {
            int pd = l * 2 + dir;
            const float* iw = in_w + (size_t)pd * 2 * DI * DM;
            const float* ib = in_b + (size_t)pd * 2 * DI;
            if (dir == 0)
                gemm_awt<0, false, false, false><<<dim3(MROWS / 64, (2 * DI) / 64), 256, 0, stream>>>(
                    YN, DM, iw, ib, XZ, 2 * DI, MROWS, 2 * DI, DM);
            else
                gemm_awt<0, false, true, false><<<dim3(MROWS / 64, (2 * DI) / 64), 256, 0, stream>>>(
                    YN, DM, iw, ib, XZ, 2 * DI, MROWS, 2 * DI, DM);
            conv_silu<<<dim3(DI / 256, Ss / 16, Bb), 256, 0, stream>>>(
                XZ, convw + (size_t)pd * DI * DCONV, convb + pd * DI, U);
            gemm_awt<0, false, false, false><<<dim3(MROWS / 64, 1), 256, 0, stream>>>(
                U, DI, xpw + (size_t)pd * 64 * DI, nullptr, XD, 64, MROWS, 64, DI);
            gemm_awt<2, false, false, false><<<dim3(MROWS / 64, DI / 64), 256, 0, stream>>>(
                XD, 64, dtw + (size_t)pd * DI * DTR, dtb + pd * DI, DEL, DI, MROWS, DI, DTR);
            scan_fused<<<dim3(DI / 256, Bb), 256, 0, stream>>>(
                DEL, U, XD, XZ, Alog + (size_t)pd * DI * DS, Dm + pd * DI, Y);
            if (dir == 0)
                gemm_awt<0, true, false, false><<<dim3(MROWS / 64, DM / 64), 256, 0, stream>>>(
                    Y, DI, outw + (size_t)pd * DM * DI, outb + pd * DM, T, DM, MROWS, DM, DI);
            else
                gemm_awt<0, true, false, true><<<dim3(MROWS / 64, DM / 64), 256, 0, stream>>>(
                    Y, DI, outw + (size_t)pd * DM * DI, outb + pd * DM, T, DM, MROWS, DM, DI);
        }
        // FFN
        ln_rows<<<MROWS, DM, 0, stream>>>(T, fnw + l * DM, fnb + l * DM, YN);
        gemm_awt<1, false, false, false><<<dim3(MROWS / 64, DFF / 64), 256, 0, stream>>>(
            YN, DM, fw1 + (size_t)l * DFF * DM, fb1 + l * DFF, XZ, DFF, MROWS, DFF, DM);
        gemm_awt<0, true, false, false><<<dim3(MROWS / 64, DM / 64), 256, 0, stream>>>(
            XZ, DFF, fw2 + (size_t)l * DM * DFF, fb2 + l * DM, T, DM, MROWS, DM, DFF);
    }
    ln_rows<<<MROWS, DM, 0, stream>>>(T, nw, nb, YN);
    gemm_awt<0, false, false, false><<<dim3(MROWS / 64, (Hh + 63) / 64), 256, 0, stream>>>(
        YN, DM, hw, hb, PRED, Hh, MROWS, Hh, DM);
    finalize_out<<<dim3(Hh, Bb), NV, 0, stream>>>(PRED, MU, SD, (float*)d_out);
}

// Round 2
// 3746.429 us; speedup vs baseline: 1.2963x; 1.2963x over previous
//
#include <hip/hip_runtime.h>
#include <hip/hip_bf16.h>

#define Bb 16
#define Ll 512
#define NV 512
#define DM 512
#define DS 16
#define NLAY 2
#define DFF 2048
#define DI 1024
#define DCONV 4
#define DTR 32
#define Hh 96
#define Ss NV
#define MROWS (Bb*Ss)
#define EPSf 1e-5f
#define CH 32
#define NCH (Ss/CH)

// ---------------- RevIN stats ----------------
__global__ void revin_stats(const float* __restrict__ x, float* __restrict__ mu, float* __restrict__ sd) {
    int b = blockIdx.x, n = threadIdx.x;
    const float* xp = x + (size_t)b * Ll * NV + n;
    float s1 = 0.f, s2 = 0.f;
    for (int l = 0; l < Ll; l++) { float v = xp[(size_t)l * NV]; s1 += v; s2 += v * v; }
    float m = s1 / Ll;
    float var = s2 / Ll - m * m;
    mu[b * NV + n] = m;
    sd[b * NV + n] = sqrtf(var + EPSf);
}

// ------------- normalize + transpose: xnT[b,n,l] = (x[b,l,n]-mu)/sd -------------
__global__ void transpose_norm(const float* __restrict__ x, const float* __restrict__ mu,
                               const float* __restrict__ sd, float* __restrict__ xnT) {
    __shared__ float t[32][33];
    int b = blockIdx.z;
    int l0 = blockIdx.x * 32, n0 = blockIdx.y * 32;
    int tx = threadIdx.x, ty = threadIdx.y; // 32x8
    #pragma unroll
    for (int q = 0; q < 4; q++)
        t[ty + q * 8][tx] = x[(size_t)b * Ll * NV + (size_t)(l0 + ty + q * 8) * NV + n0 + tx];
    __syncthreads();
    #pragma unroll
    for (int q = 0; q < 4; q++) {
        int n = n0 + ty + q * 8;
        float m = mu[b * NV + n], s = sd[b * NV + n];
        xnT[(size_t)b * NV * Ll + (size_t)n * Ll + l0 + tx] = (t[tx][ty + q * 8] - m) / s;
    }
}

// ---------------- LayerNorm over rows of DM ----------------
__global__ void ln_rows(const float* __restrict__ in, const float* __restrict__ w,
                        const float* __restrict__ bvec, float* __restrict__ out) {
    int row = blockIdx.x;
    int tid = threadIdx.x;
    float v = in[(size_t)row * DM + tid];
    float s1 = v, s2 = v * v;
    #pragma unroll
    for (int o = 32; o > 0; o >>= 1) { s1 += __shfl_down(s1, o, 64); s2 += __shfl_down(s2, o, 64); }
    __shared__ float l1[8], l2[8];
    int wv = tid >> 6, ln = tid & 63;
    if (ln == 0) { l1[wv] = s1; l2[wv] = s2; }
    __syncthreads();
    if (tid == 0) {
        float a = 0.f, c = 0.f;
        #pragma unroll
        for (int i = 0; i < DM / 64; i++) { a += l1[i]; c += l2[i]; }
        l1[0] = a; l2[0] = c;
    }
    __syncthreads();
    float mean = l1[0] / DM;
    float var = l2[0] / DM - mean * mean;
    float inv = rsqrtf(var + EPSf);
    out[(size_t)row * DM + tid] = (v - mean) * inv * w[tid] + bvec[tid];
}

// ---------------- GEMM: C = A(M,K;lda) @ W(N,K)^T + bias, epilogues ----------------
template<int EPI, bool ACC, bool REVA, bool REVC>
__global__ __launch_bounds__(256) void gemm_awt(
    const float* __restrict__ A, int lda,
    const float* __restrict__ W,
    const float* __restrict__ bias,
    float* __restrict__ C, int ldc,
    int M, int Nn, int K) {
    __shared__ float As[16][68];
    __shared__ float Ws[16][68];
    int m0 = blockIdx.x * 64;
    int n0 = blockIdx.y * 64;
    int tid = threadIdx.x;
    int tm = (tid / 16) * 4, tn = (tid % 16) * 4;
    float acc[4][4] = {};
    int lr = tid / 4;        // 0..63
    int lk = (tid % 4) * 4;  // 0,4,8,12
    int arow = m0 + lr;
    if (REVA) arow = (arow & ~(Ss - 1)) | ((Ss - 1) - (arow & (Ss - 1)));
    const float* aptr = A + (size_t)arow * lda + lk;
    int wrow = n0 + lr;
    bool wok = wrow < Nn;
    const float* wptr = W + (size_t)wrow * K + lk;
    for (int k0 = 0; k0 < K; k0 += 16) {
        float4 av = *(const float4*)(aptr + k0);
        float4 wv = wok ? *(const float4*)(wptr + k0) : make_float4(0.f, 0.f, 0.f, 0.f);
        As[lk + 0][lr] = av.x; As[lk + 1][lr] = av.y; As[lk + 2][lr] = av.z; As[lk + 3][lr] = av.w;
        Ws[lk + 0][lr] = wv.x; Ws[lk + 1][lr] = wv.y; Ws[lk + 2][lr] = wv.z; Ws[lk + 3][lr] = wv.w;
        __syncthreads();
        #pragma unroll
        for (int kk = 0; kk < 16; kk++) {
            float4 a = *(const float4*)&As[kk][tm];
            float4 w = *(const float4*)&Ws[kk][tn];
            float ar[4] = {a.x, a.y, a.z, a.w};
            float wr[4] = {w.x, w.y, w.z, w.w};
            #pragma unroll
            for (int i = 0; i < 4; i++)
                #pragma unroll
                for (int j = 0; j < 4; j++)
                    acc[i][j] = fmaf(ar[i], wr[j], acc[i][j]);
        }
        __syncthreads();
    }
    #pragma unroll
    for (int i = 0; i < 4; i++) {
        int m = m0 + tm + i;
        int mc = REVC ? ((m & ~(Ss - 1)) | ((Ss - 1) - (m & (Ss - 1)))) : m;
        #pragma unroll
        for (int j = 0; j < 4; j++) {
            int n = n0 + tn + j;
            if (n < Nn) {
                float r = acc[i][j];
                if (bias) r += bias[n];
                if (EPI == 1) {
                    float x3 = r * r * r;
                    r = 0.5f * r * (1.f + tanhf(0.7978845608028654f * (r + 0.044715f * x3)));
                } else if (EPI == 2) {
                    r = fmaxf(r, 0.f) + log1pf(expf(-fabsf(r)));
                }
                if (ACC) C[(size_t)mc * ldc + n] += r;
                else     C[(size_t)mc * ldc + n] = r;
            }
        }
    }
}

// ---------------- causal depthwise conv (k=4) + silu ----------------
__global__ void conv_silu(const float* __restrict__ xz, const float* __restrict__ cw,
                          const float* __restrict__ cb, float* __restrict__ u) {
    int c = blockIdx.x * 256 + threadIdx.x;
    int s0 = blockIdx.y * 16;
    int b = blockIdx.z;
    const float* src = xz + (size_t)b * Ss * (2 * DI) + c;
    float w0 = cw[c * 4 + 0], w1 = cw[c * 4 + 1], w2 = cw[c * 4 + 2], w3 = cw[c * 4 + 3];
    float bias = cb[c];
    float r0 = (s0 - 3 >= 0) ? src[(size_t)(s0 - 3) * (2 * DI)] : 0.f;
    float r1 = (s0 - 2 >= 0) ? src[(size_t)(s0 - 2) * (2 * DI)] : 0.f;
    float r2 = (s0 - 1 >= 0) ? src[(size_t)(s0 - 1) * (2 * DI)] : 0.f;
    for (int i = 0; i < 16; i++) {
        int s = s0 + i;
        float r3 = src[(size_t)s * (2 * DI)];
        float a = fmaf(r0, w0, fmaf(r1, w1, fmaf(r2, w2, fmaf(r3, w3, bias))));
        u[((size_t)b * Ss + s) * DI + c] = a / (1.f + expf(-a));
        r0 = r1; r1 = r2; r2 = r3;
    }
}

// ======== chunked parallel selective scan ========
// Pass 1: per (b, chunk, d) compute P[j]=prod(exp(dl*A_j)) and local end-state hloc[j] (h_in = 0)
__global__ __launch_bounds__(256) void scan_pass1(
    const float* __restrict__ delta, const float* __restrict__ u,
    const float* __restrict__ xdbl, const float* __restrict__ A_log,
    float* __restrict__ PB, float* __restrict__ HB) {
    int d = blockIdx.x * 256 + threadIdx.x;
    int c = blockIdx.y;
    int b = blockIdx.z;
    float Aj[DS], P[DS], h[DS];
    #pragma unroll
    for (int j = 0; j < DS; j++) { Aj[j] = -expf(A_log[(size_t)d * DS + j]); P[j] = 1.f; h[j] = 0.f; }
    const float* dp = delta + ((size_t)b * Ss + c * CH) * DI + d;
    const float* up = u + ((size_t)b * Ss + c * CH) * DI + d;
    const float* bc = xdbl + ((size_t)b * Ss + c * CH) * 64 + DTR;
    for (int i = 0; i < CH; i++) {
        float dl = dp[(size_t)i * DI];
        float ut = up[(size_t)i * DI];
        float du = dl * ut;
        const float4* q4 = (const float4*)(bc + (size_t)i * 64);
        float4 B0 = q4[0], B1 = q4[1], B2 = q4[2], B3 = q4[3];
        float Bv[DS] = {B0.x, B0.y, B0.z, B0.w, B1.x, B1.y, B1.z, B1.w,
                        B2.x, B2.y, B2.z, B2.w, B3.x, B3.y, B3.z, B3.w};
        #pragma unroll
        for (int j = 0; j < DS; j++) {
            float a = expf(dl * Aj[j]);
            P[j] *= a;
            h[j] = fmaf(a, h[j], du * Bv[j]);
        }
    }
    size_t base = ((size_t)(b * NCH + c)) * DS * DI + d;
    #pragma unroll
    for (int j = 0; j < DS; j++) {
        PB[base + (size_t)j * DI] = P[j];
        HB[base + (size_t)j * DI] = h[j];
    }
}

// Pass 2: per (b, j, d): sequential combine over NCH chunks -> h_in per chunk
__global__ __launch_bounds__(256) void scan_pass2(
    const float* __restrict__ PB, const float* __restrict__ HB, float* __restrict__ HIN) {
    int idx = blockIdx.x * 256 + threadIdx.x;   // b*(DS*DI) + j*DI + d
    int b = idx >> 14;                          // DS*DI = 16384
    int rem = idx & 16383;
    float h = 0.f;
    #pragma unroll
    for (int c = 0; c < NCH; c++) {
        size_t o = ((size_t)(b * NCH + c)) * (DS * DI) + rem;
        float p = PB[o], hl = HB[o];
        HIN[o] = h;
        h = fmaf(p, h, hl);
    }
}

// Pass 3: re-run chunk scan with correct h_in, fused epilogue y=(acc+u*D)*silu(z)
__global__ __launch_bounds__(256) void scan_pass3(
    const float* __restrict__ delta, const float* __restrict__ u,
    const float* __restrict__ xdbl, const float* __restrict__ xz,
    const float* __restrict__ A_log, const float* __restrict__ Dp,
    const float* __restrict__ HIN, float* __restrict__ y) {
    int d = blockIdx.x * 256 + threadIdx.x;
    int c = blockIdx.y;
    int b = blockIdx.z;
    float Aj[DS], h[DS];
    size_t hbase = ((size_t)(b * NCH + c)) * DS * DI + d;
    #pragma unroll
    for (int j = 0; j < DS; j++) {
        Aj[j] = -expf(A_log[(size_t)d * DS + j]);
        h[j] = HIN[hbase + (size_t)j * DI];
    }
    float Dd = Dp[d];
    const float* dp = delta + ((size_t)b * Ss + c * CH) * DI + d;
    const float* up = u + ((size_t)b * Ss + c * CH) * DI + d;
    const float* zp = xz + ((size_t)b * Ss + c * CH) * (2 * DI) + DI + d;
    const float* bc = xdbl + ((size_t)b * Ss + c * CH) * 64 + DTR;
    float* yp = y + ((size_t)b * Ss + c * CH) * DI + d;
    for (int i = 0; i < CH; i++) {
        float dl = dp[(size_t)i * DI];
        float ut = up[(size_t)i * DI];
        float zz = zp[(size_t)i * (2 * DI)];
        float du = dl * ut;
        const float4* q4 = (const float4*)(bc + (size_t)i * 64);
        float4 B0 = q4[0], B1 = q4[1], B2 = q4[2], B3 = q4[3];
        float4 C0 = q4[4], C1 = q4[5], C2 = q4[6], C3 = q4[7];
        float Bv[DS] = {B0.x, B0.y, B0.z, B0.w, B1.x, B1.y, B1.z, B1.w,
                        B2.x, B2.y, B2.z, B2.w, B3.x, B3.y, B3.z, B3.w};
        float Cv[DS] = {C0.x, C0.y, C0.z, C0.w, C1.x, C1.y, C1.z, C1.w,
                        C2.x, C2.y, C2.z, C2.w, C3.x, C3.y, C3.z, C3.w};
        float acc = 0.f;
        #pragma unroll
        for (int j = 0; j < DS; j++) {
            float a = expf(dl * Aj[j]);
            h[j] = fmaf(a, h[j], du * Bv[j]);
            acc = fmaf(h[j], Cv[j], acc);
        }
        float sg = 1.f / (1.f + expf(-zz));
        yp[(size_t)i * DI] = (acc + ut * Dd) * (zz * sg);
    }
}

// ---------------- final: out[b,h,n] = pred[b,n,h]*sd + mu ----------------
__global__ void finalize_out(const float* __restrict__ pred, const float* __restrict__ mu,
                             const float* __restrict__ sd, float* __restrict__ out) {
    int n = threadIdx.x;
    int h = blockIdx.x;
    int b = blockIdx.y;
    out[((size_t)b * Hh + h) * NV + n] =
        pred[((size_t)b * NV + n) * Hh + h] * sd[b * NV + n] + mu[b * NV + n];
}

extern "C" void kernel_launch(void* const* d_in, const int* in_sizes, int n_in,
                              void* d_out, int out_size, void* d_ws, size_t ws_size,
                              hipStream_t stream) {
    const float* x     = (const float*)d_in[0];
    const float* tokw  = (const float*)d_in[1];
    const float* tokb  = (const float*)d_in[2];
    const float* in_w  = (const float*)d_in[3];
    const float* in_b  = (const float*)d_in[4];
    const float* convw = (const float*)d_in[5];
    const float* convb = (const float*)d_in[6];
    const float* xpw   = (const float*)d_in[7];
    const float* dtw   = (const float*)d_in[8];
    const float* dtb   = (const float*)d_in[9];
    const float* Alog  = (const float*)d_in[10];
    const float* Dm    = (const float*)d_in[11];
    const float* outw  = (const float*)d_in[12];
    const float* outb  = (const float*)d_in[13];
    const float* mnw   = (const float*)d_in[14];
    const float* mnb   = (const float*)d_in[15];
    const float* fnw   = (const float*)d_in[16];
    const float* fnb   = (const float*)d_in[17];
    const float* fw1   = (const float*)d_in[18];
    const float* fb1   = (const float*)d_in[19];
    const float* fw2   = (const float*)d_in[20];
    const float* fb2   = (const float*)d_in[21];
    const float* nw    = (const float*)d_in[22];
    const float* nb    = (const float*)d_in[23];
    const float* hw    = (const float*)d_in[24];
    const float* hb    = (const float*)d_in[25];

    float* ws = (float*)d_ws;
    float* MU  = ws;                       // B*NV
    float* SD  = MU + Bb * NV;             // B*NV
    float* XNT = SD + Bb * NV;             // B*NV*L  (reused as HIN during scans)
    float* T   = XNT + (size_t)Bb * NV * Ll;   // B*NV*DM
    float* YN  = T + (size_t)Bb * NV * DM;     // B*NV*DM
    float* XZ  = YN + (size_t)Bb * NV * DM;    // MROWS*2DI (also FFN hidden)
    float* U   = XZ + (size_t)MROWS * 2 * DI;  // MROWS*DI
    float* XD  = U + (size_t)MROWS * DI;       // MROWS*64
    float* DEL = XD + (size_t)MROWS * 64;      // MROWS*DI
    float* Y   = DEL + (size_t)MROWS * DI;     // MROWS*DI (PB/HB live here before pass3)
    float* PRED = Y + (size_t)MROWS * DI;      // MROWS*H

    // scan scratch aliases (dead buffers at scan time)
    float* PB  = Y;                             // B*NCH*DS*DI = 4M floats
    float* HB  = Y + (size_t)Bb * NCH * DS * DI; // 4M floats (Y is 8M total: exact fit)
    float* HIN = XNT;                           // 4M floats (XNT dead after tokenize)

    revin_stats<<<Bb, NV, 0, stream>>>(x, MU, SD);
    transpose_norm<<<dim3(Ll / 32, NV / 32, Bb), dim3(32, 8), 0, stream>>>(x, MU, SD, XNT);
    gemm_awt<0, false, false, false><<<dim3(MROWS / 64, DM / 64), 256, 0, stream>>>(
        XNT, Ll, tokw, tokb, T, DM, MROWS, DM, Ll);

    for (int l = 0; l < NLAY; l++) {
        ln_rows<<<MROWS, DM, 0, stream>>>(T, mnw + l * DM, mnb + l * DM, YN);
        for (int dir = 0; dir < 2; dir++) {
            int pd = l * 2 + dir;
            const float* iw = in_w + (size_t)pd * 2 * DI * DM;
            const float* ib = in_b + (size_t)pd * 2 * DI;
            if (dir == 0)
                gemm_awt<0, false, false, false><<<dim3(MROWS / 64, (2 * DI) / 64), 256, 0, stream>>>(
                    YN, DM, iw, ib, XZ, 2 * DI, MROWS, 2 * DI, DM);
            else
                gemm_awt<0, false, true, false><<<dim3(MROWS / 64, (2 * DI) / 64), 256, 0, stream>>>(
                    YN, DM, iw, ib, XZ, 2 * DI, MROWS, 2 * DI, DM);
            conv_silu<<<dim3(DI / 256, Ss / 16, Bb), 256, 0, stream>>>(
                XZ, convw + (size_t)pd * DI * DCONV, convb + pd * DI, U);
            gemm_awt<0, false, false, false><<<dim3(MROWS / 64, 1), 256, 0, stream>>>(
                U, DI, xpw + (size_t)pd * 64 * DI, nullptr, XD, 64, MROWS, 64, DI);
            gemm_awt<2, false, false, false><<<dim3(MROWS / 64, DI / 64), 256, 0, stream>>>(
                XD, 64, dtw + (size_t)pd * DI * DTR, dtb + pd * DI, DEL, DI, MROWS, DI, DTR);
            // chunked parallel scan
            scan_pass1<<<dim3(DI / 256, NCH, Bb), 256, 0, stream>>>(
                DEL, U, XD, Alog + (size_t)pd * DI * DS, PB, HB);
            scan_pass2<<<(Bb * DS * DI) / 256, 256, 0, stream>>>(PB, HB, HIN);
            scan_pass3<<<dim3(DI / 256, NCH, Bb), 256, 0, stream>>>(
                DEL, U, XD, XZ, Alog + (size_t)pd * DI * DS, Dm + pd * DI, HIN, Y);
            if (dir == 0)
                gemm_awt<0, true, false, false><<<dim3(MROWS / 64, DM / 64), 256, 0, stream>>>(
                    Y, DI, outw + (size_t)pd * DM * DI, outb + pd * DM, T, DM, MROWS, DM, DI);
            else
                gemm_awt<0, true, false, true><<<dim3(MROWS / 64, DM / 64), 256, 0, stream>>>(
                    Y, DI, outw + (size_t)pd * DM * DI, outb + pd * DM, T, DM, MROWS, DM, DI);
        }
        // FFN
        ln_rows<<<MROWS, DM, 0, stream>>>(T, fnw + l * DM, fnb + l * DM, YN);
        gemm_awt<1, false, false, false><<<dim3(MROWS / 64, DFF / 64), 256, 0, stream>>>(
            YN, DM, fw1 + (size_t)l * DFF * DM, fb1 + l * DFF, XZ, DFF, MROWS, DFF, DM);
        gemm_awt<0, true, false, false><<<dim3(MROWS / 64, DM / 64), 256, 0, stream>>>(
            XZ, DFF, fw2 + (size_t)l * DM * DFF, fb2 + l * DM, T, DM, MROWS, DM, DFF);
    }
    ln_rows<<<MROWS, DM, 0, stream>>>(T, nw, nb, YN);
    gemm_awt<0, false, false, false><<<dim3(MROWS / 64, (Hh + 63) / 64), 256, 0, stream>>>(
        YN, DM, hw, hb, PRED, Hh, MROWS, Hh, DM);
    finalize_out<<<dim3(Hh, Bb), NV, 0, stream>>>(PRED, MU, SD, (float*)d_out);
}

// Round 3
// 1570.692 us; speedup vs baseline: 3.0919x; 2.3852x over previous
//
#include <hip/hip_runtime.h>
#include <hip/hip_bf16.h>

#define Bb 16
#define Ll 512
#define NV 512
#define DM 512
#define DS 16
#define NLAY 2
#define DFF 2048
#define DI 1024
#define DCONV 4
#define DTR 32
#define Hh 96
#define Ss NV
#define MROWS (Bb*Ss)
#define EPSf 1e-5f
#define CH 32
#define NCH (Ss/CH)

typedef __hip_bfloat16 bf16;
typedef __attribute__((ext_vector_type(8))) short bf16x8;
typedef __attribute__((ext_vector_type(4))) float f32x4;

#define GLL16(g, l) __builtin_amdgcn_global_load_lds( \
    (const __attribute__((address_space(1))) unsigned int*)(g), \
    (__attribute__((address_space(3))) unsigned int*)(l), 16, 0, 0)

// ---------------- fp32 -> bf16 convert ----------------
__global__ void f2bf(const float* __restrict__ in, bf16* __restrict__ out, int n) {
    int i = (blockIdx.x * 256 + threadIdx.x) * 4;
    if (i < n) {
        float4 v = *(const float4*)(in + i);
        out[i + 0] = __float2bfloat16(v.x);
        out[i + 1] = __float2bfloat16(v.y);
        out[i + 2] = __float2bfloat16(v.z);
        out[i + 3] = __float2bfloat16(v.w);
    }
}

// ---------------- RevIN stats ----------------
__global__ void revin_stats(const float* __restrict__ x, float* __restrict__ mu, float* __restrict__ sd) {
    int b = blockIdx.x, n = threadIdx.x;
    const float* xp = x + (size_t)b * Ll * NV + n;
    float s1 = 0.f, s2 = 0.f;
    for (int l = 0; l < Ll; l++) { float v = xp[(size_t)l * NV]; s1 += v; s2 += v * v; }
    float m = s1 / Ll;
    float var = s2 / Ll - m * m;
    mu[b * NV + n] = m;
    sd[b * NV + n] = sqrtf(var + EPSf);
}

// ------------- normalize + transpose -> bf16: xnT[b,n,l] -------------
__global__ void transpose_norm(const float* __restrict__ x, const float* __restrict__ mu,
                               const float* __restrict__ sd, bf16* __restrict__ xnT) {
    __shared__ float t[32][33];
    int b = blockIdx.z;
    int l0 = blockIdx.x * 32, n0 = blockIdx.y * 32;
    int tx = threadIdx.x, ty = threadIdx.y; // 32x8
    #pragma unroll
    for (int q = 0; q < 4; q++)
        t[ty + q * 8][tx] = x[(size_t)b * Ll * NV + (size_t)(l0 + ty + q * 8) * NV + n0 + tx];
    __syncthreads();
    #pragma unroll
    for (int q = 0; q < 4; q++) {
        int n = n0 + ty + q * 8;
        float m = mu[b * NV + n], s = sd[b * NV + n];
        xnT[(size_t)b * NV * Ll + (size_t)n * Ll + l0 + tx] = __float2bfloat16((t[tx][ty + q * 8] - m) / s);
    }
}

// ---------------- LayerNorm over rows of DM -> bf16 ----------------
__global__ void ln_rows(const float* __restrict__ in, const float* __restrict__ w,
                        const float* __restrict__ bvec, bf16* __restrict__ out) {
    int row = blockIdx.x;
    int tid = threadIdx.x;
    float v = in[(size_t)row * DM + tid];
    float s1 = v, s2 = v * v;
    #pragma unroll
    for (int o = 32; o > 0; o >>= 1) { s1 += __shfl_down(s1, o, 64); s2 += __shfl_down(s2, o, 64); }
    __shared__ float l1[8], l2[8];
    int wv = tid >> 6, ln = tid & 63;
    if (ln == 0) { l1[wv] = s1; l2[wv] = s2; }
    __syncthreads();
    if (tid == 0) {
        float a = 0.f, c = 0.f;
        #pragma unroll
        for (int i = 0; i < DM / 64; i++) { a += l1[i]; c += l2[i]; }
        l1[0] = a; l2[0] = c;
    }
    __syncthreads();
    float mean = l1[0] / DM;
    float var = l2[0] / DM - mean * mean;
    float inv = rsqrtf(var + EPSf);
    out[(size_t)row * DM + tid] = __float2bfloat16((v - mean) * inv * w[tid] + bvec[tid]);
}

// ---------------- MFMA GEMM: C = A(M,K) @ W(N,K)^T + bias ----------------
// A, W bf16 (K-contiguous). C fp32 or bf16 (OUTBF). EPI: 0 none, 1 gelu.
// REVA/REVC: reverse rows within 512-blocks. Tile 128x128, BK=32, 4 waves.
template<int EPI, bool ACC, bool REVA, bool REVC, bool OUTBF>
__global__ __launch_bounds__(256) void gemm_mfma(
    const bf16* __restrict__ A, int lda,
    const bf16* __restrict__ W,
    const float* __restrict__ bias,
    void* __restrict__ Cv, int ldc,
    int M, int Nn, int K) {
    __shared__ bf16 As[128 * 32];
    __shared__ bf16 Bs[128 * 32];
    int m0 = blockIdx.x * 128, n0 = blockIdx.y * 128;
    int tid = threadIdx.x;
    int w = tid >> 6, lane = tid & 63;
    int wm = (w >> 1) * 64, wn = (w & 1) * 64;
    f32x4 acc[4][4] = {};

    // staging: wave w stages rows [w*32, w*32+32) of each tile, 2 instrs each
    int srow = w * 32 + (lane >> 2);
    int scol = (lane & 3) * 16;                 // bytes within 64B row
    long arow0 = m0 + srow, arow1 = m0 + srow + 16;
    if (REVA) {
        arow0 = (arow0 & ~511L) | (511 - (arow0 & 511));
        arow1 = (arow1 & ~511L) | (511 - (arow1 & 511));
    }
    const char* agp0 = (const char*)(A + arow0 * (long)lda) + scol;
    const char* agp1 = (const char*)(A + arow1 * (long)lda) + scol;
    long wrow0 = n0 + srow;      if (wrow0 >= Nn) wrow0 = Nn - 1;
    long wrow1 = n0 + srow + 16; if (wrow1 >= Nn) wrow1 = Nn - 1;
    const char* wgp0 = (const char*)(W + wrow0 * (long)K) + scol;
    const char* wgp1 = (const char*)(W + wrow1 * (long)K) + scol;

    char* lA0 = (char*)&As[(w * 32) * 32];
    char* lA1 = (char*)&As[(w * 32 + 16) * 32];
    char* lB0 = (char*)&Bs[(w * 32) * 32];
    char* lB1 = (char*)&Bs[(w * 32 + 16) * 32];

    int lrow = lane & 15, lk = (lane >> 4) * 16; // frag read: row, byte offset

    for (int k0 = 0; k0 < K; k0 += 32) {
        GLL16(agp0, lA0);
        GLL16(agp1, lA1);
        GLL16(wgp0, lB0);
        GLL16(wgp1, lB1);
        agp0 += 64; agp1 += 64; wgp0 += 64; wgp1 += 64;
        __syncthreads();
        bf16x8 af[4], bfr[4];
        #pragma unroll
        for (int i = 0; i < 4; i++) {
            af[i]  = *(const bf16x8*)((const char*)&As[(wm + i * 16 + lrow) * 32] + lk);
            bfr[i] = *(const bf16x8*)((const char*)&Bs[(wn + i * 16 + lrow) * 32] + lk);
        }
        #pragma unroll
        for (int i = 0; i < 4; i++)
            #pragma unroll
            for (int j = 0; j < 4; j++)
                acc[i][j] = __builtin_amdgcn_mfma_f32_16x16x32_bf16(af[i], bfr[j], acc[i][j], 0, 0, 0);
        __syncthreads();
    }

    #pragma unroll
    for (int i = 0; i < 4; i++) {
        #pragma unroll
        for (int j = 0; j < 4; j++) {
            int n = n0 + wn + j * 16 + (lane & 15);
            if (n >= Nn) continue;
            float bv = bias ? bias[n] : 0.f;
            #pragma unroll
            for (int r = 0; r < 4; r++) {
                int m = m0 + wm + i * 16 + (lane >> 4) * 4 + r;
                float v = acc[i][j][r] + bv;
                if (EPI == 1) {
                    float x3 = v * v * v;
                    v = 0.5f * v * (1.f + tanhf(0.7978845608028654f * (v + 0.044715f * x3)));
                }
                long mc = REVC ? ((m & ~511) | (511 - (m & 511))) : m;
                if (OUTBF) {
                    ((bf16*)Cv)[mc * (long)ldc + n] = __float2bfloat16(v);
                } else if (ACC) {
                    ((float*)Cv)[mc * (long)ldc + n] += v;
                } else {
                    ((float*)Cv)[mc * (long)ldc + n] = v;
                }
            }
        }
    }
}

// ---------------- fp32 GEMM (kept for dt-proj, K=32) ----------------
template<int EPI, bool ACC, bool REVA, bool REVC>
__global__ __launch_bounds__(256) void gemm_awt(
    const float* __restrict__ A, int lda,
    const float* __restrict__ W,
    const float* __restrict__ bias,
    float* __restrict__ C, int ldc,
    int M, int Nn, int K) {
    __shared__ float Asm[16][68];
    __shared__ float Wsm[16][68];
    int m0 = blockIdx.x * 64;
    int n0 = blockIdx.y * 64;
    int tid = threadIdx.x;
    int tm = (tid / 16) * 4, tn = (tid % 16) * 4;
    float acc[4][4] = {};
    int lr = tid / 4;
    int lk = (tid % 4) * 4;
    int arow = m0 + lr;
    if (REVA) arow = (arow & ~(Ss - 1)) | ((Ss - 1) - (arow & (Ss - 1)));
    const float* aptr = A + (size_t)arow * lda + lk;
    int wrow = n0 + lr;
    bool wok = wrow < Nn;
    const float* wptr = W + (size_t)wrow * K + lk;
    for (int k0 = 0; k0 < K; k0 += 16) {
        float4 av = *(const float4*)(aptr + k0);
        float4 wv = wok ? *(const float4*)(wptr + k0) : make_float4(0.f, 0.f, 0.f, 0.f);
        Asm[lk + 0][lr] = av.x; Asm[lk + 1][lr] = av.y; Asm[lk + 2][lr] = av.z; Asm[lk + 3][lr] = av.w;
        Wsm[lk + 0][lr] = wv.x; Wsm[lk + 1][lr] = wv.y; Wsm[lk + 2][lr] = wv.z; Wsm[lk + 3][lr] = wv.w;
        __syncthreads();
        #pragma unroll
        for (int kk = 0; kk < 16; kk++) {
            float4 a = *(const float4*)&Asm[kk][tm];
            float4 wv2 = *(const float4*)&Wsm[kk][tn];
            float ar[4] = {a.x, a.y, a.z, a.w};
            float wr[4] = {wv2.x, wv2.y, wv2.z, wv2.w};
            #pragma unroll
            for (int i = 0; i < 4; i++)
                #pragma unroll
                for (int j = 0; j < 4; j++)
                    acc[i][j] = fmaf(ar[i], wr[j], acc[i][j]);
        }
        __syncthreads();
    }
    #pragma unroll
    for (int i = 0; i < 4; i++) {
        int m = m0 + tm + i;
        int mc = REVC ? ((m & ~(Ss - 1)) | ((Ss - 1) - (m & (Ss - 1)))) : m;
        #pragma unroll
        for (int j = 0; j < 4; j++) {
            int n = n0 + tn + j;
            if (n < Nn) {
                float r = acc[i][j];
                if (bias) r += bias[n];
                if (EPI == 1) {
                    float x3 = r * r * r;
                    r = 0.5f * r * (1.f + tanhf(0.7978845608028654f * (r + 0.044715f * x3)));
                } else if (EPI == 2) {
                    r = fmaxf(r, 0.f) + log1pf(expf(-fabsf(r)));
                }
                if (ACC) C[(size_t)mc * ldc + n] += r;
                else     C[(size_t)mc * ldc + n] = r;
            }
        }
    }
}

// ---------------- causal depthwise conv (k=4) + silu, dual output ----------------
__global__ void conv_silu(const float* __restrict__ xz, const float* __restrict__ cw,
                          const float* __restrict__ cb, float* __restrict__ u,
                          bf16* __restrict__ ub) {
    int c = blockIdx.x * 256 + threadIdx.x;
    int s0 = blockIdx.y * 16;
    int b = blockIdx.z;
    const float* src = xz + (size_t)b * Ss * (2 * DI) + c;
    float w0 = cw[c * 4 + 0], w1 = cw[c * 4 + 1], w2 = cw[c * 4 + 2], w3 = cw[c * 4 + 3];
    float bias = cb[c];
    float r0 = (s0 - 3 >= 0) ? src[(size_t)(s0 - 3) * (2 * DI)] : 0.f;
    float r1 = (s0 - 2 >= 0) ? src[(size_t)(s0 - 2) * (2 * DI)] : 0.f;
    float r2 = (s0 - 1 >= 0) ? src[(size_t)(s0 - 1) * (2 * DI)] : 0.f;
    for (int i = 0; i < 16; i++) {
        int s = s0 + i;
        float r3 = src[(size_t)s * (2 * DI)];
        float a = fmaf(r0, w0, fmaf(r1, w1, fmaf(r2, w2, fmaf(r3, w3, bias))));
        float v = a / (1.f + expf(-a));
        u[((size_t)b * Ss + s) * DI + c] = v;
        ub[((size_t)b * Ss + s) * DI + c] = __float2bfloat16(v);
        r0 = r1; r1 = r2; r2 = r3;
    }
}

// ======== chunked parallel selective scan ========
__global__ __launch_bounds__(256) void scan_pass1(
    const float* __restrict__ delta, const float* __restrict__ u,
    const float* __restrict__ xdbl, const float* __restrict__ A_log,
    float* __restrict__ PB, float* __restrict__ HB) {
    int d = blockIdx.x * 256 + threadIdx.x;
    int c = blockIdx.y;
    int b = blockIdx.z;
    float Aj[DS], P[DS], h[DS];
    #pragma unroll
    for (int j = 0; j < DS; j++) { Aj[j] = -expf(A_log[(size_t)d * DS + j]); P[j] = 1.f; h[j] = 0.f; }
    const float* dp = delta + ((size_t)b * Ss + c * CH) * DI + d;
    const float* up = u + ((size_t)b * Ss + c * CH) * DI + d;
    const float* bc = xdbl + ((size_t)b * Ss + c * CH) * 64 + DTR;
    for (int i = 0; i < CH; i++) {
        float dl = dp[(size_t)i * DI];
        float ut = up[(size_t)i * DI];
        float du = dl * ut;
        const float4* q4 = (const float4*)(bc + (size_t)i * 64);
        float4 B0 = q4[0], B1 = q4[1], B2 = q4[2], B3 = q4[3];
        float Bv[DS] = {B0.x, B0.y, B0.z, B0.w, B1.x, B1.y, B1.z, B1.w,
                        B2.x, B2.y, B2.z, B2.w, B3.x, B3.y, B3.z, B3.w};
        #pragma unroll
        for (int j = 0; j < DS; j++) {
            float a = expf(dl * Aj[j]);
            P[j] *= a;
            h[j] = fmaf(a, h[j], du * Bv[j]);
        }
    }
    size_t base = ((size_t)(b * NCH + c)) * DS * DI + d;
    #pragma unroll
    for (int j = 0; j < DS; j++) {
        PB[base + (size_t)j * DI] = P[j];
        HB[base + (size_t)j * DI] = h[j];
    }
}

__global__ __launch_bounds__(256) void scan_pass2(
    const float* __restrict__ PB, const float* __restrict__ HB, float* __restrict__ HIN) {
    int idx = blockIdx.x * 256 + threadIdx.x;
    int b = idx >> 14;
    int rem = idx & 16383;
    float h = 0.f;
    #pragma unroll
    for (int c = 0; c < NCH; c++) {
        size_t o = ((size_t)(b * NCH + c)) * (DS * DI) + rem;
        float p = PB[o], hl = HB[o];
        HIN[o] = h;
        h = fmaf(p, h, hl);
    }
}

__global__ __launch_bounds__(256) void scan_pass3(
    const float* __restrict__ delta, const float* __restrict__ u,
    const float* __restrict__ xdbl, const float* __restrict__ xz,
    const float* __restrict__ A_log, const float* __restrict__ Dp,
    const float* __restrict__ HIN, bf16* __restrict__ y) {
    int d = blockIdx.x * 256 + threadIdx.x;
    int c = blockIdx.y;
    int b = blockIdx.z;
    float Aj[DS], h[DS];
    size_t hbase = ((size_t)(b * NCH + c)) * DS * DI + d;
    #pragma unroll
    for (int j = 0; j < DS; j++) {
        Aj[j] = -expf(A_log[(size_t)d * DS + j]);
        h[j] = HIN[hbase + (size_t)j * DI];
    }
    float Dd = Dp[d];
    const float* dp = delta + ((size_t)b * Ss + c * CH) * DI + d;
    const float* up = u + ((size_t)b * Ss + c * CH) * DI + d;
    const float* zp = xz + ((size_t)b * Ss + c * CH) * (2 * DI) + DI + d;
    const float* bc = xdbl + ((size_t)b * Ss + c * CH) * 64 + DTR;
    bf16* yp = y + ((size_t)b * Ss + c * CH) * DI + d;
    for (int i = 0; i < CH; i++) {
        float dl = dp[(size_t)i * DI];
        float ut = up[(size_t)i * DI];
        float zz = zp[(size_t)i * (2 * DI)];
        float du = dl * ut;
        const float4* q4 = (const float4*)(bc + (size_t)i * 64);
        float4 B0 = q4[0], B1 = q4[1], B2 = q4[2], B3 = q4[3];
        float4 C0 = q4[4], C1 = q4[5], C2 = q4[6], C3 = q4[7];
        float Bv[DS] = {B0.x, B0.y, B0.z, B0.w, B1.x, B1.y, B1.z, B1.w,
                        B2.x, B2.y, B2.z, B2.w, B3.x, B3.y, B3.z, B3.w};
        float Cv[DS] = {C0.x, C0.y, C0.z, C0.w, C1.x, C1.y, C1.z, C1.w,
                        C2.x, C2.y, C2.z, C2.w, C3.x, C3.y, C3.z, C3.w};
        float acc = 0.f;
        #pragma unroll
        for (int j = 0; j < DS; j++) {
            float a = expf(dl * Aj[j]);
            h[j] = fmaf(a, h[j], du * Bv[j]);
            acc = fmaf(h[j], Cv[j], acc);
        }
        float sg = 1.f / (1.f + expf(-zz));
        yp[(size_t)i * DI] = __float2bfloat16((acc + ut * Dd) * (zz * sg));
    }
}

// ---------------- final: out[b,h,n] = pred[b,n,h]*sd + mu ----------------
__global__ void finalize_out(const float* __restrict__ pred, const float* __restrict__ mu,
                             const float* __restrict__ sd, float* __restrict__ out) {
    int n = threadIdx.x;
    int h = blockIdx.x;
    int b = blockIdx.y;
    out[((size_t)b * Hh + h) * NV + n] =
        pred[((size_t)b * NV + n) * Hh + h] * sd[b * NV + n] + mu[b * NV + n];
}

extern "C" void kernel_launch(void* const* d_in, const int* in_sizes, int n_in,
                              void* d_out, int out_size, void* d_ws, size_t ws_size,
                              hipStream_t stream) {
    const float* x     = (const float*)d_in[0];
    const float* tokw  = (const float*)d_in[1];
    const float* tokb  = (const float*)d_in[2];
    const float* in_w  = (const float*)d_in[3];
    const float* in_b  = (const float*)d_in[4];
    const float* convw = (const float*)d_in[5];
    const float* convb = (const float*)d_in[6];
    const float* xpw   = (const float*)d_in[7];
    const float* dtw   = (const float*)d_in[8];
    const float* dtb   = (const float*)d_in[9];
    const float* Alog  = (const float*)d_in[10];
    const float* Dm    = (const float*)d_in[11];
    const float* outw  = (const float*)d_in[12];
    const float* outb  = (const float*)d_in[13];
    const float* mnw   = (const float*)d_in[14];
    const float* mnb   = (const float*)d_in[15];
    const float* fnw   = (const float*)d_in[16];
    const float* fnb   = (const float*)d_in[17];
    const float* fw1   = (const float*)d_in[18];
    const float* fb1   = (const float*)d_in[19];
    const float* fw2   = (const float*)d_in[20];
    const float* fb2   = (const float*)d_in[21];
    const float* nw    = (const float*)d_in[22];
    const float* nb    = (const float*)d_in[23];
    const float* hw    = (const float*)d_in[24];
    const float* hb    = (const float*)d_in[25];

    float* ws = (float*)d_ws;
    float* MU  = ws;                            // B*NV
    float* SD  = MU + Bb * NV;                  // B*NV
    float* XNT = SD + Bb * NV;                  // 4M floats region (XNTb bf16 / HIN fp32)
    float* T   = XNT + (size_t)Bb * NV * Ll;    // B*NV*DM fp32
    float* YN  = T + (size_t)Bb * NV * DM;      // region (YNb bf16)
    float* XZ  = YN + (size_t)Bb * NV * DM;     // MROWS*2DI fp32 (XZb bf16 in FFN phase)
    float* U   = XZ + (size_t)MROWS * 2 * DI;   // MROWS*DI fp32
    float* XD  = U + (size_t)MROWS * DI;        // MROWS*64 fp32
    float* DEL = XD + (size_t)MROWS * 64;       // MROWS*DI fp32 (Ub bf16 pre-dt)
    float* Y   = DEL + (size_t)MROWS * DI;      // MROWS*DI region (PB/HB fp32, Yb bf16)
    float* PRED = Y + (size_t)MROWS * DI;       // MROWS*H fp32
    float* WBF  = PRED + (size_t)MROWS * Hh;    // bf16 weights region

    bf16* XNTb = (bf16*)XNT;
    bf16* YNb  = (bf16*)YN;
    bf16* XZb  = (bf16*)XZ;
    bf16* Ub   = (bf16*)DEL;
    bf16* Yb   = (bf16*)Y;
    float* PB  = Y;
    float* HB  = Y + (size_t)Bb * NCH * DS * DI;
    float* HIN = XNT;

    // bf16 weight copies
    bf16* wb = (bf16*)WBF;
    bf16* tokwb = wb;              wb += (size_t)DM * Ll;          // 262144
    bf16* inwb  = wb;              wb += (size_t)NLAY * 2 * 2 * DI * DM; // 4194304
    bf16* xpwb  = wb;              wb += (size_t)NLAY * 2 * 64 * DI;     // 262144
    bf16* outwb = wb;              wb += (size_t)NLAY * 2 * DM * DI;     // 2097152
    bf16* fw1b  = wb;              wb += (size_t)NLAY * DFF * DM;        // 2097152
    bf16* fw2b  = wb;              wb += (size_t)NLAY * DM * DFF;        // 2097152
    bf16* hwb   = wb;              wb += (size_t)Hh * DM;                // 49152

    f2bf<<<(DM * Ll) / 1024, 256, 0, stream>>>(tokw, tokwb, DM * Ll);
    f2bf<<<(NLAY * 2 * 2 * DI * DM) / 1024, 256, 0, stream>>>(in_w, inwb, NLAY * 2 * 2 * DI * DM);
    f2bf<<<(NLAY * 2 * 64 * DI) / 1024, 256, 0, stream>>>(xpw, xpwb, NLAY * 2 * 64 * DI);
    f2bf<<<(NLAY * 2 * DM * DI) / 1024, 256, 0, stream>>>(outw, outwb, NLAY * 2 * DM * DI);
    f2bf<<<(NLAY * DFF * DM) / 1024, 256, 0, stream>>>(fw1, fw1b, NLAY * DFF * DM);
    f2bf<<<(NLAY * DM * DFF) / 1024, 256, 0, stream>>>(fw2, fw2b, NLAY * DM * DFF);
    f2bf<<<(Hh * DM) / 1024, 256, 0, stream>>>(hw, hwb, Hh * DM);

    revin_stats<<<Bb, NV, 0, stream>>>(x, MU, SD);
    transpose_norm<<<dim3(Ll / 32, NV / 32, Bb), dim3(32, 8), 0, stream>>>(x, MU, SD, XNTb);
    gemm_mfma<0, false, false, false, false><<<dim3(MROWS / 128, DM / 128), 256, 0, stream>>>(
        XNTb, Ll, tokwb, tokb, T, DM, MROWS, DM, Ll);

    for (int l = 0; l < NLAY; l++) {
        ln_rows<<<MROWS, DM, 0, stream>>>(T, mnw + l * DM, mnb + l * DM, YNb);
        for (int dir = 0; dir < 2; dir++) {
            int pd = l * 2 + dir;
            const bf16* iw = inwb + (size_t)pd * 2 * DI * DM;
            const float* ib = in_b + (size_t)pd * 2 * DI;
            if (dir == 0)
                gemm_mfma<0, false, false, false, false><<<dim3(MROWS / 128, (2 * DI) / 128), 256, 0, stream>>>(
                    YNb, DM, iw, ib, XZ, 2 * DI, MROWS, 2 * DI, DM);
            else
                gemm_mfma<0, false, true, false, false><<<dim3(MROWS / 128, (2 * DI) / 128), 256, 0, stream>>>(
                    YNb, DM, iw, ib, XZ, 2 * DI, MROWS, 2 * DI, DM);
            conv_silu<<<dim3(DI / 256, Ss / 16, Bb), 256, 0, stream>>>(
                XZ, convw + (size_t)pd * DI * DCONV, convb + pd * DI, U, Ub);
            gemm_mfma<0, false, false, false, false><<<dim3(MROWS / 128, 1), 256, 0, stream>>>(
                Ub, DI, xpwb + (size_t)pd * 64 * DI, nullptr, XD, 64, MROWS, 64, DI);
            gemm_awt<2, false, false, false><<<dim3(MROWS / 64, DI / 64), 256, 0, stream>>>(
                XD, 64, dtw + (size_t)pd * DI * DTR, dtb + pd * DI, DEL, DI, MROWS, DI, DTR);
            scan_pass1<<<dim3(DI / 256, NCH, Bb), 256, 0, stream>>>(
                DEL, U, XD, Alog + (size_t)pd * DI * DS, PB, HB);
            scan_pass2<<<(Bb * DS * DI) / 256, 256, 0, stream>>>(PB, HB, HIN);
            scan_pass3<<<dim3(DI / 256, NCH, Bb), 256, 0, stream>>>(
                DEL, U, XD, XZ, Alog + (size_t)pd * DI * DS, Dm + pd * DI, HIN, Yb);
            if (dir == 0)
                gemm_mfma<0, true, false, false, false><<<dim3(MROWS / 128, DM / 128), 256, 0, stream>>>(
                    Yb, DI, outwb + (size_t)pd * DM * DI, outb + pd * DM, T, DM, MROWS, DM, DI);
            else
                gemm_mfma<0, true, false, true, false><<<dim3(MROWS / 128, DM / 128), 256, 0, stream>>>(
                    Yb, DI, outwb + (size_t)pd * DM * DI, outb + pd * DM, T, DM, MROWS, DM, DI);
        }
        // FFN
        ln_rows<<<MROWS, DM, 0, stream>>>(T, fnw + l * DM, fnb + l * DM, YNb);
        gemm_mfma<1, false, false, false, true><<<dim3(MROWS / 128, DFF / 128), 256, 0, stream>>>(
            YNb, DM, fw1b + (size_t)l * DFF * DM, fb1 + l * DFF, XZb, DFF, MROWS, DFF, DM);
        gemm_mfma<0, true, false, false, false><<<dim3(MROWS / 128, DM / 128), 256, 0, stream>>>(
            XZb, DFF, fw2b + (size_t)l * DM * DFF, fb2 + l * DM, T, DM, MROWS, DM, DFF);
    }
    ln_rows<<<MROWS, DM, 0, stream>>>(T, nw, nb, YNb);
    gemm_mfma<0, false, false, false, false><<<dim3(MROWS / 128, 1), 256, 0, stream>>>(
        YNb, DM, hwb, hb, PRED, Hh, MROWS, Hh, DM);
    finalize_out<<<dim3(Hh, Bb), NV, 0, stream>>>(PRED, MU, SD, (float*)d_out);
}

// Round 4
// 1562.782 us; speedup vs baseline: 3.1075x; 1.0051x over previous
//
#include <hip/hip_runtime.h>
#include <hip/hip_bf16.h>

#define Bb 16
#define Ll 512
#define NV 512
#define DM 512
#define DS 16
#define NLAY 2
#define DFF 2048
#define DI 1024
#define DCONV 4
#define DTR 32
#define Hh 96
#define Ss NV
#define MROWS (Bb*Ss)
#define EPSf 1e-5f
#define CH 32
#define NCH (Ss/CH)

typedef __hip_bfloat16 bf16;
typedef __attribute__((ext_vector_type(8))) short bf16x8;
typedef __attribute__((ext_vector_type(4))) float f32x4;

#define GLL16(g, l) __builtin_amdgcn_global_load_lds( \
    (const __attribute__((address_space(1))) unsigned int*)(g), \
    (__attribute__((address_space(3))) unsigned int*)(l), 16, 0, 0)

// ---------------- fp32 -> bf16 convert ----------------
__global__ void f2bf(const float* __restrict__ in, bf16* __restrict__ out, int n) {
    int i = (blockIdx.x * 256 + threadIdx.x) * 4;
    if (i < n) {
        float4 v = *(const float4*)(in + i);
        out[i + 0] = __float2bfloat16(v.x);
        out[i + 1] = __float2bfloat16(v.y);
        out[i + 2] = __float2bfloat16(v.z);
        out[i + 3] = __float2bfloat16(v.w);
    }
}

// ---------------- RevIN stats ----------------
__global__ void revin_stats(const float* __restrict__ x, float* __restrict__ mu, float* __restrict__ sd) {
    int b = blockIdx.x, n = threadIdx.x;
    const float* xp = x + (size_t)b * Ll * NV + n;
    float s1 = 0.f, s2 = 0.f;
    for (int l = 0; l < Ll; l++) { float v = xp[(size_t)l * NV]; s1 += v; s2 += v * v; }
    float m = s1 / Ll;
    float var = s2 / Ll - m * m;
    mu[b * NV + n] = m;
    sd[b * NV + n] = sqrtf(var + EPSf);
}

// ------------- normalize + transpose -> bf16: xnT[b,n,l] -------------
__global__ void transpose_norm(const float* __restrict__ x, const float* __restrict__ mu,
                               const float* __restrict__ sd, bf16* __restrict__ xnT) {
    __shared__ float t[32][33];
    int b = blockIdx.z;
    int l0 = blockIdx.x * 32, n0 = blockIdx.y * 32;
    int tx = threadIdx.x, ty = threadIdx.y; // 32x8
    #pragma unroll
    for (int q = 0; q < 4; q++)
        t[ty + q * 8][tx] = x[(size_t)b * Ll * NV + (size_t)(l0 + ty + q * 8) * NV + n0 + tx];
    __syncthreads();
    #pragma unroll
    for (int q = 0; q < 4; q++) {
        int n = n0 + ty + q * 8;
        float m = mu[b * NV + n], s = sd[b * NV + n];
        xnT[(size_t)b * NV * Ll + (size_t)n * Ll + l0 + tx] = __float2bfloat16((t[tx][ty + q * 8] - m) / s);
    }
}

// ---------------- LayerNorm over rows of DM -> bf16 ----------------
__global__ void ln_rows(const float* __restrict__ in, const float* __restrict__ w,
                        const float* __restrict__ bvec, bf16* __restrict__ out) {
    int row = blockIdx.x;
    int tid = threadIdx.x;
    float v = in[(size_t)row * DM + tid];
    float s1 = v, s2 = v * v;
    #pragma unroll
    for (int o = 32; o > 0; o >>= 1) { s1 += __shfl_down(s1, o, 64); s2 += __shfl_down(s2, o, 64); }
    __shared__ float l1[8], l2[8];
    int wv = tid >> 6, ln = tid & 63;
    if (ln == 0) { l1[wv] = s1; l2[wv] = s2; }
    __syncthreads();
    if (tid == 0) {
        float a = 0.f, c = 0.f;
        #pragma unroll
        for (int i = 0; i < DM / 64; i++) { a += l1[i]; c += l2[i]; }
        l1[0] = a; l2[0] = c;
    }
    __syncthreads();
    float mean = l1[0] / DM;
    float var = l2[0] / DM - mean * mean;
    float inv = rsqrtf(var + EPSf);
    out[(size_t)row * DM + tid] = __float2bfloat16((v - mean) * inv * w[tid] + bvec[tid]);
}

// ---------------- MFMA GEMM: C = A(M,K) @ W(N,K)^T + bias ----------------
// A, W bf16 (K-contiguous). C fp32 or bf16 (OUTBF). EPI: 0 none, 1 gelu.
// REVA/REVC: reverse rows within 512-blocks. Tile 128x128, BK=32, 4 waves.
template<int EPI, bool ACC, bool REVA, bool REVC, bool OUTBF>
__global__ __launch_bounds__(256) void gemm_mfma(
    const bf16* __restrict__ A, int lda,
    const bf16* __restrict__ W,
    const float* __restrict__ bias,
    void* __restrict__ Cv, int ldc,
    int M, int Nn, int K) {
    __shared__ bf16 As[128 * 32];
    __shared__ bf16 Bs[128 * 32];
    int m0 = blockIdx.x * 128, n0 = blockIdx.y * 128;
    int tid = threadIdx.x;
    int w = tid >> 6, lane = tid & 63;
    int wm = (w >> 1) * 64, wn = (w & 1) * 64;
    f32x4 acc[4][4] = {};

    // staging: wave w stages rows [w*32, w*32+32) of each tile, 2 instrs each
    int srow = w * 32 + (lane >> 2);
    int scol = (lane & 3) * 16;                 // bytes within 64B row
    long arow0 = m0 + srow, arow1 = m0 + srow + 16;
    if (REVA) {
        arow0 = (arow0 & ~511L) | (511 - (arow0 & 511));
        arow1 = (arow1 & ~511L) | (511 - (arow1 & 511));
    }
    const char* agp0 = (const char*)(A + arow0 * (long)lda) + scol;
    const char* agp1 = (const char*)(A + arow1 * (long)lda) + scol;
    long wrow0 = n0 + srow;      if (wrow0 >= Nn) wrow0 = Nn - 1;
    long wrow1 = n0 + srow + 16; if (wrow1 >= Nn) wrow1 = Nn - 1;
    const char* wgp0 = (const char*)(W + wrow0 * (long)K) + scol;
    const char* wgp1 = (const char*)(W + wrow1 * (long)K) + scol;

    char* lA0 = (char*)&As[(w * 32) * 32];
    char* lA1 = (char*)&As[(w * 32 + 16) * 32];
    char* lB0 = (char*)&Bs[(w * 32) * 32];
    char* lB1 = (char*)&Bs[(w * 32 + 16) * 32];

    int lrow = lane & 15, lk = (lane >> 4) * 16; // frag read: row, byte offset

    for (int k0 = 0; k0 < K; k0 += 32) {
        GLL16(agp0, lA0);
        GLL16(agp1, lA1);
        GLL16(wgp0, lB0);
        GLL16(wgp1, lB1);
        agp0 += 64; agp1 += 64; wgp0 += 64; wgp1 += 64;
        __syncthreads();
        bf16x8 af[4], bfr[4];
        #pragma unroll
        for (int i = 0; i < 4; i++) {
            af[i]  = *(const bf16x8*)((const char*)&As[(wm + i * 16 + lrow) * 32] + lk);
            bfr[i] = *(const bf16x8*)((const char*)&Bs[(wn + i * 16 + lrow) * 32] + lk);
        }
        #pragma unroll
        for (int i = 0; i < 4; i++)
            #pragma unroll
            for (int j = 0; j < 4; j++)
                acc[i][j] = __builtin_amdgcn_mfma_f32_16x16x32_bf16(af[i], bfr[j], acc[i][j], 0, 0, 0);
        __syncthreads();
    }

    #pragma unroll
    for (int i = 0; i < 4; i++) {
        #pragma unroll
        for (int j = 0; j < 4; j++) {
            int n = n0 + wn + j * 16 + (lane & 15);
            if (n >= Nn) continue;
            float bv = bias ? bias[n] : 0.f;
            #pragma unroll
            for (int r = 0; r < 4; r++) {
                int m = m0 + wm + i * 16 + (lane >> 4) * 4 + r;
                float v = acc[i][j][r] + bv;
                if (EPI == 1) {
                    float x3 = v * v * v;
                    v = 0.5f * v * (1.f + tanhf(0.7978845608028654f * (v + 0.044715f * x3)));
                }
                long mc = REVC ? ((m & ~511) | (511 - (m & 511))) : m;
                if (OUTBF) {
                    ((bf16*)Cv)[mc * (long)ldc + n] = __float2bfloat16(v);
                } else if (ACC) {
                    ((float*)Cv)[mc * (long)ldc + n] += v;
                } else {
                    ((float*)Cv)[mc * (long)ldc + n] = v;
                }
            }
        }
    }
}

// ---------------- fp32 GEMM (kept for dt-proj, K=32) ----------------
template<int EPI, bool ACC, bool REVA, bool REVC>
__global__ __launch_bounds__(256) void gemm_awt(
    const float* __restrict__ A, int lda,
    const float* __restrict__ W,
    const float* __restrict__ bias,
    float* __restrict__ C, int ldc,
    int M, int Nn, int K) {
    __shared__ float Asm[16][68];
    __shared__ float Wsm[16][68];
    int m0 = blockIdx.x * 64;
    int n0 = blockIdx.y * 64;
    int tid = threadIdx.x;
    int tm = (tid / 16) * 4, tn = (tid % 16) * 4;
    float acc[4][4] = {};
    int lr = tid / 4;
    int lk = (tid % 4) * 4;
    int arow = m0 + lr;
    if (REVA) arow = (arow & ~(Ss - 1)) | ((Ss - 1) - (arow & (Ss - 1)));
    const float* aptr = A + (size_t)arow * lda + lk;
    int wrow = n0 + lr;
    bool wok = wrow < Nn;
    const float* wptr = W + (size_t)wrow * K + lk;
    for (int k0 = 0; k0 < K; k0 += 16) {
        float4 av = *(const float4*)(aptr + k0);
        float4 wv = wok ? *(const float4*)(wptr + k0) : make_float4(0.f, 0.f, 0.f, 0.f);
        Asm[lk + 0][lr] = av.x; Asm[lk + 1][lr] = av.y; Asm[lk + 2][lr] = av.z; Asm[lk + 3][lr] = av.w;
        Wsm[lk + 0][lr] = wv.x; Wsm[lk + 1][lr] = wv.y; Wsm[lk + 2][lr] = wv.z; Wsm[lk + 3][lr] = wv.w;
        __syncthreads();
        #pragma unroll
        for (int kk = 0; kk < 16; kk++) {
            float4 a = *(const float4*)&Asm[kk][tm];
            float4 wv2 = *(const float4*)&Wsm[kk][tn];
            float ar[4] = {a.x, a.y, a.z, a.w};
            float wr[4] = {wv2.x, wv2.y, wv2.z, wv2.w};
            #pragma unroll
            for (int i = 0; i < 4; i++)
                #pragma unroll
                for (int j = 0; j < 4; j++)
                    acc[i][j] = fmaf(ar[i], wr[j], acc[i][j]);
        }
        __syncthreads();
    }
    #pragma unroll
    for (int i = 0; i < 4; i++) {
        int m = m0 + tm + i;
        int mc = REVC ? ((m & ~(Ss - 1)) | ((Ss - 1) - (m & (Ss - 1)))) : m;
        #pragma unroll
        for (int j = 0; j < 4; j++) {
            int n = n0 + tn + j;
            if (n < Nn) {
                float r = acc[i][j];
                if (bias) r += bias[n];
                if (EPI == 1) {
                    float x3 = r * r * r;
                    r = 0.5f * r * (1.f + tanhf(0.7978845608028654f * (r + 0.044715f * x3)));
                } else if (EPI == 2) {
                    r = fmaxf(r, 0.f) + log1pf(expf(-fabsf(r)));
                }
                if (ACC) C[(size_t)mc * ldc + n] += r;
                else     C[(size_t)mc * ldc + n] = r;
            }
        }
    }
}

// ---------------- causal depthwise conv (k=4) + silu, dual output ----------------
__global__ void conv_silu(const float* __restrict__ xz, const float* __restrict__ cw,
                          const float* __restrict__ cb, float* __restrict__ u,
                          bf16* __restrict__ ub) {
    int c = blockIdx.x * 256 + threadIdx.x;
    int s0 = blockIdx.y * 16;
    int b = blockIdx.z;
    const float* src = xz + (size_t)b * Ss * (2 * DI) + c;
    float w0 = cw[c * 4 + 0], w1 = cw[c * 4 + 1], w2 = cw[c * 4 + 2], w3 = cw[c * 4 + 3];
    float bias = cb[c];
    float r0 = (s0 - 3 >= 0) ? src[(size_t)(s0 - 3) * (2 * DI)] : 0.f;
    float r1 = (s0 - 2 >= 0) ? src[(size_t)(s0 - 2) * (2 * DI)] : 0.f;
    float r2 = (s0 - 1 >= 0) ? src[(size_t)(s0 - 1) * (2 * DI)] : 0.f;
    for (int i = 0; i < 16; i++) {
        int s = s0 + i;
        float r3 = src[(size_t)s * (2 * DI)];
        float a = fmaf(r0, w0, fmaf(r1, w1, fmaf(r2, w2, fmaf(r3, w3, bias))));
        float v = a / (1.f + expf(-a));
        u[((size_t)b * Ss + s) * DI + c] = v;
        ub[((size_t)b * Ss + s) * DI + c] = __float2bfloat16(v);
        r0 = r1; r1 = r2; r2 = r3;
    }
}

// ======== chunked parallel selective scan ========
__global__ __launch_bounds__(256) void scan_pass1(
    const float* __restrict__ delta, const float* __restrict__ u,
    const float* __restrict__ xdbl, const float* __restrict__ A_log,
    float* __restrict__ PB, float* __restrict__ HB) {
    int d = blockIdx.x * 256 + threadIdx.x;
    int c = blockIdx.y;
    int b = blockIdx.z;
    float Aj[DS], P[DS], h[DS];
    #pragma unroll
    for (int j = 0; j < DS; j++) { Aj[j] = -expf(A_log[(size_t)d * DS + j]); P[j] = 1.f; h[j] = 0.f; }
    const float* dp = delta + ((size_t)b * Ss + c * CH) * DI + d;
    const float* up = u + ((size_t)b * Ss + c * CH) * DI + d;
    const float* bc = xdbl + ((size_t)b * Ss + c * CH) * 64 + DTR;
    for (int i = 0; i < CH; i++) {
        float dl = dp[(size_t)i * DI];
        float ut = up[(size_t)i * DI];
        float du = dl * ut;
        const float4* q4 = (const float4*)(bc + (size_t)i * 64);
        float4 B0 = q4[0], B1 = q4[1], B2 = q4[2], B3 = q4[3];
        float Bv[DS] = {B0.x, B0.y, B0.z, B0.w, B1.x, B1.y, B1.z, B1.w,
                        B2.x, B2.y, B2.z, B2.w, B3.x, B3.y, B3.z, B3.w};
        #pragma unroll
        for (int j = 0; j < DS; j++) {
            float a = expf(dl * Aj[j]);
            P[j] *= a;
            h[j] = fmaf(a, h[j], du * Bv[j]);
        }
    }
    size_t base = ((size_t)(b * NCH + c)) * DS * DI + d;
    #pragma unroll
    for (int j = 0; j < DS; j++) {
        PB[base + (size_t)j * DI] = P[j];
        HB[base + (size_t)j * DI] = h[j];
    }
}

__global__ __launch_bounds__(256) void scan_pass2(
    const float* __restrict__ PB, const float* __restrict__ HB, float* __restrict__ HIN) {
    int idx = blockIdx.x * 256 + threadIdx.x;
    int b = idx >> 14;
    int rem = idx & 16383;
    float h = 0.f;
    #pragma unroll
    for (int c = 0; c < NCH; c++) {
        size_t o = ((size_t)(b * NCH + c)) * (DS * DI) + rem;
        float p = PB[o], hl = HB[o];
        HIN[o] = h;
        h = fmaf(p, h, hl);
    }
}

__global__ __launch_bounds__(256) void scan_pass3(
    const float* __restrict__ delta, const float* __restrict__ u,
    const float* __restrict__ xdbl, const float* __restrict__ xz,
    const float* __restrict__ A_log, const float* __restrict__ Dp,
    const float* __restrict__ HIN, bf16* __restrict__ y) {
    int d = blockIdx.x * 256 + threadIdx.x;
    int c = blockIdx.y;
    int b = blockIdx.z;
    float Aj[DS], h[DS];
    size_t hbase = ((size_t)(b * NCH + c)) * DS * DI + d;
    #pragma unroll
    for (int j = 0; j < DS; j++) {
        Aj[j] = -expf(A_log[(size_t)d * DS + j]);
        h[j] = HIN[hbase + (size_t)j * DI];
    }
    float Dd = Dp[d];
    const float* dp = delta + ((size_t)b * Ss + c * CH) * DI + d;
    const float* up = u + ((size_t)b * Ss + c * CH) * DI + d;
    const float* zp = xz + ((size_t)b * Ss + c * CH) * (2 * DI) + DI + d;
    const float* bc = xdbl + ((size_t)b * Ss + c * CH) * 64 + DTR;
    bf16* yp = y + ((size_t)b * Ss + c * CH) * DI + d;
    for (int i = 0; i < CH; i++) {
        float dl = dp[(size_t)i * DI];
        float ut = up[(size_t)i * DI];
        float zz = zp[(size_t)i * (2 * DI)];
        float du = dl * ut;
        const float4* q4 = (const float4*)(bc + (size_t)i * 64);
        float4 B0 = q4[0], B1 = q4[1], B2 = q4[2], B3 = q4[3];
        float4 C0 = q4[4], C1 = q4[5], C2 = q4[6], C3 = q4[7];
        float Bv[DS] = {B0.x, B0.y, B0.z, B0.w, B1.x, B1.y, B1.z, B1.w,
                        B2.x, B2.y, B2.z, B2.w, B3.x, B3.y, B3.z, B3.w};
        float Cv[DS] = {C0.x, C0.y, C0.z, C0.w, C1.x, C1.y, C1.z, C1.w,
                        C2.x, C2.y, C2.z, C2.w, C3.x, C3.y, C3.z, C3.w};
        float acc = 0.f;
        #pragma unroll
        for (int j = 0; j < DS; j++) {
            float a = expf(dl * Aj[j]);
            h[j] = fmaf(a, h[j], du * Bv[j]);
            acc = fmaf(h[j], Cv[j], acc);
        }
        float sg = 1.f / (1.f + expf(-zz));
        yp[(size_t)i * DI] = __float2bfloat16((acc + ut * Dd) * (zz * sg));
    }
}

// ---------------- final: out[b,h,n] = pred[b,n,h]*sd + mu ----------------
__global__ void finalize_out(const float* __restrict__ pred, const float* __restrict__ mu,
                             const float* __restrict__ sd, float* __restrict__ out) {
    int n = threadIdx.x;
    int h = blockIdx.x;
    int b = blockIdx.y;
    out[((size_t)b * Hh + h) * NV + n] =
        pred[((size_t)b * NV + n) * Hh + h] * sd[b * NV + n] + mu[b * NV + n];
}

extern "C" void kernel_launch(void* const* d_in, const int* in_sizes, int n_in,
                              void* d_out, int out_size, void* d_ws, size_t ws_size,
                              hipStream_t stream) {
    const float* x     = (const float*)d_in[0];
    const float* tokw  = (const float*)d_in[1];
    const float* tokb  = (const float*)d_in[2];
    const float* in_w  = (const float*)d_in[3];
    const float* in_b  = (const float*)d_in[4];
    const float* convw = (const float*)d_in[5];
    const float* convb = (const float*)d_in[6];
    const float* xpw   = (const float*)d_in[7];
    const float* dtw   = (const float*)d_in[8];
    const float* dtb   = (const float*)d_in[9];
    const float* Alog  = (const float*)d_in[10];
    const float* Dm    = (const float*)d_in[11];
    const float* outw  = (const float*)d_in[12];
    const float* outb  = (const float*)d_in[13];
    const float* mnw   = (const float*)d_in[14];
    const float* mnb   = (const float*)d_in[15];
    const float* fnw   = (const float*)d_in[16];
    const float* fnb   = (const float*)d_in[17];
    const float* fw1   = (const float*)d_in[18];
    const float* fb1   = (const float*)d_in[19];
    const float* fw2   = (const float*)d_in[20];
    const float* fb2   = (const float*)d_in[21];
    const float* nw    = (const float*)d_in[22];
    const float* nb    = (const float*)d_in[23];
    const float* hw    = (const float*)d_in[24];
    const float* hb    = (const float*)d_in[25];

    float* ws = (float*)d_ws;
    float* MU  = ws;                            // B*NV
    float* SD  = MU + Bb * NV;                  // B*NV
    float* XNT = SD + Bb * NV;                  // 4M floats region (XNTb bf16 / HIN fp32)
    float* T   = XNT + (size_t)Bb * NV * Ll;    // B*NV*DM fp32
    float* YN  = T + (size_t)Bb * NV * DM;      // region (YNb bf16)
    float* XZ  = YN + (size_t)Bb * NV * DM;     // MROWS*2DI fp32 (XZb bf16 in FFN phase)
    float* U   = XZ + (size_t)MROWS * 2 * DI;   // MROWS*DI fp32
    float* XD  = U + (size_t)MROWS * DI;        // MROWS*64 fp32
    float* DEL = XD + (size_t)MROWS * 64;       // MROWS*DI fp32 (Ub bf16 pre-dt)
    float* Y   = DEL + (size_t)MROWS * DI;      // MROWS*DI region (PB/HB fp32, Yb bf16)
    float* PRED = Y + (size_t)MROWS * DI;       // MROWS*H fp32
    float* WBF  = PRED + (size_t)MROWS * Hh;    // bf16 weights region

    bf16* XNTb = (bf16*)XNT;
    bf16* YNb  = (bf16*)YN;
    bf16* XZb  = (bf16*)XZ;
    bf16* Ub   = (bf16*)DEL;
    bf16* Yb   = (bf16*)Y;
    float* PB  = Y;
    float* HB  = Y + (size_t)Bb * NCH * DS * DI;
    float* HIN = XNT;

    // bf16 weight copies
    bf16* wb = (bf16*)WBF;
    bf16* tokwb = wb;              wb += (size_t)DM * Ll;          // 262144
    bf16* inwb  = wb;              wb += (size_t)NLAY * 2 * 2 * DI * DM; // 4194304
    bf16* xpwb  = wb;              wb += (size_t)NLAY * 2 * 64 * DI;     // 262144
    bf16* outwb = wb;              wb += (size_t)NLAY * 2 * DM * DI;     // 2097152
    bf16* fw1b  = wb;              wb += (size_t)NLAY * DFF * DM;        // 2097152
    bf16* fw2b  = wb;              wb += (size_t)NLAY * DM * DFF;        // 2097152
    bf16* hwb   = wb;              wb += (size_t)Hh * DM;                // 49152

    f2bf<<<(DM * Ll) / 1024, 256, 0, stream>>>(tokw, tokwb, DM * Ll);
    f2bf<<<(NLAY * 2 * 2 * DI * DM) / 1024, 256, 0, stream>>>(in_w, inwb, NLAY * 2 * 2 * DI * DM);
    f2bf<<<(NLAY * 2 * 64 * DI) / 1024, 256, 0, stream>>>(xpw, xpwb, NLAY * 2 * 64 * DI);
    f2bf<<<(NLAY * 2 * DM * DI) / 1024, 256, 0, stream>>>(outw, outwb, NLAY * 2 * DM * DI);
    f2bf<<<(NLAY * DFF * DM) / 1024, 256, 0, stream>>>(fw1, fw1b, NLAY * DFF * DM);
    f2bf<<<(NLAY * DM * DFF) / 1024, 256, 0, stream>>>(fw2, fw2b, NLAY * DM * DFF);
    f2bf<<<(Hh * DM) / 1024, 256, 0, stream>>>(hw, hwb, Hh * DM);

    revin_stats<<<Bb, NV, 0, stream>>>(x, MU, SD);
    transpose_norm<<<dim3(Ll / 32, NV / 32, Bb), dim3(32, 8), 0, stream>>>(x, MU, SD, XNTb);
    gemm_mfma<0, false, false, false, false><<<dim3(MROWS / 128, DM / 128), 256, 0, stream>>>(
        XNTb, Ll, tokwb, tokb, T, DM, MROWS, DM, Ll);

    for (int l = 0; l < NLAY; l++) {
        ln_rows<<<MROWS, DM, 0, stream>>>(T, mnw + l * DM, mnb + l * DM, YNb);
        for (int dir = 0; dir < 2; dir++) {
            int pd = l * 2 + dir;
            const bf16* iw = inwb + (size_t)pd * 2 * DI * DM;
            const float* ib = in_b + (size_t)pd * 2 * DI;
            if (dir == 0)
                gemm_mfma<0, false, false, false, false><<<dim3(MROWS / 128, (2 * DI) / 128), 256, 0, stream>>>(
                    YNb, DM, iw, ib, XZ, 2 * DI, MROWS, 2 * DI, DM);
            else
                gemm_mfma<0, false, true, false, false><<<dim3(MROWS / 128, (2 * DI) / 128), 256, 0, stream>>>(
                    YNb, DM, iw, ib, XZ, 2 * DI, MROWS, 2 * DI, DM);
            conv_silu<<<dim3(DI / 256, Ss / 16, Bb), 256, 0, stream>>>(
                XZ, convw + (size_t)pd * DI * DCONV, convb + pd * DI, U, Ub);
            gemm_mfma<0, false, false, false, false><<<dim3(MROWS / 128, 1), 256, 0, stream>>>(
                Ub, DI, xpwb + (size_t)pd * 64 * DI, nullptr, XD, 64, MROWS, 64, DI);
            gemm_awt<2, false, false, false><<<dim3(MROWS / 64, DI / 64), 256, 0, stream>>>(
                XD, 64, dtw + (size_t)pd * DI * DTR, dtb + pd * DI, DEL, DI, MROWS, DI, DTR);
            scan_pass1<<<dim3(DI / 256, NCH, Bb), 256, 0, stream>>>(
                DEL, U, XD, Alog + (size_t)pd * DI * DS, PB, HB);
            scan_pass2<<<(Bb * DS * DI) / 256, 256, 0, stream>>>(PB, HB, HIN);
            scan_pass3<<<dim3(DI / 256, NCH, Bb), 256, 0, stream>>>(
                DEL, U, XD, XZ, Alog + (size_t)pd * DI * DS, Dm + pd * DI, HIN, Yb);
            if (dir == 0)
                gemm_mfma<0, true, false, false, false><<<dim3(MROWS / 128, DM / 128), 256, 0, stream>>>(
                    Yb, DI, outwb + (size_t)pd * DM * DI, outb + pd * DM, T, DM, MROWS, DM, DI);
            else
                gemm_mfma<0, true, false, true, false><<<dim3(MROWS / 128, DM / 128), 256, 0, stream>>>(
                    Yb, DI, outwb + (size_t)pd * DM * DI, outb + pd * DM, T, DM, MROWS, DM, DI);
        }
        // FFN
        ln_rows<<<MROWS, DM, 0, stream>>>(T, fnw + l * DM, fnb + l * DM, YNb);
        gemm_mfma<1, false, false, false, true><<<dim3(MROWS / 128, DFF / 128), 256, 0, stream>>>(
            YNb, DM, fw1b + (size_t)l * DFF * DM, fb1 + l * DFF, XZb, DFF, MROWS, DFF, DM);
        gemm_mfma<0, true, false, false, false><<<dim3(MROWS / 128, DM / 128), 256, 0, stream>>>(
            XZb, DFF, fw2b + (size_t)l * DM * DFF, fb2 + l * DM, T, DM, MROWS, DM, DFF);
    }
    ln_rows<<<MROWS, DM, 0, stream>>>(T, nw, nb, YNb);
    gemm_mfma<0, false, false, false, false><<<dim3(MROWS / 128, 1), 256, 0, stream>>>(
        YNb, DM, hwb, hb, PRED, Hh, MROWS, Hh, DM);
    finalize_out<<<dim3(Hh, Bb), NV, 0, stream>>>(PRED, MU, SD, (float*)d_out);
}

// Round 5
// 1209.580 us; speedup vs baseline: 4.0149x; 1.2920x over previous
//
#include <hip/hip_runtime.h>
#include <hip/hip_bf16.h>

#define Bb 16
#define Ll 512
#define NV 512
#define DM 512
#define DS 16
#define NLAY 2
#define DFF 2048
#define DI 1024
#define DCONV 4
#define DTR 32
#define Hh 96
#define Ss NV
#define MROWS (Bb*Ss)
#define EPSf 1e-5f
#define CH 32
#define NCH (Ss/CH)

typedef __hip_bfloat16 bf16;
typedef __attribute__((ext_vector_type(8))) short bf16x8;
typedef __attribute__((ext_vector_type(4))) float f32x4;

#define GLL16(g, l) __builtin_amdgcn_global_load_lds( \
    (const __attribute__((address_space(1))) unsigned int*)(g), \
    (__attribute__((address_space(3))) unsigned int*)(l), 16, 0, 0)

__device__ __forceinline__ float fast_exp(float x) { return __expf(x); }
__device__ __forceinline__ float fast_sig(float x) {
    return __builtin_amdgcn_rcpf(1.f + __expf(-x));
}
__device__ __forceinline__ float fast_softplus(float r) {
    float e = __expf(-fabsf(r));
    return fmaxf(r, 0.f) + __logf(1.f + e);
}

// ---------------- fp32 -> bf16 convert ----------------
__global__ void f2bf(const float* __restrict__ in, bf16* __restrict__ out, int n) {
    int i = (blockIdx.x * 256 + threadIdx.x) * 4;
    if (i < n) {
        float4 v = *(const float4*)(in + i);
        out[i + 0] = __float2bfloat16(v.x);
        out[i + 1] = __float2bfloat16(v.y);
        out[i + 2] = __float2bfloat16(v.z);
        out[i + 3] = __float2bfloat16(v.w);
    }
}

// ---------------- RevIN stats (two-stage) ----------------
__global__ void revin_partial(const float* __restrict__ x, float* __restrict__ ps1,
                              float* __restrict__ ps2) {
    int b = blockIdx.x, c = blockIdx.y, n = threadIdx.x;
    const float* xp = x + (size_t)b * Ll * NV + (size_t)c * (Ll / 8) * NV + n;
    float s1 = 0.f, s2 = 0.f;
    #pragma unroll 4
    for (int l = 0; l < Ll / 8; l++) { float v = xp[(size_t)l * NV]; s1 += v; s2 += v * v; }
    ps1[((size_t)b * 8 + c) * NV + n] = s1;
    ps2[((size_t)b * 8 + c) * NV + n] = s2;
}

__global__ void revin_final(const float* __restrict__ ps1, const float* __restrict__ ps2,
                            float* __restrict__ mu, float* __restrict__ sd) {
    int b = blockIdx.x, n = threadIdx.x;
    float s1 = 0.f, s2 = 0.f;
    #pragma unroll
    for (int c = 0; c < 8; c++) {
        s1 += ps1[((size_t)b * 8 + c) * NV + n];
        s2 += ps2[((size_t)b * 8 + c) * NV + n];
    }
    float m = s1 / Ll;
    float var = s2 / Ll - m * m;
    mu[b * NV + n] = m;
    sd[b * NV + n] = sqrtf(var + EPSf);
}

// ------------- normalize + transpose -> bf16: xnT[b,n,l] -------------
__global__ void transpose_norm(const float* __restrict__ x, const float* __restrict__ mu,
                               const float* __restrict__ sd, bf16* __restrict__ xnT) {
    __shared__ float t[32][33];
    int b = blockIdx.z;
    int l0 = blockIdx.x * 32, n0 = blockIdx.y * 32;
    int tx = threadIdx.x, ty = threadIdx.y; // 32x8
    #pragma unroll
    for (int q = 0; q < 4; q++)
        t[ty + q * 8][tx] = x[(size_t)b * Ll * NV + (size_t)(l0 + ty + q * 8) * NV + n0 + tx];
    __syncthreads();
    #pragma unroll
    for (int q = 0; q < 4; q++) {
        int n = n0 + ty + q * 8;
        float m = mu[b * NV + n], s = sd[b * NV + n];
        xnT[(size_t)b * NV * Ll + (size_t)n * Ll + l0 + tx] = __float2bfloat16((t[tx][ty + q * 8] - m) / s);
    }
}

// ---------------- LayerNorm over rows of DM -> bf16 ----------------
__global__ void ln_rows(const float* __restrict__ in, const float* __restrict__ w,
                        const float* __restrict__ bvec, bf16* __restrict__ out) {
    int row = blockIdx.x;
    int tid = threadIdx.x;
    float v = in[(size_t)row * DM + tid];
    float s1 = v, s2 = v * v;
    #pragma unroll
    for (int o = 32; o > 0; o >>= 1) { s1 += __shfl_down(s1, o, 64); s2 += __shfl_down(s2, o, 64); }
    __shared__ float l1[8], l2[8];
    int wv = tid >> 6, ln = tid & 63;
    if (ln == 0) { l1[wv] = s1; l2[wv] = s2; }
    __syncthreads();
    if (tid == 0) {
        float a = 0.f, c = 0.f;
        #pragma unroll
        for (int i = 0; i < DM / 64; i++) { a += l1[i]; c += l2[i]; }
        l1[0] = a; l2[0] = c;
    }
    __syncthreads();
    float mean = l1[0] / DM;
    float var = l2[0] / DM - mean * mean;
    float inv = rsqrtf(var + EPSf);
    out[(size_t)row * DM + tid] = __float2bfloat16((v - mean) * inv * w[tid] + bvec[tid]);
}

// ---------------- MFMA GEMM: C = A(M,K) @ W(N,K)^T + bias ----------------
template<int EPI, bool ACC, bool REVA, bool REVC, bool OUTBF>
__global__ __launch_bounds__(256) void gemm_mfma(
    const bf16* __restrict__ A, int lda,
    const bf16* __restrict__ W,
    const float* __restrict__ bias,
    void* __restrict__ Cv, int ldc,
    int M, int Nn, int K) {
    __shared__ bf16 As[128 * 32];
    __shared__ bf16 Bs[128 * 32];
    int m0 = blockIdx.x * 128, n0 = blockIdx.y * 128;
    int tid = threadIdx.x;
    int w = tid >> 6, lane = tid & 63;
    int wm = (w >> 1) * 64, wn = (w & 1) * 64;
    f32x4 acc[4][4] = {};

    int srow = w * 32 + (lane >> 2);
    int scol = (lane & 3) * 16;
    long arow0 = m0 + srow, arow1 = m0 + srow + 16;
    if (REVA) {
        arow0 = (arow0 & ~511L) | (511 - (arow0 & 511));
        arow1 = (arow1 & ~511L) | (511 - (arow1 & 511));
    }
    const char* agp0 = (const char*)(A + arow0 * (long)lda) + scol;
    const char* agp1 = (const char*)(A + arow1 * (long)lda) + scol;
    long wrow0 = n0 + srow;      if (wrow0 >= Nn) wrow0 = Nn - 1;
    long wrow1 = n0 + srow + 16; if (wrow1 >= Nn) wrow1 = Nn - 1;
    const char* wgp0 = (const char*)(W + wrow0 * (long)K) + scol;
    const char* wgp1 = (const char*)(W + wrow1 * (long)K) + scol;

    char* lA0 = (char*)&As[(w * 32) * 32];
    char* lA1 = (char*)&As[(w * 32 + 16) * 32];
    char* lB0 = (char*)&Bs[(w * 32) * 32];
    char* lB1 = (char*)&Bs[(w * 32 + 16) * 32];

    int lrow = lane & 15, lk = (lane >> 4) * 16;

    for (int k0 = 0; k0 < K; k0 += 32) {
        GLL16(agp0, lA0);
        GLL16(agp1, lA1);
        GLL16(wgp0, lB0);
        GLL16(wgp1, lB1);
        agp0 += 64; agp1 += 64; wgp0 += 64; wgp1 += 64;
        __syncthreads();
        bf16x8 af[4], bfr[4];
        #pragma unroll
        for (int i = 0; i < 4; i++) {
            af[i]  = *(const bf16x8*)((const char*)&As[(wm + i * 16 + lrow) * 32] + lk);
            bfr[i] = *(const bf16x8*)((const char*)&Bs[(wn + i * 16 + lrow) * 32] + lk);
        }
        #pragma unroll
        for (int i = 0; i < 4; i++)
            #pragma unroll
            for (int j = 0; j < 4; j++)
                acc[i][j] = __builtin_amdgcn_mfma_f32_16x16x32_bf16(af[i], bfr[j], acc[i][j], 0, 0, 0);
        __syncthreads();
    }

    #pragma unroll
    for (int i = 0; i < 4; i++) {
        #pragma unroll
        for (int j = 0; j < 4; j++) {
            int n = n0 + wn + j * 16 + (lane & 15);
            if (n >= Nn) continue;
            float bv = bias ? bias[n] : 0.f;
            #pragma unroll
            for (int r = 0; r < 4; r++) {
                int m = m0 + wm + i * 16 + (lane >> 4) * 4 + r;
                float v = acc[i][j][r] + bv;
                if (EPI == 1) {
                    float x3 = v * v * v;
                    v = 0.5f * v * (1.f + tanhf(0.7978845608028654f * (v + 0.044715f * x3)));
                }
                long mc = REVC ? ((m & ~511) | (511 - (m & 511))) : m;
                if (OUTBF) {
                    ((bf16*)Cv)[mc * (long)ldc + n] = __float2bfloat16(v);
                } else if (ACC) {
                    ((float*)Cv)[mc * (long)ldc + n] += v;
                } else {
                    ((float*)Cv)[mc * (long)ldc + n] = v;
                }
            }
        }
    }
}

// ---------------- fp32 GEMM (dt-proj, K=32) ----------------
template<int EPI, bool ACC, bool REVA, bool REVC>
__global__ __launch_bounds__(256) void gemm_awt(
    const float* __restrict__ A, int lda,
    const float* __restrict__ W,
    const float* __restrict__ bias,
    float* __restrict__ C, int ldc,
    int M, int Nn, int K) {
    __shared__ float Asm[16][68];
    __shared__ float Wsm[16][68];
    int m0 = blockIdx.x * 64;
    int n0 = blockIdx.y * 64;
    int tid = threadIdx.x;
    int tm = (tid / 16) * 4, tn = (tid % 16) * 4;
    float acc[4][4] = {};
    int lr = tid / 4;
    int lk = (tid % 4) * 4;
    int arow = m0 + lr;
    if (REVA) arow = (arow & ~(Ss - 1)) | ((Ss - 1) - (arow & (Ss - 1)));
    const float* aptr = A + (size_t)arow * lda + lk;
    int wrow = n0 + lr;
    bool wok = wrow < Nn;
    const float* wptr = W + (size_t)wrow * K + lk;
    for (int k0 = 0; k0 < K; k0 += 16) {
        float4 av = *(const float4*)(aptr + k0);
        float4 wv = wok ? *(const float4*)(wptr + k0) : make_float4(0.f, 0.f, 0.f, 0.f);
        Asm[lk + 0][lr] = av.x; Asm[lk + 1][lr] = av.y; Asm[lk + 2][lr] = av.z; Asm[lk + 3][lr] = av.w;
        Wsm[lk + 0][lr] = wv.x; Wsm[lk + 1][lr] = wv.y; Wsm[lk + 2][lr] = wv.z; Wsm[lk + 3][lr] = wv.w;
        __syncthreads();
        #pragma unroll
        for (int kk = 0; kk < 16; kk++) {
            float4 a = *(const float4*)&Asm[kk][tm];
            float4 wv2 = *(const float4*)&Wsm[kk][tn];
            float ar[4] = {a.x, a.y, a.z, a.w};
            float wr[4] = {wv2.x, wv2.y, wv2.z, wv2.w};
            #pragma unroll
            for (int i = 0; i < 4; i++)
                #pragma unroll
                for (int j = 0; j < 4; j++)
                    acc[i][j] = fmaf(ar[i], wr[j], acc[i][j]);
        }
        __syncthreads();
    }
    #pragma unroll
    for (int i = 0; i < 4; i++) {
        int m = m0 + tm + i;
        int mc = REVC ? ((m & ~(Ss - 1)) | ((Ss - 1) - (m & (Ss - 1)))) : m;
        #pragma unroll
        for (int j = 0; j < 4; j++) {
            int n = n0 + tn + j;
            if (n < Nn) {
                float r = acc[i][j];
                if (bias) r += bias[n];
                if (EPI == 1) {
                    float x3 = r * r * r;
                    r = 0.5f * r * (1.f + tanhf(0.7978845608028654f * (r + 0.044715f * x3)));
                } else if (EPI == 2) {
                    r = fast_softplus(r);
                }
                if (ACC) C[(size_t)mc * ldc + n] += r;
                else     C[(size_t)mc * ldc + n] = r;
            }
        }
    }
}

// ---------------- causal depthwise conv (k=4) + silu, dual output ----------------
__global__ void conv_silu(const float* __restrict__ xz, const float* __restrict__ cw,
                          const float* __restrict__ cb, float* __restrict__ u,
                          bf16* __restrict__ ub) {
    int c = blockIdx.x * 256 + threadIdx.x;
    int s0 = blockIdx.y * 16;
    int b = blockIdx.z;
    const float* src = xz + (size_t)b * Ss * (2 * DI) + c;
    float w0 = cw[c * 4 + 0], w1 = cw[c * 4 + 1], w2 = cw[c * 4 + 2], w3 = cw[c * 4 + 3];
    float bias = cb[c];
    float r0 = (s0 - 3 >= 0) ? src[(size_t)(s0 - 3) * (2 * DI)] : 0.f;
    float r1 = (s0 - 2 >= 0) ? src[(size_t)(s0 - 2) * (2 * DI)] : 0.f;
    float r2 = (s0 - 1 >= 0) ? src[(size_t)(s0 - 1) * (2 * DI)] : 0.f;
    for (int i = 0; i < 16; i++) {
        int s = s0 + i;
        float r3 = src[(size_t)s * (2 * DI)];
        float a = fmaf(r0, w0, fmaf(r1, w1, fmaf(r2, w2, fmaf(r3, w3, bias))));
        float v = a * fast_sig(a);
        u[((size_t)b * Ss + s) * DI + c] = v;
        ub[((size_t)b * Ss + s) * DI + c] = __float2bfloat16(v);
        r0 = r1; r1 = r2; r2 = r3;
    }
}

// ======== chunked parallel selective scan ========
__global__ __launch_bounds__(256) void scan_pass1(
    const float* __restrict__ delta, const float* __restrict__ u,
    const float* __restrict__ xdbl, const float* __restrict__ A_log,
    float* __restrict__ PB, float* __restrict__ HB) {
    int d = blockIdx.x * 256 + threadIdx.x;
    int c = blockIdx.y;
    int b = blockIdx.z;
    float Aj[DS], h[DS];
    #pragma unroll
    for (int j = 0; j < DS; j++) { Aj[j] = -fast_exp(A_log[(size_t)d * DS + j]); h[j] = 0.f; }
    const float* dp = delta + ((size_t)b * Ss + c * CH) * DI + d;
    const float* up = u + ((size_t)b * Ss + c * CH) * DI + d;
    const float* bc = xdbl + ((size_t)b * Ss + c * CH) * 64 + DTR;
    float dlsum = 0.f;
    for (int i = 0; i < CH; i++) {
        float dl = dp[(size_t)i * DI];
        float ut = up[(size_t)i * DI];
        float du = dl * ut;
        dlsum += dl;
        const float4* q4 = (const float4*)(bc + (size_t)i * 64);
        float4 B0 = q4[0], B1 = q4[1], B2 = q4[2], B3 = q4[3];
        float Bv[DS] = {B0.x, B0.y, B0.z, B0.w, B1.x, B1.y, B1.z, B1.w,
                        B2.x, B2.y, B2.z, B2.w, B3.x, B3.y, B3.z, B3.w};
        #pragma unroll
        for (int j = 0; j < DS; j++) {
            float a = fast_exp(dl * Aj[j]);
            h[j] = fmaf(a, h[j], du * Bv[j]);
        }
    }
    size_t base = ((size_t)(b * NCH + c)) * DS * DI + d;
    #pragma unroll
    for (int j = 0; j < DS; j++) {
        PB[base + (size_t)j * DI] = fast_exp(dlsum * Aj[j]);  // prod of exps = exp of sum
        HB[base + (size_t)j * DI] = h[j];
    }
}

__global__ __launch_bounds__(256) void scan_pass2(
    const float* __restrict__ PB, const float* __restrict__ HB, float* __restrict__ HIN) {
    int idx = blockIdx.x * 256 + threadIdx.x;
    int b = idx >> 14;
    int rem = idx & 16383;
    float h = 0.f;
    #pragma unroll
    for (int c = 0; c < NCH; c++) {
        size_t o = ((size_t)(b * NCH + c)) * (DS * DI) + rem;
        float p = PB[o], hl = HB[o];
        HIN[o] = h;
        h = fmaf(p, h, hl);
    }
}

__global__ __launch_bounds__(256) void scan_pass3(
    const float* __restrict__ delta, const float* __restrict__ u,
    const float* __restrict__ xdbl, const float* __restrict__ xz,
    const float* __restrict__ A_log, const float* __restrict__ Dp,
    const float* __restrict__ HIN, bf16* __restrict__ y) {
    int d = blockIdx.x * 256 + threadIdx.x;
    int c = blockIdx.y;
    int b = blockIdx.z;
    float Aj[DS], h[DS];
    size_t hbase = ((size_t)(b * NCH + c)) * DS * DI + d;
    #pragma unroll
    for (int j = 0; j < DS; j++) {
        Aj[j] = -fast_exp(A_log[(size_t)d * DS + j]);
        h[j] = HIN[hbase + (size_t)j * DI];
    }
    float Dd = Dp[d];
    const float* dp = delta + ((size_t)b * Ss + c * CH) * DI + d;
    const float* up = u + ((size_t)b * Ss + c * CH) * DI + d;
    const float* zp = xz + ((size_t)b * Ss + c * CH) * (2 * DI) + DI + d;
    const float* bc = xdbl + ((size_t)b * Ss + c * CH) * 64 + DTR;
    bf16* yp = y + ((size_t)b * Ss + c * CH) * DI + d;
    for (int i = 0; i < CH; i++) {
        float dl = dp[(size_t)i * DI];
        float ut = up[(size_t)i * DI];
        float zz = zp[(size_t)i * (2 * DI)];
        float du = dl * ut;
        const float4* q4 = (const float4*)(bc + (size_t)i * 64);
        float4 B0 = q4[0], B1 = q4[1], B2 = q4[2], B3 = q4[3];
        float4 C0 = q4[4], C1 = q4[5], C2 = q4[6], C3 = q4[7];
        float Bv[DS] = {B0.x, B0.y, B0.z, B0.w, B1.x, B1.y, B1.z, B1.w,
                        B2.x, B2.y, B2.z, B2.w, B3.x, B3.y, B3.z, B3.w};
        float Cv[DS] = {C0.x, C0.y, C0.z, C0.w, C1.x, C1.y, C1.z, C1.w,
                        C2.x, C2.y, C2.z, C2.w, C3.x, C3.y, C3.z, C3.w};
        float acc = 0.f;
        #pragma unroll
        for (int j = 0; j < DS; j++) {
            float a = fast_exp(dl * Aj[j]);
            h[j] = fmaf(a, h[j], du * Bv[j]);
            acc = fmaf(h[j], Cv[j], acc);
        }
        float sg = fast_sig(zz);
        yp[(size_t)i * DI] = __float2bfloat16((acc + ut * Dd) * (zz * sg));
    }
}

// ---------------- final: out[b,h,n] = pred[b,n,h]*sd + mu ----------------
__global__ void finalize_out(const float* __restrict__ pred, const float* __restrict__ mu,
                             const float* __restrict__ sd, float* __restrict__ out) {
    int n = threadIdx.x;
    int h = blockIdx.x;
    int b = blockIdx.y;
    out[((size_t)b * Hh + h) * NV + n] =
        pred[((size_t)b * NV + n) * Hh + h] * sd[b * NV + n] + mu[b * NV + n];
}

extern "C" void kernel_launch(void* const* d_in, const int* in_sizes, int n_in,
                              void* d_out, int out_size, void* d_ws, size_t ws_size,
                              hipStream_t stream) {
    const float* x     = (const float*)d_in[0];
    const float* tokw  = (const float*)d_in[1];
    const float* tokb  = (const float*)d_in[2];
    const float* in_w  = (const float*)d_in[3];
    const float* in_b  = (const float*)d_in[4];
    const float* convw = (const float*)d_in[5];
    const float* convb = (const float*)d_in[6];
    const float* xpw   = (const float*)d_in[7];
    const float* dtw   = (const float*)d_in[8];
    const float* dtb   = (const float*)d_in[9];
    const float* Alog  = (const float*)d_in[10];
    const float* Dm    = (const float*)d_in[11];
    const float* outw  = (const float*)d_in[12];
    const float* outb  = (const float*)d_in[13];
    const float* mnw   = (const float*)d_in[14];
    const float* mnb   = (const float*)d_in[15];
    const float* fnw   = (const float*)d_in[16];
    const float* fnb   = (const float*)d_in[17];
    const float* fw1   = (const float*)d_in[18];
    const float* fb1   = (const float*)d_in[19];
    const float* fw2   = (const float*)d_in[20];
    const float* fb2   = (const float*)d_in[21];
    const float* nw    = (const float*)d_in[22];
    const float* nb    = (const float*)d_in[23];
    const float* hw    = (const float*)d_in[24];
    const float* hb    = (const float*)d_in[25];

    float* ws = (float*)d_ws;
    float* MU  = ws;
    float* SD  = MU + Bb * NV;
    float* XNT = SD + Bb * NV;
    float* T   = XNT + (size_t)Bb * NV * Ll;
    float* YN  = T + (size_t)Bb * NV * DM;
    float* XZ  = YN + (size_t)Bb * NV * DM;
    float* U   = XZ + (size_t)MROWS * 2 * DI;
    float* XD  = U + (size_t)MROWS * DI;
    float* DEL = XD + (size_t)MROWS * 64;
    float* Y   = DEL + (size_t)MROWS * DI;
    float* PRED = Y + (size_t)MROWS * DI;
    float* WBF  = PRED + (size_t)MROWS * Hh;

    bf16* XNTb = (bf16*)XNT;
    bf16* YNb  = (bf16*)YN;
    bf16* XZb  = (bf16*)XZ;
    bf16* Ub   = (bf16*)DEL;
    bf16* Yb   = (bf16*)Y;
    float* PB  = Y;
    float* HB  = Y + (size_t)Bb * NCH * DS * DI;
    float* HIN = XNT;

    bf16* wb = (bf16*)WBF;
    bf16* tokwb = wb;              wb += (size_t)DM * Ll;
    bf16* inwb  = wb;              wb += (size_t)NLAY * 2 * 2 * DI * DM;
    bf16* xpwb  = wb;              wb += (size_t)NLAY * 2 * 64 * DI;
    bf16* outwb = wb;              wb += (size_t)NLAY * 2 * DM * DI;
    bf16* fw1b  = wb;              wb += (size_t)NLAY * DFF * DM;
    bf16* fw2b  = wb;              wb += (size_t)NLAY * DM * DFF;
    bf16* hwb   = wb;              wb += (size_t)Hh * DM;
    float* PS1  = (float*)wb;      // revin partials: 16*8*512 * 2
    float* PS2  = PS1 + Bb * 8 * NV;

    f2bf<<<(DM * Ll) / 1024, 256, 0, stream>>>(tokw, tokwb, DM * Ll);
    f2bf<<<(NLAY * 2 * 2 * DI * DM) / 1024, 256, 0, stream>>>(in_w, inwb, NLAY * 2 * 2 * DI * DM);
    f2bf<<<(NLAY * 2 * 64 * DI) / 1024, 256, 0, stream>>>(xpw, xpwb, NLAY * 2 * 64 * DI);
    f2bf<<<(NLAY * 2 * DM * DI) / 1024, 256, 0, stream>>>(outw, outwb, NLAY * 2 * DM * DI);
    f2bf<<<(NLAY * DFF * DM) / 1024, 256, 0, stream>>>(fw1, fw1b, NLAY * DFF * DM);
    f2bf<<<(NLAY * DM * DFF) / 1024, 256, 0, stream>>>(fw2, fw2b, NLAY * DM * DFF);
    f2bf<<<(Hh * DM) / 1024, 256, 0, stream>>>(hw, hwb, Hh * DM);

    revin_partial<<<dim3(Bb, 8), NV, 0, stream>>>(x, PS1, PS2);
    revin_final<<<Bb, NV, 0, stream>>>(PS1, PS2, MU, SD);
    transpose_norm<<<dim3(Ll / 32, NV / 32, Bb), dim3(32, 8), 0, stream>>>(x, MU, SD, XNTb);
    gemm_mfma<0, false, false, false, false><<<dim3(MROWS / 128, DM / 128), 256, 0, stream>>>(
        XNTb, Ll, tokwb, tokb, T, DM, MROWS, DM, Ll);

    for (int l = 0; l < NLAY; l++) {
        ln_rows<<<MROWS, DM, 0, stream>>>(T, mnw + l * DM, mnb + l * DM, YNb);
        for (int dir = 0; dir < 2; dir++) {
            int pd = l * 2 + dir;
            const bf16* iw = inwb + (size_t)pd * 2 * DI * DM;
            const float* ib = in_b + (size_t)pd * 2 * DI;
            if (dir == 0)
                gemm_mfma<0, false, false, false, false><<<dim3(MROWS / 128, (2 * DI) / 128), 256, 0, stream>>>(
                    YNb, DM, iw, ib, XZ, 2 * DI, MROWS, 2 * DI, DM);
            else
                gemm_mfma<0, false, true, false, false><<<dim3(MROWS / 128, (2 * DI) / 128), 256, 0, stream>>>(
                    YNb, DM, iw, ib, XZ, 2 * DI, MROWS, 2 * DI, DM);
            conv_silu<<<dim3(DI / 256, Ss / 16, Bb), 256, 0, stream>>>(
                XZ, convw + (size_t)pd * DI * DCONV, convb + pd * DI, U, Ub);
            gemm_mfma<0, false, false, false, false><<<dim3(MROWS / 128, 1), 256, 0, stream>>>(
                Ub, DI, xpwb + (size_t)pd * 64 * DI, nullptr, XD, 64, MROWS, 64, DI);
            gemm_awt<2, false, false, false><<<dim3(MROWS / 64, DI / 64), 256, 0, stream>>>(
                XD, 64, dtw + (size_t)pd * DI * DTR, dtb + pd * DI, DEL, DI, MROWS, DI, DTR);
            scan_pass1<<<dim3(DI / 256, NCH, Bb), 256, 0, stream>>>(
                DEL, U, XD, Alog + (size_t)pd * DI * DS, PB, HB);
            scan_pass2<<<(Bb * DS * DI) / 256, 256, 0, stream>>>(PB, HB, HIN);
            scan_pass3<<<dim3(DI / 256, NCH, Bb), 256, 0, stream>>>(
                DEL, U, XD, XZ, Alog + (size_t)pd * DI * DS, Dm + pd * DI, HIN, Yb);
            if (dir == 0)
                gemm_mfma<0, true, false, false, false><<<dim3(MROWS / 128, DM / 128), 256, 0, stream>>>(
                    Yb, DI, outwb + (size_t)pd * DM * DI, outb + pd * DM, T, DM, MROWS, DM, DI);
            else
                gemm_mfma<0, true, false, true, false><<<dim3(MROWS / 128, DM / 128), 256, 0, stream>>>(
                    Yb, DI, outwb + (size_t)pd * DM * DI, outb + pd * DM, T, DM, MROWS, DM, DI);
        }
        // FFN
        ln_rows<<<MROWS, DM, 0, stream>>>(T, fnw + l * DM, fnb + l * DM, YNb);
        gemm_mfma<1, false, false, false, true><<<dim3(MROWS / 128, DFF / 128), 256, 0, stream>>>(
            YNb, DM, fw1b + (size_t)l * DFF * DM, fb1 + l * DFF, XZb, DFF, MROWS, DFF, DM);
        gemm_mfma<0, true, false, false, false><<<dim3(MROWS / 128, DM / 128), 256, 0, stream>>>(
            XZb, DFF, fw2b + (size_t)l * DM * DFF, fb2 + l * DM, T, DM, MROWS, DM, DFF);
    }
    ln_rows<<<MROWS, DM, 0, stream>>>(T, nw, nb, YNb);
    gemm_mfma<0, false, false, false, false><<<dim3(MROWS / 128, 1), 256, 0, stream>>>(
        YNb, DM, hwb, hb, PRED, Hh, MROWS, Hh, DM);
    finalize_out<<<dim3(Hh, Bb), NV, 0, stream>>>(PRED, MU, SD, (float*)d_out);
}

// Round 6
// 1005.784 us; speedup vs baseline: 4.8284x; 1.2026x over previous
//
#include <hip/hip_runtime.h>
#include <hip/hip_bf16.h>

#define Bb 16
#define Ll 512
#define NV 512
#define DM 512
#define DS 16
#define NLAY 2
#define DFF 2048
#define DI 1024
#define DCONV 4
#define DTR 32
#define Hh 96
#define Ss NV
#define MROWS (Bb*Ss)
#define EPSf 1e-5f
#define CH 32
#define NCH (Ss/CH)

typedef __hip_bfloat16 bf16;
typedef __attribute__((ext_vector_type(8))) short bf16x8;
typedef __attribute__((ext_vector_type(4))) float f32x4;

#define GLL16(g, l) __builtin_amdgcn_global_load_lds( \
    (const __attribute__((address_space(1))) unsigned int*)(g), \
    (__attribute__((address_space(3))) unsigned int*)(l), 16, 0, 0)

__device__ __forceinline__ float fast_exp(float x) { return __expf(x); }
__device__ __forceinline__ float fast_sig(float x) {
    return __builtin_amdgcn_rcpf(1.f + __expf(-x));
}
__device__ __forceinline__ float fast_softplus(float r) {
    float e = __expf(-fabsf(r));
    return fmaxf(r, 0.f) + __logf(1.f + e);
}

// ---------------- fp32 -> bf16 convert ----------------
__global__ void f2bf(const float* __restrict__ in, bf16* __restrict__ out, int n) {
    int i = (blockIdx.x * 256 + threadIdx.x) * 4;
    if (i < n) {
        float4 v = *(const float4*)(in + i);
        out[i + 0] = __float2bfloat16(v.x);
        out[i + 1] = __float2bfloat16(v.y);
        out[i + 2] = __float2bfloat16(v.z);
        out[i + 3] = __float2bfloat16(v.w);
    }
}

// ---------------- RevIN stats (two-stage) ----------------
__global__ void revin_partial(const float* __restrict__ x, float* __restrict__ ps1,
                              float* __restrict__ ps2) {
    int b = blockIdx.x, c = blockIdx.y, n = threadIdx.x;
    const float* xp = x + (size_t)b * Ll * NV + (size_t)c * (Ll / 8) * NV + n;
    float s1 = 0.f, s2 = 0.f;
    #pragma unroll 4
    for (int l = 0; l < Ll / 8; l++) { float v = xp[(size_t)l * NV]; s1 += v; s2 += v * v; }
    ps1[((size_t)b * 8 + c) * NV + n] = s1;
    ps2[((size_t)b * 8 + c) * NV + n] = s2;
}

__global__ void revin_final(const float* __restrict__ ps1, const float* __restrict__ ps2,
                            float* __restrict__ mu, float* __restrict__ sd) {
    int b = blockIdx.x, n = threadIdx.x;
    float s1 = 0.f, s2 = 0.f;
    #pragma unroll
    for (int c = 0; c < 8; c++) {
        s1 += ps1[((size_t)b * 8 + c) * NV + n];
        s2 += ps2[((size_t)b * 8 + c) * NV + n];
    }
    float m = s1 / Ll;
    float var = s2 / Ll - m * m;
    mu[b * NV + n] = m;
    sd[b * NV + n] = sqrtf(var + EPSf);
}

// ------------- normalize + transpose -> bf16: xnT[b,n,l] -------------
__global__ void transpose_norm(const float* __restrict__ x, const float* __restrict__ mu,
                               const float* __restrict__ sd, bf16* __restrict__ xnT) {
    __shared__ float t[32][33];
    int b = blockIdx.z;
    int l0 = blockIdx.x * 32, n0 = blockIdx.y * 32;
    int tx = threadIdx.x, ty = threadIdx.y; // 32x8
    #pragma unroll
    for (int q = 0; q < 4; q++)
        t[ty + q * 8][tx] = x[(size_t)b * Ll * NV + (size_t)(l0 + ty + q * 8) * NV + n0 + tx];
    __syncthreads();
    #pragma unroll
    for (int q = 0; q < 4; q++) {
        int n = n0 + ty + q * 8;
        float m = mu[b * NV + n], s = sd[b * NV + n];
        xnT[(size_t)b * NV * Ll + (size_t)n * Ll + l0 + tx] = __float2bfloat16((t[tx][ty + q * 8] - m) / s);
    }
}

// ---------------- LayerNorm over rows of DM -> bf16 ----------------
__global__ void ln_rows(const float* __restrict__ in, const float* __restrict__ w,
                        const float* __restrict__ bvec, bf16* __restrict__ out) {
    int row = blockIdx.x;
    int tid = threadIdx.x;
    float v = in[(size_t)row * DM + tid];
    float s1 = v, s2 = v * v;
    #pragma unroll
    for (int o = 32; o > 0; o >>= 1) { s1 += __shfl_down(s1, o, 64); s2 += __shfl_down(s2, o, 64); }
    __shared__ float l1[8], l2[8];
    int wv = tid >> 6, ln = tid & 63;
    if (ln == 0) { l1[wv] = s1; l2[wv] = s2; }
    __syncthreads();
    if (tid == 0) {
        float a = 0.f, c = 0.f;
        #pragma unroll
        for (int i = 0; i < DM / 64; i++) { a += l1[i]; c += l2[i]; }
        l1[0] = a; l2[0] = c;
    }
    __syncthreads();
    float mean = l1[0] / DM;
    float var = l2[0] / DM - mean * mean;
    float inv = rsqrtf(var + EPSf);
    out[(size_t)row * DM + tid] = __float2bfloat16((v - mean) * inv * w[tid] + bvec[tid]);
}

// ============ MFMA GEMM, 128x128 tile, BK=32, double-buffered, swizzled ============
// C = A(M,K) @ W(N,K)^T + bias. REVA: reverse A rows within 512-blocks.
template<int EPI, bool ACC, bool REVA, bool OUTBF>
__global__ __launch_bounds__(256) void gemm128(
    const bf16* __restrict__ A, int lda,
    const bf16* __restrict__ W,
    const float* __restrict__ bias,
    void* __restrict__ Cv, int ldc,
    int M, int Nn, int K) {
    __shared__ bf16 As[2][128 * 32];
    __shared__ bf16 Bs[2][128 * 32];
    int m0 = blockIdx.x * 128, n0 = blockIdx.y * 128;
    int tid = threadIdx.x;
    int w = tid >> 6, lane = tid & 63;
    int wm = (w >> 1) * 64, wn = (w & 1) * 64;
    f32x4 acc[4][4] = {};

    // ---- staging addresses (pre-swizzled global source, linear LDS dest) ----
    int srow = w * 32 + (lane >> 2);
    int sslot = (lane & 3) ^ ((lane >> 2) & 3);        // global col slot for this lane
    long arow0 = m0 + srow, arow1 = m0 + srow + 16;
    if (REVA) {
        arow0 = (arow0 & ~511L) | (511 - (arow0 & 511));
        arow1 = (arow1 & ~511L) | (511 - (arow1 & 511));
    }
    const char* agp0 = (const char*)(A + arow0 * (long)lda) + sslot * 16;
    const char* agp1 = (const char*)(A + arow1 * (long)lda) + sslot * 16;
    long wr0 = n0 + srow;      if (wr0 >= Nn) wr0 = Nn - 1;
    long wr1 = n0 + srow + 16; if (wr1 >= Nn) wr1 = Nn - 1;
    const char* wgp0 = (const char*)(W + wr0 * (long)K) + sslot * 16;
    const char* wgp1 = (const char*)(W + wr1 * (long)K) + sslot * 16;

    char* a0 = (char*)As[0]; char* a1 = (char*)As[1];
    char* b0 = (char*)Bs[0]; char* b1 = (char*)Bs[1];
    int dA0 = (w * 32) * 64, dA1 = (w * 32 + 16) * 64;   // LDS byte offsets (wave-uniform)

    int lrow = lane & 15;
    int salt = (((lane >> 4)) ^ (lane & 3)) * 16;        // swizzled read slot

    const int nk = K >> 5;
#define STG128(pa, pb, ko) do { \
        GLL16(agp0 + (size_t)(ko) * 64, pa + dA0); \
        GLL16(agp1 + (size_t)(ko) * 64, pa + dA1); \
        GLL16(wgp0 + (size_t)(ko) * 64, pb + dA0); \
        GLL16(wgp1 + (size_t)(ko) * 64, pb + dA1); } while (0)

    STG128(a0, b0, 0);
    __syncthreads();
    for (int t = 0; t < nk; ++t) {
        char* ac = (t & 1) ? a1 : a0;
        char* bc = (t & 1) ? b1 : b0;
        if (t + 1 < nk) {
            char* an = (t & 1) ? a0 : a1;
            char* bn = (t & 1) ? b0 : b1;
            STG128(an, bn, t + 1);
        }
        bf16x8 af[4], bfr[4];
        #pragma unroll
        for (int i = 0; i < 4; i++) {
            af[i]  = *(const bf16x8*)(ac + (wm + i * 16 + lrow) * 64 + salt);
            bfr[i] = *(const bf16x8*)(bc + (wn + i * 16 + lrow) * 64 + salt);
        }
        #pragma unroll
        for (int i = 0; i < 4; i++)
            #pragma unroll
            for (int j = 0; j < 4; j++)
                acc[i][j] = __builtin_amdgcn_mfma_f32_16x16x32_bf16(af[i], bfr[j], acc[i][j], 0, 0, 0);
        __syncthreads();
    }
#undef STG128

    #pragma unroll
    for (int i = 0; i < 4; i++) {
        #pragma unroll
        for (int j = 0; j < 4; j++) {
            int n = n0 + wn + j * 16 + (lane & 15);
            if (n >= Nn) continue;
            float bv = bias ? bias[n] : 0.f;
            #pragma unroll
            for (int r = 0; r < 4; r++) {
                long m = m0 + wm + i * 16 + (lane >> 4) * 4 + r;
                float v = acc[i][j][r] + bv;
                if (EPI == 1) {
                    float x3 = v * v * v;
                    v = 0.5f * v * (1.f + tanhf(0.7978845608028654f * (v + 0.044715f * x3)));
                }
                if (OUTBF) {
                    ((bf16*)Cv)[m * (long)ldc + n] = __float2bfloat16(v);
                } else if (ACC) {
                    ((float*)Cv)[m * (long)ldc + n] += v;
                } else {
                    ((float*)Cv)[m * (long)ldc + n] = v;
                }
            }
        }
    }
}

// ============ MFMA GEMM, 128x64 tile, BK=64, double-buffered, swizzled ============
// 4 waves, each 32x64. For N<=512 shapes (more blocks -> 2 blocks/CU).
template<int EPI, bool ACC, bool OUTBF>
__global__ __launch_bounds__(256) void gemm64(
    const bf16* __restrict__ A, int lda,
    const bf16* __restrict__ W,
    const float* __restrict__ bias,
    void* __restrict__ Cv, int ldc,
    int M, int Nn, int K) {
    __shared__ bf16 As[2][128 * 64];
    __shared__ bf16 Bs[2][64 * 64];
    int m0 = blockIdx.x * 128, n0 = blockIdx.y * 64;
    int tid = threadIdx.x;
    int w = tid >> 6, lane = tid & 63;
    int wm = w * 32;
    f32x4 acc[2][4] = {};

    // ---- staging: rows of 128B; lane -> (row = lane>>3, slot = lane&7), swizzled source ----
    int srow = lane >> 3;
    int sslot = (lane & 7) ^ srow;                      // slot ^ (row&7)
    const char* agp[4];
    #pragma unroll
    for (int g = 0; g < 4; g++) {
        long ar = m0 + w * 32 + g * 8 + srow;
        agp[g] = (const char*)(A + ar * (long)lda) + sslot * 16;
    }
    const char* wgp[2];
    #pragma unroll
    for (int g = 0; g < 2; g++) {
        long br = n0 + w * 16 + g * 8 + srow;
        if (br >= Nn) br = Nn - 1;
        wgp[g] = (const char*)(W + br * (long)K) + sslot * 16;
    }
    char* a0 = (char*)As[0]; char* a1 = (char*)As[1];
    char* b0 = (char*)Bs[0]; char* b1 = (char*)Bs[1];

    int lrow = lane & 15;
    int rk = lane & 7, hi = lane >> 4;
    int salt0 = ((hi) ^ rk) * 16;
    int salt1 = ((4 + hi) ^ rk) * 16;

    const int nk = K >> 6;
#define STG64(pa, pb, ko) do { \
        GLL16(agp[0] + (size_t)(ko) * 128, pa + (w * 32 + 0)  * 128); \
        GLL16(agp[1] + (size_t)(ko) * 128, pa + (w * 32 + 8)  * 128); \
        GLL16(agp[2] + (size_t)(ko) * 128, pa + (w * 32 + 16) * 128); \
        GLL16(agp[3] + (size_t)(ko) * 128, pa + (w * 32 + 24) * 128); \
        GLL16(wgp[0] + (size_t)(ko) * 128, pb + (w * 16 + 0)  * 128); \
        GLL16(wgp[1] + (size_t)(ko) * 128, pb + (w * 16 + 8)  * 128); } while (0)

    STG64(a0, b0, 0);
    __syncthreads();
    for (int t = 0; t < nk; ++t) {
        char* ac = (t & 1) ? a1 : a0;
        char* bc = (t & 1) ? b1 : b0;
        if (t + 1 < nk) {
            char* an = (t & 1) ? a0 : a1;
            char* bn = (t & 1) ? b0 : b1;
            STG64(an, bn, t + 1);
        }
        bf16x8 af[2][2], bfr[2][4];
        #pragma unroll
        for (int i = 0; i < 2; i++) {
            af[0][i] = *(const bf16x8*)(ac + (wm + i * 16 + lrow) * 128 + salt0);
            af[1][i] = *(const bf16x8*)(ac + (wm + i * 16 + lrow) * 128 + salt1);
        }
        #pragma unroll
        for (int j = 0; j < 4; j++) {
            bfr[0][j] = *(const bf16x8*)(bc + (j * 16 + lrow) * 128 + salt0);
            bfr[1][j] = *(const bf16x8*)(bc + (j * 16 + lrow) * 128 + salt1);
        }
        #pragma unroll
        for (int kk = 0; kk < 2; kk++)
            #pragma unroll
            for (int i = 0; i < 2; i++)
                #pragma unroll
                for (int j = 0; j < 4; j++)
                    acc[i][j] = __builtin_amdgcn_mfma_f32_16x16x32_bf16(af[kk][i], bfr[kk][j], acc[i][j], 0, 0, 0);
        __syncthreads();
    }
#undef STG64

    #pragma unroll
    for (int i = 0; i < 2; i++) {
        #pragma unroll
        for (int j = 0; j < 4; j++) {
            int n = n0 + j * 16 + (lane & 15);
            if (n >= Nn) continue;
            float bv = bias ? bias[n] : 0.f;
            #pragma unroll
            for (int r = 0; r < 4; r++) {
                long m = m0 + wm + i * 16 + (lane >> 4) * 4 + r;
                float v = acc[i][j][r] + bv;
                if (EPI == 1) {
                    float x3 = v * v * v;
                    v = 0.5f * v * (1.f + tanhf(0.7978845608028654f * (v + 0.044715f * x3)));
                }
                if (OUTBF) {
                    ((bf16*)Cv)[m * (long)ldc + n] = __float2bfloat16(v);
                } else if (ACC) {
                    ((float*)Cv)[m * (long)ldc + n] += v;
                } else {
                    ((float*)Cv)[m * (long)ldc + n] = v;
                }
            }
        }
    }
}

// ---------------- fp32 GEMM (dt-proj, K=32) ----------------
template<int EPI, bool ACC>
__global__ __launch_bounds__(256) void gemm_awt(
    const float* __restrict__ A, int lda,
    const float* __restrict__ W,
    const float* __restrict__ bias,
    float* __restrict__ C, int ldc,
    int M, int Nn, int K) {
    __shared__ float Asm[16][68];
    __shared__ float Wsm[16][68];
    int m0 = blockIdx.x * 64;
    int n0 = blockIdx.y * 64;
    int tid = threadIdx.x;
    int tm = (tid / 16) * 4, tn = (tid % 16) * 4;
    float acc[4][4] = {};
    int lr = tid / 4;
    int lk = (tid % 4) * 4;
    const float* aptr = A + (size_t)(m0 + lr) * lda + lk;
    int wrow = n0 + lr;
    bool wok = wrow < Nn;
    const float* wptr = W + (size_t)wrow * K + lk;
    for (int k0 = 0; k0 < K; k0 += 16) {
        float4 av = *(const float4*)(aptr + k0);
        float4 wv = wok ? *(const float4*)(wptr + k0) : make_float4(0.f, 0.f, 0.f, 0.f);
        Asm[lk + 0][lr] = av.x; Asm[lk + 1][lr] = av.y; Asm[lk + 2][lr] = av.z; Asm[lk + 3][lr] = av.w;
        Wsm[lk + 0][lr] = wv.x; Wsm[lk + 1][lr] = wv.y; Wsm[lk + 2][lr] = wv.z; Wsm[lk + 3][lr] = wv.w;
        __syncthreads();
        #pragma unroll
        for (int kk = 0; kk < 16; kk++) {
            float4 a = *(const float4*)&Asm[kk][tm];
            float4 wv2 = *(const float4*)&Wsm[kk][tn];
            float ar[4] = {a.x, a.y, a.z, a.w};
            float wr[4] = {wv2.x, wv2.y, wv2.z, wv2.w};
            #pragma unroll
            for (int i = 0; i < 4; i++)
                #pragma unroll
                for (int j = 0; j < 4; j++)
                    acc[i][j] = fmaf(ar[i], wr[j], acc[i][j]);
        }
        __syncthreads();
    }
    #pragma unroll
    for (int i = 0; i < 4; i++) {
        int m = m0 + tm + i;
        #pragma unroll
        for (int j = 0; j < 4; j++) {
            int n = n0 + tn + j;
            if (n < Nn) {
                float r = acc[i][j];
                if (bias) r += bias[n];
                if (EPI == 2) r = fast_softplus(r);
                if (ACC) C[(size_t)m * ldc + n] += r;
                else     C[(size_t)m * ldc + n] = r;
            }
        }
    }
}

// ---------------- causal depthwise conv (k=4) + silu, dual output ----------------
__global__ void conv_silu(const float* __restrict__ xz, const float* __restrict__ cw,
                          const float* __restrict__ cb, float* __restrict__ u,
                          bf16* __restrict__ ub) {
    int c = blockIdx.x * 256 + threadIdx.x;
    int s0 = blockIdx.y * 16;
    int b = blockIdx.z;
    const float* src = xz + (size_t)b * Ss * (2 * DI) + c;
    float w0 = cw[c * 4 + 0], w1 = cw[c * 4 + 1], w2 = cw[c * 4 + 2], w3 = cw[c * 4 + 3];
    float bias = cb[c];
    float r0 = (s0 - 3 >= 0) ? src[(size_t)(s0 - 3) * (2 * DI)] : 0.f;
    float r1 = (s0 - 2 >= 0) ? src[(size_t)(s0 - 2) * (2 * DI)] : 0.f;
    float r2 = (s0 - 1 >= 0) ? src[(size_t)(s0 - 1) * (2 * DI)] : 0.f;
    for (int i = 0; i < 16; i++) {
        int s = s0 + i;
        float r3 = src[(size_t)s * (2 * DI)];
        float a = fmaf(r0, w0, fmaf(r1, w1, fmaf(r2, w2, fmaf(r3, w3, bias))));
        float v = a * fast_sig(a);
        u[((size_t)b * Ss + s) * DI + c] = v;
        ub[((size_t)b * Ss + s) * DI + c] = __float2bfloat16(v);
        r0 = r1; r1 = r2; r2 = r3;
    }
}

// ======== chunked parallel selective scan ========
__global__ __launch_bounds__(256) void scan_pass1(
    const float* __restrict__ delta, const float* __restrict__ u,
    const float* __restrict__ xdbl, const float* __restrict__ A_log,
    float* __restrict__ PB, float* __restrict__ HB) {
    int d = blockIdx.x * 256 + threadIdx.x;
    int c = blockIdx.y;
    int b = blockIdx.z;
    float Aj[DS], h[DS];
    #pragma unroll
    for (int j = 0; j < DS; j++) { Aj[j] = -fast_exp(A_log[(size_t)d * DS + j]); h[j] = 0.f; }
    const float* dp = delta + ((size_t)b * Ss + c * CH) * DI + d;
    const float* up = u + ((size_t)b * Ss + c * CH) * DI + d;
    const float* bc = xdbl + ((size_t)b * Ss + c * CH) * 64 + DTR;
    float dlsum = 0.f;
    for (int i = 0; i < CH; i++) {
        float dl = dp[(size_t)i * DI];
        float ut = up[(size_t)i * DI];
        float du = dl * ut;
        dlsum += dl;
        const float4* q4 = (const float4*)(bc + (size_t)i * 64);
        float4 B0 = q4[0], B1 = q4[1], B2 = q4[2], B3 = q4[3];
        float Bv[DS] = {B0.x, B0.y, B0.z, B0.w, B1.x, B1.y, B1.z, B1.w,
                        B2.x, B2.y, B2.z, B2.w, B3.x, B3.y, B3.z, B3.w};
        #pragma unroll
        for (int j = 0; j < DS; j++) {
            float a = fast_exp(dl * Aj[j]);
            h[j] = fmaf(a, h[j], du * Bv[j]);
        }
    }
    size_t base = ((size_t)(b * NCH + c)) * DS * DI + d;
    #pragma unroll
    for (int j = 0; j < DS; j++) {
        PB[base + (size_t)j * DI] = fast_exp(dlsum * Aj[j]);
        HB[base + (size_t)j * DI] = h[j];
    }
}

__global__ __launch_bounds__(256) void scan_pass2(
    const float* __restrict__ PB, const float* __restrict__ HB, float* __restrict__ HIN) {
    int idx = blockIdx.x * 256 + threadIdx.x;
    int b = idx >> 14;
    int rem = idx & 16383;
    float h = 0.f;
    #pragma unroll
    for (int c = 0; c < NCH; c++) {
        size_t o = ((size_t)(b * NCH + c)) * (DS * DI) + rem;
        float p = PB[o], hl = HB[o];
        HIN[o] = h;
        h = fmaf(p, h, hl);
    }
}

// REV: write y back in ORIGINAL row order (folds the old REVC into the scan epilogue)
template<bool REV>
__global__ __launch_bounds__(256) void scan_pass3(
    const float* __restrict__ delta, const float* __restrict__ u,
    const float* __restrict__ xdbl, const float* __restrict__ xz,
    const float* __restrict__ A_log, const float* __restrict__ Dp,
    const float* __restrict__ HIN, bf16* __restrict__ y) {
    int d = blockIdx.x * 256 + threadIdx.x;
    int c = blockIdx.y;
    int b = blockIdx.z;
    float Aj[DS], h[DS];
    size_t hbase = ((size_t)(b * NCH + c)) * DS * DI + d;
    #pragma unroll
    for (int j = 0; j < DS; j++) {
        Aj[j] = -fast_exp(A_log[(size_t)d * DS + j]);
        h[j] = HIN[hbase + (size_t)j * DI];
    }
    float Dd = Dp[d];
    const float* dp = delta + ((size_t)b * Ss + c * CH) * DI + d;
    const float* up = u + ((size_t)b * Ss + c * CH) * DI + d;
    const float* zp = xz + ((size_t)b * Ss + c * CH) * (2 * DI) + DI + d;
    const float* bc = xdbl + ((size_t)b * Ss + c * CH) * 64 + DTR;
    for (int i = 0; i < CH; i++) {
        float dl = dp[(size_t)i * DI];
        float ut = up[(size_t)i * DI];
        float zz = zp[(size_t)i * (2 * DI)];
        float du = dl * ut;
        const float4* q4 = (const float4*)(bc + (size_t)i * 64);
        float4 B0 = q4[0], B1 = q4[1], B2 = q4[2], B3 = q4[3];
        float4 C0 = q4[4], C1 = q4[5], C2 = q4[6], C3 = q4[7];
        float Bv[DS] = {B0.x, B0.y, B0.z, B0.w, B1.x, B1.y, B1.z, B1.w,
                        B2.x, B2.y, B2.z, B2.w, B3.x, B3.y, B3.z, B3.w};
        float Cv[DS] = {C0.x, C0.y, C0.z, C0.w, C1.x, C1.y, C1.z, C1.w,
                        C2.x, C2.y, C2.z, C2.w, C3.x, C3.y, C3.z, C3.w};
        float acc = 0.f;
        #pragma unroll
        for (int j = 0; j < DS; j++) {
            float a = fast_exp(dl * Aj[j]);
            h[j] = fmaf(a, h[j], du * Bv[j]);
            acc = fmaf(h[j], Cv[j], acc);
        }
        float sg = fast_sig(zz);
        int sidx = c * CH + i;
        int so = REV ? (Ss - 1 - sidx) : sidx;
        y[((size_t)b * Ss + so) * DI + d] = __float2bfloat16((acc + ut * Dd) * (zz * sg));
    }
}

// ---------------- final: out[b,h,n] = pred[b,n,h]*sd + mu ----------------
__global__ void finalize_out(const float* __restrict__ pred, const float* __restrict__ mu,
                             const float* __restrict__ sd, float* __restrict__ out) {
    int n = threadIdx.x;
    int h = blockIdx.x;
    int b = blockIdx.y;
    out[((size_t)b * Hh + h) * NV + n] =
        pred[((size_t)b * NV + n) * Hh + h] * sd[b * NV + n] + mu[b * NV + n];
}

extern "C" void kernel_launch(void* const* d_in, const int* in_sizes, int n_in,
                              void* d_out, int out_size, void* d_ws, size_t ws_size,
                              hipStream_t stream) {
    const float* x     = (const float*)d_in[0];
    const float* tokw  = (const float*)d_in[1];
    const float* tokb  = (const float*)d_in[2];
    const float* in_w  = (const float*)d_in[3];
    const float* in_b  = (const float*)d_in[4];
    const float* convw = (const float*)d_in[5];
    const float* convb = (const float*)d_in[6];
    const float* xpw   = (const float*)d_in[7];
    const float* dtw   = (const float*)d_in[8];
    const float* dtb   = (const float*)d_in[9];
    const float* Alog  = (const float*)d_in[10];
    const float* Dm    = (const float*)d_in[11];
    const float* outw  = (const float*)d_in[12];
    const float* outb  = (const float*)d_in[13];
    const float* mnw   = (const float*)d_in[14];
    const float* mnb   = (const float*)d_in[15];
    const float* fnw   = (const float*)d_in[16];
    const float* fnb   = (const float*)d_in[17];
    const float* fw1   = (const float*)d_in[18];
    const float* fb1   = (const float*)d_in[19];
    const float* fw2   = (const float*)d_in[20];
    const float* fb2   = (const float*)d_in[21];
    const float* nw    = (const float*)d_in[22];
    const float* nb    = (const float*)d_in[23];
    const float* hw    = (const float*)d_in[24];
    const float* hb    = (const float*)d_in[25];

    float* ws = (float*)d_ws;
    float* MU  = ws;
    float* SD  = MU + Bb * NV;
    float* XNT = SD + Bb * NV;
    float* T   = XNT + (size_t)Bb * NV * Ll;
    float* YN  = T + (size_t)Bb * NV * DM;
    float* XZ  = YN + (size_t)Bb * NV * DM;
    float* U   = XZ + (size_t)MROWS * 2 * DI;
    float* XD  = U + (size_t)MROWS * DI;
    float* DEL = XD + (size_t)MROWS * 64;
    float* Y   = DEL + (size_t)MROWS * DI;
    float* PRED = Y + (size_t)MROWS * DI;
    float* WBF  = PRED + (size_t)MROWS * Hh;

    bf16* XNTb = (bf16*)XNT;
    bf16* YNb  = (bf16*)YN;
    bf16* XZb  = (bf16*)XZ;
    bf16* Ub   = (bf16*)DEL;
    bf16* Yb   = (bf16*)Y;
    float* PB  = Y;
    float* HB  = Y + (size_t)Bb * NCH * DS * DI;
    float* HIN = XNT;

    bf16* wb = (bf16*)WBF;
    bf16* tokwb = wb;              wb += (size_t)DM * Ll;
    bf16* inwb  = wb;              wb += (size_t)NLAY * 2 * 2 * DI * DM;
    bf16* xpwb  = wb;              wb += (size_t)NLAY * 2 * 64 * DI;
    bf16* outwb = wb;              wb += (size_t)NLAY * 2 * DM * DI;
    bf16* fw1b  = wb;              wb += (size_t)NLAY * DFF * DM;
    bf16* fw2b  = wb;              wb += (size_t)NLAY * DM * DFF;
    bf16* hwb   = wb;              wb += (size_t)Hh * DM;
    float* PS1  = (float*)wb;
    float* PS2  = PS1 + Bb * 8 * NV;

    f2bf<<<(DM * Ll) / 1024, 256, 0, stream>>>(tokw, tokwb, DM * Ll);
    f2bf<<<(NLAY * 2 * 2 * DI * DM) / 1024, 256, 0, stream>>>(in_w, inwb, NLAY * 2 * 2 * DI * DM);
    f2bf<<<(NLAY * 2 * 64 * DI) / 1024, 256, 0, stream>>>(xpw, xpwb, NLAY * 2 * 64 * DI);
    f2bf<<<(NLAY * 2 * DM * DI) / 1024, 256, 0, stream>>>(outw, outwb, NLAY * 2 * DM * DI);
    f2bf<<<(NLAY * DFF * DM) / 1024, 256, 0, stream>>>(fw1, fw1b, NLAY * DFF * DM);
    f2bf<<<(NLAY * DM * DFF) / 1024, 256, 0, stream>>>(fw2, fw2b, NLAY * DM * DFF);
    f2bf<<<(Hh * DM) / 1024, 256, 0, stream>>>(hw, hwb, Hh * DM);

    revin_partial<<<dim3(Bb, 8), NV, 0, stream>>>(x, PS1, PS2);
    revin_final<<<Bb, NV, 0, stream>>>(PS1, PS2, MU, SD);
    transpose_norm<<<dim3(Ll / 32, NV / 32, Bb), dim3(32, 8), 0, stream>>>(x, MU, SD, XNTb);
    gemm64<0, false, false><<<dim3(MROWS / 128, DM / 64), 256, 0, stream>>>(
        XNTb, Ll, tokwb, tokb, T, DM, MROWS, DM, Ll);

    for (int l = 0; l < NLAY; l++) {
        ln_rows<<<MROWS, DM, 0, stream>>>(T, mnw + l * DM, mnb + l * DM, YNb);
        for (int dir = 0; dir < 2; dir++) {
            int pd = l * 2 + dir;
            const bf16* iw = inwb + (size_t)pd * 2 * DI * DM;
            const float* ib = in_b + (size_t)pd * 2 * DI;
            if (dir == 0)
                gemm128<0, false, false, false><<<dim3(MROWS / 128, (2 * DI) / 128), 256, 0, stream>>>(
                    YNb, DM, iw, ib, XZ, 2 * DI, MROWS, 2 * DI, DM);
            else
                gemm128<0, false, true, false><<<dim3(MROWS / 128, (2 * DI) / 128), 256, 0, stream>>>(
                    YNb, DM, iw, ib, XZ, 2 * DI, MROWS, 2 * DI, DM);
            conv_silu<<<dim3(DI / 256, Ss / 16, Bb), 256, 0, stream>>>(
                XZ, convw + (size_t)pd * DI * DCONV, convb + pd * DI, U, Ub);
            gemm64<0, false, false><<<dim3(MROWS / 128, 1), 256, 0, stream>>>(
                Ub, DI, xpwb + (size_t)pd * 64 * DI, nullptr, XD, 64, MROWS, 64, DI);
            gemm_awt<2, false><<<dim3(MROWS / 64, DI / 64), 256, 0, stream>>>(
                XD, 64, dtw + (size_t)pd * DI * DTR, dtb + pd * DI, DEL, DI, MROWS, DI, DTR);
            scan_pass1<<<dim3(DI / 256, NCH, Bb), 256, 0, stream>>>(
                DEL, U, XD, Alog + (size_t)pd * DI * DS, PB, HB);
            scan_pass2<<<(Bb * DS * DI) / 256, 256, 0, stream>>>(PB, HB, HIN);
            if (dir == 0)
                scan_pass3<false><<<dim3(DI / 256, NCH, Bb), 256, 0, stream>>>(
                    DEL, U, XD, XZ, Alog + (size_t)pd * DI * DS, Dm + pd * DI, HIN, Yb);
            else
                scan_pass3<true><<<dim3(DI / 256, NCH, Bb), 256, 0, stream>>>(
                    DEL, U, XD, XZ, Alog + (size_t)pd * DI * DS, Dm + pd * DI, HIN, Yb);
            gemm64<0, true, false><<<dim3(MROWS / 128, DM / 64), 256, 0, stream>>>(
                Yb, DI, outwb + (size_t)pd * DM * DI, outb + pd * DM, T, DM, MROWS, DM, DI);
        }
        // FFN
        ln_rows<<<MROWS, DM, 0, stream>>>(T, fnw + l * DM, fnb + l * DM, YNb);
        gemm128<1, false, false, true><<<dim3(MROWS / 128, DFF / 128), 256, 0, stream>>>(
            YNb, DM, fw1b + (size_t)l * DFF * DM, fb1 + l * DFF, XZb, DFF, MROWS, DFF, DM);
        gemm64<0, true, false><<<dim3(MROWS / 128, DM / 64), 256, 0, stream>>>(
            XZb, DFF, fw2b + (size_t)l * DM * DFF, fb2 + l * DM, T, DM, MROWS, DM, DFF);
    }
    ln_rows<<<MROWS, DM, 0, stream>>>(T, nw, nb, YNb);
    gemm64<0, false, false><<<dim3(MROWS / 128, 2), 256, 0, stream>>>(
        YNb, DM, hwb, hb, PRED, Hh, MROWS, Hh, DM);
    finalize_out<<<dim3(Hh, Bb), NV, 0, stream>>>(PRED, MU, SD, (float*)d_out);
}

// Round 7
// 990.797 us; speedup vs baseline: 4.9015x; 1.0151x over previous
//
#include <hip/hip_runtime.h>
#include <hip/hip_bf16.h>

#define Bb 16
#define Ll 512
#define NV 512
#define DM 512
#define DS 16
#define NLAY 2
#define DFF 2048
#define DI 1024
#define DCONV 4
#define DTR 32
#define Hh 96
#define Ss NV
#define MROWS (Bb*Ss)
#define EPSf 1e-5f
#define CH 32
#define NCH (Ss/CH)

typedef __hip_bfloat16 bf16;
typedef __attribute__((ext_vector_type(8))) short bf16x8;
typedef __attribute__((ext_vector_type(4))) float f32x4;

#define GLL16(g, l) __builtin_amdgcn_global_load_lds( \
    (const __attribute__((address_space(1))) unsigned int*)(g), \
    (__attribute__((address_space(3))) unsigned int*)(l), 16, 0, 0)

__device__ __forceinline__ float fast_exp(float x) { return __expf(x); }
__device__ __forceinline__ float fast_sig(float x) {
    return __builtin_amdgcn_rcpf(1.f + __expf(-x));
}
__device__ __forceinline__ float fast_softplus(float r) {
    float e = __expf(-fabsf(r));
    return fmaxf(r, 0.f) + __logf(1.f + e);
}

// ---------------- fp32 -> bf16 convert ----------------
__global__ void f2bf(const float* __restrict__ in, bf16* __restrict__ out, int n) {
    int i = (blockIdx.x * 256 + threadIdx.x) * 4;
    if (i < n) {
        float4 v = *(const float4*)(in + i);
        out[i + 0] = __float2bfloat16(v.x);
        out[i + 1] = __float2bfloat16(v.y);
        out[i + 2] = __float2bfloat16(v.z);
        out[i + 3] = __float2bfloat16(v.w);
    }
}

// ---------------- RevIN stats (two-stage) ----------------
__global__ void revin_partial(const float* __restrict__ x, float* __restrict__ ps1,
                              float* __restrict__ ps2) {
    int b = blockIdx.x, c = blockIdx.y, n = threadIdx.x;
    const float* xp = x + (size_t)b * Ll * NV + (size_t)c * (Ll / 8) * NV + n;
    float s1 = 0.f, s2 = 0.f;
    #pragma unroll 4
    for (int l = 0; l < Ll / 8; l++) { float v = xp[(size_t)l * NV]; s1 += v; s2 += v * v; }
    ps1[((size_t)b * 8 + c) * NV + n] = s1;
    ps2[((size_t)b * 8 + c) * NV + n] = s2;
}

__global__ void revin_final(const float* __restrict__ ps1, const float* __restrict__ ps2,
                            float* __restrict__ mu, float* __restrict__ sd) {
    int b = blockIdx.x, n = threadIdx.x;
    float s1 = 0.f, s2 = 0.f;
    #pragma unroll
    for (int c = 0; c < 8; c++) {
        s1 += ps1[((size_t)b * 8 + c) * NV + n];
        s2 += ps2[((size_t)b * 8 + c) * NV + n];
    }
    float m = s1 / Ll;
    float var = s2 / Ll - m * m;
    mu[b * NV + n] = m;
    sd[b * NV + n] = sqrtf(var + EPSf);
}

// ------------- normalize + transpose -> bf16: xnT[b,n,l] -------------
__global__ void transpose_norm(const float* __restrict__ x, const float* __restrict__ mu,
                               const float* __restrict__ sd, bf16* __restrict__ xnT) {
    __shared__ float t[32][33];
    int b = blockIdx.z;
    int l0 = blockIdx.x * 32, n0 = blockIdx.y * 32;
    int tx = threadIdx.x, ty = threadIdx.y; // 32x8
    #pragma unroll
    for (int q = 0; q < 4; q++)
        t[ty + q * 8][tx] = x[(size_t)b * Ll * NV + (size_t)(l0 + ty + q * 8) * NV + n0 + tx];
    __syncthreads();
    #pragma unroll
    for (int q = 0; q < 4; q++) {
        int n = n0 + ty + q * 8;
        float m = mu[b * NV + n], s = sd[b * NV + n];
        xnT[(size_t)b * NV * Ll + (size_t)n * Ll + l0 + tx] = __float2bfloat16((t[tx][ty + q * 8] - m) / s);
    }
}

// ---------------- LayerNorm over rows of DM -> bf16 ----------------
__global__ void ln_rows(const float* __restrict__ in, const float* __restrict__ w,
                        const float* __restrict__ bvec, bf16* __restrict__ out) {
    int row = blockIdx.x;
    int tid = threadIdx.x;
    float v = in[(size_t)row * DM + tid];
    float s1 = v, s2 = v * v;
    #pragma unroll
    for (int o = 32; o > 0; o >>= 1) { s1 += __shfl_down(s1, o, 64); s2 += __shfl_down(s2, o, 64); }
    __shared__ float l1[8], l2[8];
    int wv = tid >> 6, ln = tid & 63;
    if (ln == 0) { l1[wv] = s1; l2[wv] = s2; }
    __syncthreads();
    if (tid == 0) {
        float a = 0.f, c = 0.f;
        #pragma unroll
        for (int i = 0; i < DM / 64; i++) { a += l1[i]; c += l2[i]; }
        l1[0] = a; l2[0] = c;
    }
    __syncthreads();
    float mean = l1[0] / DM;
    float var = l2[0] / DM - mean * mean;
    float inv = rsqrtf(var + EPSf);
    out[(size_t)row * DM + tid] = __float2bfloat16((v - mean) * inv * w[tid] + bvec[tid]);
}

// ============ MFMA GEMM, 128x128 tile, BK=32, double-buffered, swizzled ============
// C = A(M,K) @ W(N,K)^T + bias. REVA: reverse A rows within 512-blocks.
// LDS rows are 64B: stripe half = row&1, so XOR-spread bits are (row>>1)&3.
template<int EPI, bool ACC, bool REVA, bool OUTBF>
__global__ __launch_bounds__(256) void gemm128(
    const bf16* __restrict__ A, int lda,
    const bf16* __restrict__ W,
    const float* __restrict__ bias,
    void* __restrict__ Cv, int ldc,
    int M, int Nn, int K) {
    __shared__ bf16 As[2][128 * 32];
    __shared__ bf16 Bs[2][128 * 32];
    int m0 = blockIdx.x * 128, n0 = blockIdx.y * 128;
    int tid = threadIdx.x;
    int w = tid >> 6, lane = tid & 63;
    int wm = (w >> 1) * 64, wn = (w & 1) * 64;
    f32x4 acc[4][4] = {};

    // staging: lane covers row (lane>>2), slot lane&3; pre-swizzle the GLOBAL slot
    int srow = w * 32 + (lane >> 2);
    int sslot = (lane & 3) ^ ((lane >> 3) & 3);          // slot ^ ((row>>1)&3)
    long arow0 = m0 + srow, arow1 = m0 + srow + 16;
    if (REVA) {
        arow0 = (arow0 & ~511L) | (511 - (arow0 & 511));
        arow1 = (arow1 & ~511L) | (511 - (arow1 & 511));
    }
    const char* agp0 = (const char*)(A + arow0 * (long)lda) + sslot * 16;
    const char* agp1 = (const char*)(A + arow1 * (long)lda) + sslot * 16;
    long wr0 = n0 + srow;      if (wr0 >= Nn) wr0 = Nn - 1;
    long wr1 = n0 + srow + 16; if (wr1 >= Nn) wr1 = Nn - 1;
    const char* wgp0 = (const char*)(W + wr0 * (long)K) + sslot * 16;
    const char* wgp1 = (const char*)(W + wr1 * (long)K) + sslot * 16;

    char* a0 = (char*)As[0]; char* a1 = (char*)As[1];
    char* b0 = (char*)Bs[0]; char* b1 = (char*)Bs[1];
    int dA0 = (w * 32) * 64, dA1 = (w * 32 + 16) * 64;

    int lrow = lane & 15;
    int salt = ((lane >> 4) ^ ((lane >> 1) & 3)) * 16;   // q ^ ((row>>1)&3), row≡lane&15

    const int nk = K >> 5;
#define STG128(pa, pb, ko) do { \
        GLL16(agp0 + (size_t)(ko) * 64, pa + dA0); \
        GLL16(agp1 + (size_t)(ko) * 64, pa + dA1); \
        GLL16(wgp0 + (size_t)(ko) * 64, pb + dA0); \
        GLL16(wgp1 + (size_t)(ko) * 64, pb + dA1); } while (0)

    STG128(a0, b0, 0);
    __syncthreads();
    for (int t = 0; t < nk; ++t) {
        char* ac = (t & 1) ? a1 : a0;
        char* bc = (t & 1) ? b1 : b0;
        if (t + 1 < nk) {
            char* an = (t & 1) ? a0 : a1;
            char* bn = (t & 1) ? b0 : b1;
            STG128(an, bn, t + 1);
        }
        bf16x8 af[4], bfr[4];
        #pragma unroll
        for (int i = 0; i < 4; i++) {
            af[i]  = *(const bf16x8*)(ac + (wm + i * 16 + lrow) * 64 + salt);
            bfr[i] = *(const bf16x8*)(bc + (wn + i * 16 + lrow) * 64 + salt);
        }
        #pragma unroll
        for (int i = 0; i < 4; i++)
            #pragma unroll
            for (int j = 0; j < 4; j++)
                acc[i][j] = __builtin_amdgcn_mfma_f32_16x16x32_bf16(af[i], bfr[j], acc[i][j], 0, 0, 0);
        __syncthreads();
    }
#undef STG128

    #pragma unroll
    for (int i = 0; i < 4; i++) {
        #pragma unroll
        for (int j = 0; j < 4; j++) {
            int n = n0 + wn + j * 16 + (lane & 15);
            if (n >= Nn) continue;
            float bv = bias ? bias[n] : 0.f;
            #pragma unroll
            for (int r = 0; r < 4; r++) {
                long m = m0 + wm + i * 16 + (lane >> 4) * 4 + r;
                float v = acc[i][j][r] + bv;
                if (EPI == 1) {
                    float x3 = v * v * v;
                    v = 0.5f * v * (1.f + tanhf(0.7978845608028654f * (v + 0.044715f * x3)));
                }
                if (OUTBF) {
                    ((bf16*)Cv)[m * (long)ldc + n] = __float2bfloat16(v);
                } else if (ACC) {
                    ((float*)Cv)[m * (long)ldc + n] += v;
                } else {
                    ((float*)Cv)[m * (long)ldc + n] = v;
                }
            }
        }
    }
}

// ============ MFMA GEMM, MTx64 tile (MT=128 or 64), BK=64, dbuf, swizzled ============
// 4 waves, each (MT/4)x64. 128B LDS rows: XOR-spread bits (row&7). 2-way = free.
template<int EPI, bool ACC, bool OUTBF, int MT>
__global__ __launch_bounds__(256) void gemm64(
    const bf16* __restrict__ A, int lda,
    const bf16* __restrict__ W,
    const float* __restrict__ bias,
    void* __restrict__ Cv, int ldc,
    int M, int Nn, int K) {
    constexpr int WR = MT / 4;      // rows per wave
    constexpr int IF = MT / 64;     // i-fragments per wave
    constexpr int AG = WR / 8;      // A staging groups per wave
    __shared__ bf16 As[2][MT * 64];
    __shared__ bf16 Bs[2][64 * 64];
    int m0 = blockIdx.x * MT, n0 = blockIdx.y * 64;
    int tid = threadIdx.x;
    int w = tid >> 6, lane = tid & 63;
    int wm = w * WR;
    f32x4 acc[IF][4] = {};

    int srow = lane >> 3;
    int sslot = (lane & 7) ^ srow;                      // slot ^ (row&7)
    const char* agp[AG];
    #pragma unroll
    for (int g = 0; g < AG; g++) {
        long ar = m0 + w * WR + g * 8 + srow;
        agp[g] = (const char*)(A + ar * (long)lda) + sslot * 16;
    }
    const char* wgp[2];
    #pragma unroll
    for (int g = 0; g < 2; g++) {
        long br = n0 + w * 16 + g * 8 + srow;
        if (br >= Nn) br = Nn - 1;
        wgp[g] = (const char*)(W + br * (long)K) + sslot * 16;
    }
    char* a0 = (char*)As[0]; char* a1 = (char*)As[1];
    char* b0 = (char*)Bs[0]; char* b1 = (char*)Bs[1];

    int lrow = lane & 15;
    int rk = lane & 7, hi = lane >> 4;
    int salt0 = (hi ^ rk) * 16;
    int salt1 = ((4 + hi) ^ rk) * 16;

    const int nk = K >> 6;
#define STG64(pa, pb, ko) do { \
        _Pragma("unroll") \
        for (int g = 0; g < AG; g++) \
            GLL16(agp[g] + (size_t)(ko) * 128, pa + (w * WR + g * 8) * 128); \
        _Pragma("unroll") \
        for (int g = 0; g < 2; g++) \
            GLL16(wgp[g] + (size_t)(ko) * 128, pb + (w * 16 + g * 8) * 128); } while (0)

    STG64(a0, b0, 0);
    __syncthreads();
    for (int t = 0; t < nk; ++t) {
        char* ac = (t & 1) ? a1 : a0;
        char* bc = (t & 1) ? b1 : b0;
        if (t + 1 < nk) {
            char* an = (t & 1) ? a0 : a1;
            char* bn = (t & 1) ? b0 : b1;
            STG64(an, bn, t + 1);
        }
        bf16x8 af[2][IF], bfr[2][4];
        #pragma unroll
        for (int i = 0; i < IF; i++) {
            af[0][i] = *(const bf16x8*)(ac + (wm + i * 16 + lrow) * 128 + salt0);
            af[1][i] = *(const bf16x8*)(ac + (wm + i * 16 + lrow) * 128 + salt1);
        }
        #pragma unroll
        for (int j = 0; j < 4; j++) {
            bfr[0][j] = *(const bf16x8*)(bc + (j * 16 + lrow) * 128 + salt0);
            bfr[1][j] = *(const bf16x8*)(bc + (j * 16 + lrow) * 128 + salt1);
        }
        #pragma unroll
        for (int kk = 0; kk < 2; kk++)
            #pragma unroll
            for (int i = 0; i < IF; i++)
                #pragma unroll
                for (int j = 0; j < 4; j++)
                    acc[i][j] = __builtin_amdgcn_mfma_f32_16x16x32_bf16(af[kk][i], bfr[kk][j], acc[i][j], 0, 0, 0);
        __syncthreads();
    }
#undef STG64

    #pragma unroll
    for (int i = 0; i < IF; i++) {
        #pragma unroll
        for (int j = 0; j < 4; j++) {
            int n = n0 + j * 16 + (lane & 15);
            if (n >= Nn) continue;
            float bv = bias ? bias[n] : 0.f;
            #pragma unroll
            for (int r = 0; r < 4; r++) {
                long m = m0 + wm + i * 16 + (lane >> 4) * 4 + r;
                float v = acc[i][j][r] + bv;
                if (EPI == 1) {
                    float x3 = v * v * v;
                    v = 0.5f * v * (1.f + tanhf(0.7978845608028654f * (v + 0.044715f * x3)));
                }
                if (OUTBF) {
                    ((bf16*)Cv)[m * (long)ldc + n] = __float2bfloat16(v);
                } else if (ACC) {
                    ((float*)Cv)[m * (long)ldc + n] += v;
                } else {
                    ((float*)Cv)[m * (long)ldc + n] = v;
                }
            }
        }
    }
}

// ---------------- fp32 GEMM (dt-proj, K=32) ----------------
template<int EPI, bool ACC>
__global__ __launch_bounds__(256) void gemm_awt(
    const float* __restrict__ A, int lda,
    const float* __restrict__ W,
    const float* __restrict__ bias,
    float* __restrict__ C, int ldc,
    int M, int Nn, int K) {
    __shared__ float Asm[16][68];
    __shared__ float Wsm[16][68];
    int m0 = blockIdx.x * 64;
    int n0 = blockIdx.y * 64;
    int tid = threadIdx.x;
    int tm = (tid / 16) * 4, tn = (tid % 16) * 4;
    float acc[4][4] = {};
    int lr = tid / 4;
    int lk = (tid % 4) * 4;
    const float* aptr = A + (size_t)(m0 + lr) * lda + lk;
    int wrow = n0 + lr;
    bool wok = wrow < Nn;
    const float* wptr = W + (size_t)wrow * K + lk;
    for (int k0 = 0; k0 < K; k0 += 16) {
        float4 av = *(const float4*)(aptr + k0);
        float4 wv = wok ? *(const float4*)(wptr + k0) : make_float4(0.f, 0.f, 0.f, 0.f);
        Asm[lk + 0][lr] = av.x; Asm[lk + 1][lr] = av.y; Asm[lk + 2][lr] = av.z; Asm[lk + 3][lr] = av.w;
        Wsm[lk + 0][lr] = wv.x; Wsm[lk + 1][lr] = wv.y; Wsm[lk + 2][lr] = wv.z; Wsm[lk + 3][lr] = wv.w;
        __syncthreads();
        #pragma unroll
        for (int kk = 0; kk < 16; kk++) {
            float4 a = *(const float4*)&Asm[kk][tm];
            float4 wv2 = *(const float4*)&Wsm[kk][tn];
            float ar[4] = {a.x, a.y, a.z, a.w};
            float wr[4] = {wv2.x, wv2.y, wv2.z, wv2.w};
            #pragma unroll
            for (int i = 0; i < 4; i++)
                #pragma unroll
                for (int j = 0; j < 4; j++)
                    acc[i][j] = fmaf(ar[i], wr[j], acc[i][j]);
        }
        __syncthreads();
    }
    #pragma unroll
    for (int i = 0; i < 4; i++) {
        int m = m0 + tm + i;
        #pragma unroll
        for (int j = 0; j < 4; j++) {
            int n = n0 + tn + j;
            if (n < Nn) {
                float r = acc[i][j];
                if (bias) r += bias[n];
                if (EPI == 2) r = fast_softplus(r);
                if (ACC) C[(size_t)m * ldc + n] += r;
                else     C[(size_t)m * ldc + n] = r;
            }
        }
    }
}

// ---------------- causal depthwise conv (k=4) + silu, dual output ----------------
__global__ void conv_silu(const float* __restrict__ xz, const float* __restrict__ cw,
                          const float* __restrict__ cb, float* __restrict__ u,
                          bf16* __restrict__ ub) {
    int c = blockIdx.x * 256 + threadIdx.x;
    int s0 = blockIdx.y * 16;
    int b = blockIdx.z;
    const float* src = xz + (size_t)b * Ss * (2 * DI) + c;
    float w0 = cw[c * 4 + 0], w1 = cw[c * 4 + 1], w2 = cw[c * 4 + 2], w3 = cw[c * 4 + 3];
    float bias = cb[c];
    float r0 = (s0 - 3 >= 0) ? src[(size_t)(s0 - 3) * (2 * DI)] : 0.f;
    float r1 = (s0 - 2 >= 0) ? src[(size_t)(s0 - 2) * (2 * DI)] : 0.f;
    float r2 = (s0 - 1 >= 0) ? src[(size_t)(s0 - 1) * (2 * DI)] : 0.f;
    for (int i = 0; i < 16; i++) {
        int s = s0 + i;
        float r3 = src[(size_t)s * (2 * DI)];
        float a = fmaf(r0, w0, fmaf(r1, w1, fmaf(r2, w2, fmaf(r3, w3, bias))));
        float v = a * fast_sig(a);
        u[((size_t)b * Ss + s) * DI + c] = v;
        ub[((size_t)b * Ss + s) * DI + c] = __float2bfloat16(v);
        r0 = r1; r1 = r2; r2 = r3;
    }
}

// ======== chunked parallel selective scan ========
__global__ __launch_bounds__(256) void scan_pass1(
    const float* __restrict__ delta, const float* __restrict__ u,
    const float* __restrict__ xdbl, const float* __restrict__ A_log,
    float* __restrict__ PB, float* __restrict__ HB) {
    int d = blockIdx.x * 256 + threadIdx.x;
    int c = blockIdx.y;
    int b = blockIdx.z;
    float Aj[DS], h[DS];
    #pragma unroll
    for (int j = 0; j < DS; j++) { Aj[j] = -fast_exp(A_log[(size_t)d * DS + j]); h[j] = 0.f; }
    const float* dp = delta + ((size_t)b * Ss + c * CH) * DI + d;
    const float* up = u + ((size_t)b * Ss + c * CH) * DI + d;
    const float* bc = xdbl + ((size_t)b * Ss + c * CH) * 64 + DTR;
    float dlsum = 0.f;
    for (int i = 0; i < CH; i++) {
        float dl = dp[(size_t)i * DI];
        float ut = up[(size_t)i * DI];
        float du = dl * ut;
        dlsum += dl;
        const float4* q4 = (const float4*)(bc + (size_t)i * 64);
        float4 B0 = q4[0], B1 = q4[1], B2 = q4[2], B3 = q4[3];
        float Bv[DS] = {B0.x, B0.y, B0.z, B0.w, B1.x, B1.y, B1.z, B1.w,
                        B2.x, B2.y, B2.z, B2.w, B3.x, B3.y, B3.z, B3.w};
        #pragma unroll
        for (int j = 0; j < DS; j++) {
            float a = fast_exp(dl * Aj[j]);
            h[j] = fmaf(a, h[j], du * Bv[j]);
        }
    }
    size_t base = ((size_t)(b * NCH + c)) * DS * DI + d;
    #pragma unroll
    for (int j = 0; j < DS; j++) {
        PB[base + (size_t)j * DI] = fast_exp(dlsum * Aj[j]);
        HB[base + (size_t)j * DI] = h[j];
    }
}

__global__ __launch_bounds__(256) void scan_pass2(
    const float* __restrict__ PB, const float* __restrict__ HB, float* __restrict__ HIN) {
    int idx = blockIdx.x * 256 + threadIdx.x;
    int b = idx >> 14;
    int rem = idx & 16383;
    float h = 0.f;
    #pragma unroll
    for (int c = 0; c < NCH; c++) {
        size_t o = ((size_t)(b * NCH + c)) * (DS * DI) + rem;
        float p = PB[o], hl = HB[o];
        HIN[o] = h;
        h = fmaf(p, h, hl);
    }
}

// REV: write y back in ORIGINAL row order (folds REVC into the scan epilogue)
template<bool REV>
__global__ __launch_bounds__(256) void scan_pass3(
    const float* __restrict__ delta, const float* __restrict__ u,
    const float* __restrict__ xdbl, const float* __restrict__ xz,
    const float* __restrict__ A_log, const float* __restrict__ Dp,
    const float* __restrict__ HIN, bf16* __restrict__ y) {
    int d = blockIdx.x * 256 + threadIdx.x;
    int c = blockIdx.y;
    int b = blockIdx.z;
    float Aj[DS], h[DS];
    size_t hbase = ((size_t)(b * NCH + c)) * DS * DI + d;
    #pragma unroll
    for (int j = 0; j < DS; j++) {
        Aj[j] = -fast_exp(A_log[(size_t)d * DS + j]);
        h[j] = HIN[hbase + (size_t)j * DI];
    }
    float Dd = Dp[d];
    const float* dp = delta + ((size_t)b * Ss + c * CH) * DI + d;
    const float* up = u + ((size_t)b * Ss + c * CH) * DI + d;
    const float* zp = xz + ((size_t)b * Ss + c * CH) * (2 * DI) + DI + d;
    const float* bc = xdbl + ((size_t)b * Ss + c * CH) * 64 + DTR;
    for (int i = 0; i < CH; i++) {
        float dl = dp[(size_t)i * DI];
        float ut = up[(size_t)i * DI];
        float zz = zp[(size_t)i * (2 * DI)];
        float du = dl * ut;
        const float4* q4 = (const float4*)(bc + (size_t)i * 64);
        float4 B0 = q4[0], B1 = q4[1], B2 = q4[2], B3 = q4[3];
        float4 C0 = q4[4], C1 = q4[5], C2 = q4[6], C3 = q4[7];
        float Bv[DS] = {B0.x, B0.y, B0.z, B0.w, B1.x, B1.y, B1.z, B1.w,
                        B2.x, B2.y, B2.z, B2.w, B3.x, B3.y, B3.z, B3.w};
        float Cv[DS] = {C0.x, C0.y, C0.z, C0.w, C1.x, C1.y, C1.z, C1.w,
                        C2.x, C2.y, C2.z, C2.w, C3.x, C3.y, C3.z, C3.w};
        float acc = 0.f;
        #pragma unroll
        for (int j = 0; j < DS; j++) {
            float a = fast_exp(dl * Aj[j]);
            h[j] = fmaf(a, h[j], du * Bv[j]);
            acc = fmaf(h[j], Cv[j], acc);
        }
        float sg = fast_sig(zz);
        int sidx = c * CH + i;
        int so = REV ? (Ss - 1 - sidx) : sidx;
        y[((size_t)b * Ss + so) * DI + d] = __float2bfloat16((acc + ut * Dd) * (zz * sg));
    }
}

// ---------------- final: out[b,h,n] = pred[b,n,h]*sd + mu ----------------
__global__ void finalize_out(const float* __restrict__ pred, const float* __restrict__ mu,
                             const float* __restrict__ sd, float* __restrict__ out) {
    int n = threadIdx.x;
    int h = blockIdx.x;
    int b = blockIdx.y;
    out[((size_t)b * Hh + h) * NV + n] =
        pred[((size_t)b * NV + n) * Hh + h] * sd[b * NV + n] + mu[b * NV + n];
}

extern "C" void kernel_launch(void* const* d_in, const int* in_sizes, int n_in,
                              void* d_out, int out_size, void* d_ws, size_t ws_size,
                              hipStream_t stream) {
    const float* x     = (const float*)d_in[0];
    const float* tokw  = (const float*)d_in[1];
    const float* tokb  = (const float*)d_in[2];
    const float* in_w  = (const float*)d_in[3];
    const float* in_b  = (const float*)d_in[4];
    const float* convw = (const float*)d_in[5];
    const float* convb = (const float*)d_in[6];
    const float* xpw   = (const float*)d_in[7];
    const float* dtw   = (const float*)d_in[8];
    const float* dtb   = (const float*)d_in[9];
    const float* Alog  = (const float*)d_in[10];
    const float* Dm    = (const float*)d_in[11];
    const float* outw  = (const float*)d_in[12];
    const float* outb  = (const float*)d_in[13];
    const float* mnw   = (const float*)d_in[14];
    const float* mnb   = (const float*)d_in[15];
    const float* fnw   = (const float*)d_in[16];
    const float* fnb   = (const float*)d_in[17];
    const float* fw1   = (const float*)d_in[18];
    const float* fb1   = (const float*)d_in[19];
    const float* fw2   = (const float*)d_in[20];
    const float* fb2   = (const float*)d_in[21];
    const float* nw    = (const float*)d_in[22];
    const float* nb    = (const float*)d_in[23];
    const float* hw    = (const float*)d_in[24];
    const float* hb    = (const float*)d_in[25];

    float* ws = (float*)d_ws;
    float* MU  = ws;
    float* SD  = MU + Bb * NV;
    float* XNT = SD + Bb * NV;
    float* T   = XNT + (size_t)Bb * NV * Ll;
    float* YN  = T + (size_t)Bb * NV * DM;
    float* XZ  = YN + (size_t)Bb * NV * DM;
    float* U   = XZ + (size_t)MROWS * 2 * DI;
    float* XD  = U + (size_t)MROWS * DI;
    float* DEL = XD + (size_t)MROWS * 64;
    float* Y   = DEL + (size_t)MROWS * DI;
    float* PRED = Y + (size_t)MROWS * DI;
    float* WBF  = PRED + (size_t)MROWS * Hh;

    bf16* XNTb = (bf16*)XNT;
    bf16* YNb  = (bf16*)YN;
    bf16* XZb  = (bf16*)XZ;
    bf16* Ub   = (bf16*)DEL;
    bf16* Yb   = (bf16*)Y;
    float* PB  = Y;
    float* HB  = Y + (size_t)Bb * NCH * DS * DI;
    float* HIN = XNT;

    bf16* wb = (bf16*)WBF;
    bf16* tokwb = wb;              wb += (size_t)DM * Ll;
    bf16* inwb  = wb;              wb += (size_t)NLAY * 2 * 2 * DI * DM;
    bf16* xpwb  = wb;              wb += (size_t)NLAY * 2 * 64 * DI;
    bf16* outwb = wb;              wb += (size_t)NLAY * 2 * DM * DI;
    bf16* fw1b  = wb;              wb += (size_t)NLAY * DFF * DM;
    bf16* fw2b  = wb;              wb += (size_t)NLAY * DM * DFF;
    bf16* hwb   = wb;              wb += (size_t)Hh * DM;
    float* PS1  = (float*)wb;
    float* PS2  = PS1 + Bb * 8 * NV;

    f2bf<<<(DM * Ll) / 1024, 256, 0, stream>>>(tokw, tokwb, DM * Ll);
    f2bf<<<(NLAY * 2 * 2 * DI * DM) / 1024, 256, 0, stream>>>(in_w, inwb, NLAY * 2 * 2 * DI * DM);
    f2bf<<<(NLAY * 2 * 64 * DI) / 1024, 256, 0, stream>>>(xpw, xpwb, NLAY * 2 * 64 * DI);
    f2bf<<<(NLAY * 2 * DM * DI) / 1024, 256, 0, stream>>>(outw, outwb, NLAY * 2 * DM * DI);
    f2bf<<<(NLAY * DFF * DM) / 1024, 256, 0, stream>>>(fw1, fw1b, NLAY * DFF * DM);
    f2bf<<<(NLAY * DM * DFF) / 1024, 256, 0, stream>>>(fw2, fw2b, NLAY * DM * DFF);
    f2bf<<<(Hh * DM) / 1024, 256, 0, stream>>>(hw, hwb, Hh * DM);

    revin_partial<<<dim3(Bb, 8), NV, 0, stream>>>(x, PS1, PS2);
    revin_final<<<Bb, NV, 0, stream>>>(PS1, PS2, MU, SD);
    transpose_norm<<<dim3(Ll / 32, NV / 32, Bb), dim3(32, 8), 0, stream>>>(x, MU, SD, XNTb);
    gemm64<0, false, false, 128><<<dim3(MROWS / 128, DM / 64), 256, 0, stream>>>(
        XNTb, Ll, tokwb, tokb, T, DM, MROWS, DM, Ll);

    for (int l = 0; l < NLAY; l++) {
        ln_rows<<<MROWS, DM, 0, stream>>>(T, mnw + l * DM, mnb + l * DM, YNb);
        for (int dir = 0; dir < 2; dir++) {
            int pd = l * 2 + dir;
            const bf16* iw = inwb + (size_t)pd * 2 * DI * DM;
            const float* ib = in_b + (size_t)pd * 2 * DI;
            if (dir == 0)
                gemm128<0, false, false, false><<<dim3(MROWS / 128, (2 * DI) / 128), 256, 0, stream>>>(
                    YNb, DM, iw, ib, XZ, 2 * DI, MROWS, 2 * DI, DM);
            else
                gemm128<0, false, true, false><<<dim3(MROWS / 128, (2 * DI) / 128), 256, 0, stream>>>(
                    YNb, DM, iw, ib, XZ, 2 * DI, MROWS, 2 * DI, DM);
            conv_silu<<<dim3(DI / 256, Ss / 16, Bb), 256, 0, stream>>>(
                XZ, convw + (size_t)pd * DI * DCONV, convb + pd * DI, U, Ub);
            gemm64<0, false, false, 64><<<dim3(MROWS / 64, 1), 256, 0, stream>>>(
                Ub, DI, xpwb + (size_t)pd * 64 * DI, nullptr, XD, 64, MROWS, 64, DI);
            gemm_awt<2, false><<<dim3(MROWS / 64, DI / 64), 256, 0, stream>>>(
                XD, 64, dtw + (size_t)pd * DI * DTR, dtb + pd * DI, DEL, DI, MROWS, DI, DTR);
            scan_pass1<<<dim3(DI / 256, NCH, Bb), 256, 0, stream>>>(
                DEL, U, XD, Alog + (size_t)pd * DI * DS, PB, HB);
            scan_pass2<<<(Bb * DS * DI) / 256, 256, 0, stream>>>(PB, HB, HIN);
            if (dir == 0)
                scan_pass3<false><<<dim3(DI / 256, NCH, Bb), 256, 0, stream>>>(
                    DEL, U, XD, XZ, Alog + (size_t)pd * DI * DS, Dm + pd * DI, HIN, Yb);
            else
                scan_pass3<true><<<dim3(DI / 256, NCH, Bb), 256, 0, stream>>>(
                    DEL, U, XD, XZ, Alog + (size_t)pd * DI * DS, Dm + pd * DI, HIN, Yb);
            gemm64<0, true, false, 128><<<dim3(MROWS / 128, DM / 64), 256, 0, stream>>>(
                Yb, DI, outwb + (size_t)pd * DM * DI, outb + pd * DM, T, DM, MROWS, DM, DI);
        }
        // FFN
        ln_rows<<<MROWS, DM, 0, stream>>>(T, fnw + l * DM, fnb + l * DM, YNb);
        gemm128<1, false, false, true><<<dim3(MROWS / 128, DFF / 128), 256, 0, stream>>>(
            YNb, DM, fw1b + (size_t)l * DFF * DM, fb1 + l * DFF, XZb, DFF, MROWS, DFF, DM);
        gemm64<0, true, false, 128><<<dim3(MROWS / 128, DM / 64), 256, 0, stream>>>(
            XZb, DFF, fw2b + (size_t)l * DM * DFF, fb2 + l * DM, T, DM, MROWS, DM, DFF);
    }
    ln_rows<<<MROWS, DM, 0, stream>>>(T, nw, nb, YNb);
    gemm64<0, false, false, 64><<<dim3(MROWS / 64, 2), 256, 0, stream>>>(
        YNb, DM, hwb, hb, PRED, Hh, MROWS, Hh, DM);
    finalize_out<<<dim3(Hh, Bb), NV, 0, stream>>>(PRED, MU, SD, (float*)d_out);
}

// Round 8
// 942.229 us; speedup vs baseline: 5.1541x; 1.0515x over previous
//
#include <hip/hip_runtime.h>
#include <hip/hip_bf16.h>

#define Bb 16
#define Ll 512
#define NV 512
#define DM 512
#define DS 16
#define NLAY 2
#define DFF 2048
#define DI 1024
#define DCONV 4
#define DTR 32
#define Hh 96
#define Ss NV
#define MROWS (Bb*Ss)
#define EPSf 1e-5f
#define CH 32
#define NCH (Ss/CH)

typedef __hip_bfloat16 bf16;
typedef __attribute__((ext_vector_type(8))) short bf16x8;
typedef __attribute__((ext_vector_type(4))) float f32x4;

#define GLL16(g, l) __builtin_amdgcn_global_load_lds( \
    (const __attribute__((address_space(1))) unsigned int*)(g), \
    (__attribute__((address_space(3))) unsigned int*)(l), 16, 0, 0)

__device__ __forceinline__ float fast_exp(float x) { return __expf(x); }
__device__ __forceinline__ float fast_sig(float x) {
    return __builtin_amdgcn_rcpf(1.f + __expf(-x));
}
__device__ __forceinline__ float fast_softplus(float r) {
    float e = __expf(-fabsf(r));
    return fmaxf(r, 0.f) + __logf(1.f + e);
}
__device__ __forceinline__ float b2f(bf16 v) { return __bfloat162float(v); }

// ---------------- fp32 -> bf16 convert ----------------
__global__ void f2bf(const float* __restrict__ in, bf16* __restrict__ out, int n) {
    int i = (blockIdx.x * 256 + threadIdx.x) * 4;
    if (i < n) {
        float4 v = *(const float4*)(in + i);
        out[i + 0] = __float2bfloat16(v.x);
        out[i + 1] = __float2bfloat16(v.y);
        out[i + 2] = __float2bfloat16(v.z);
        out[i + 3] = __float2bfloat16(v.w);
    }
}

// repack out_w (NL,2,DM,DI) -> outwcat (NL, DM, 2*DI) bf16 with K = [dir0 | dir1]
__global__ void repack_outw(const float* __restrict__ outw, bf16* __restrict__ outwcat) {
    int idx = (blockIdx.x * 256 + threadIdx.x) * 4;   // over NLAY*DM*2048
    int k2 = idx & 2047;
    int rest = idx >> 11;           // l*DM + n
    int l = rest >> 9, n = rest & 511;
    int dirk = k2 >> 10, k = k2 & 1023;
    const float* s = outw + (((size_t)(l * 2 + dirk) * DM + n) * DI + k);
    float4 v = *(const float4*)s;
    bf16* dpt = outwcat + (size_t)idx;
    dpt[0] = __float2bfloat16(v.x);
    dpt[1] = __float2bfloat16(v.y);
    dpt[2] = __float2bfloat16(v.z);
    dpt[3] = __float2bfloat16(v.w);
}

__global__ void sum_outb(const float* __restrict__ outb, float* __restrict__ outbsum) {
    int i = blockIdx.x * 256 + threadIdx.x;   // NLAY*DM
    int l = i >> 9, n = i & 511;
    outbsum[i] = outb[(l * 2 + 0) * DM + n] + outb[(l * 2 + 1) * DM + n];
}

// ---------------- RevIN stats (two-stage) ----------------
__global__ void revin_partial(const float* __restrict__ x, float* __restrict__ ps1,
                              float* __restrict__ ps2) {
    int b = blockIdx.x, c = blockIdx.y, n = threadIdx.x;
    const float* xp = x + (size_t)b * Ll * NV + (size_t)c * (Ll / 8) * NV + n;
    float s1 = 0.f, s2 = 0.f;
    #pragma unroll 4
    for (int l = 0; l < Ll / 8; l++) { float v = xp[(size_t)l * NV]; s1 += v; s2 += v * v; }
    ps1[((size_t)b * 8 + c) * NV + n] = s1;
    ps2[((size_t)b * 8 + c) * NV + n] = s2;
}

__global__ void revin_final(const float* __restrict__ ps1, const float* __restrict__ ps2,
                            float* __restrict__ mu, float* __restrict__ sd) {
    int b = blockIdx.x, n = threadIdx.x;
    float s1 = 0.f, s2 = 0.f;
    #pragma unroll
    for (int c = 0; c < 8; c++) {
        s1 += ps1[((size_t)b * 8 + c) * NV + n];
        s2 += ps2[((size_t)b * 8 + c) * NV + n];
    }
    float m = s1 / Ll;
    float var = s2 / Ll - m * m;
    mu[b * NV + n] = m;
    sd[b * NV + n] = sqrtf(var + EPSf);
}

// ------------- normalize + transpose -> bf16: xnT[b,n,l] -------------
__global__ void transpose_norm(const float* __restrict__ x, const float* __restrict__ mu,
                               const float* __restrict__ sd, bf16* __restrict__ xnT) {
    __shared__ float t[32][33];
    int b = blockIdx.z;
    int l0 = blockIdx.x * 32, n0 = blockIdx.y * 32;
    int tx = threadIdx.x, ty = threadIdx.y; // 32x8
    #pragma unroll
    for (int q = 0; q < 4; q++)
        t[ty + q * 8][tx] = x[(size_t)b * Ll * NV + (size_t)(l0 + ty + q * 8) * NV + n0 + tx];
    __syncthreads();
    #pragma unroll
    for (int q = 0; q < 4; q++) {
        int n = n0 + ty + q * 8;
        float m = mu[b * NV + n], s = sd[b * NV + n];
        xnT[(size_t)b * NV * Ll + (size_t)n * Ll + l0 + tx] = __float2bfloat16((t[tx][ty + q * 8] - m) / s);
    }
}

// ---------------- LayerNorm over rows of DM -> bf16 ----------------
__global__ void ln_rows(const float* __restrict__ in, const float* __restrict__ w,
                        const float* __restrict__ bvec, bf16* __restrict__ out) {
    int row = blockIdx.x;
    int tid = threadIdx.x;
    float v = in[(size_t)row * DM + tid];
    float s1 = v, s2 = v * v;
    #pragma unroll
    for (int o = 32; o > 0; o >>= 1) { s1 += __shfl_down(s1, o, 64); s2 += __shfl_down(s2, o, 64); }
    __shared__ float l1[8], l2[8];
    int wv = tid >> 6, ln = tid & 63;
    if (ln == 0) { l1[wv] = s1; l2[wv] = s2; }
    __syncthreads();
    if (tid == 0) {
        float a = 0.f, c = 0.f;
        #pragma unroll
        for (int i = 0; i < DM / 64; i++) { a += l1[i]; c += l2[i]; }
        l1[0] = a; l2[0] = c;
    }
    __syncthreads();
    float mean = l1[0] / DM;
    float var = l2[0] / DM - mean * mean;
    float inv = rsqrtf(var + EPSf);
    out[(size_t)row * DM + tid] = __float2bfloat16((v - mean) * inv * w[tid] + bvec[tid]);
}

// ============ MFMA GEMM, 128x128 tile, BK=32, double-buffered, swizzled ============
template<int EPI, bool ACC, bool OUTBF>
__global__ __launch_bounds__(256) void gemm128(
    const bf16* __restrict__ A, int lda,
    const bf16* __restrict__ W,
    const float* __restrict__ bias,
    void* __restrict__ Cv, int ldc,
    int M, int Nn, int K) {
    __shared__ bf16 As[2][128 * 32];
    __shared__ bf16 Bs[2][128 * 32];
    int m0 = blockIdx.x * 128, n0 = blockIdx.y * 128;
    int tid = threadIdx.x;
    int w = tid >> 6, lane = tid & 63;
    int wm = (w >> 1) * 64, wn = (w & 1) * 64;
    f32x4 acc[4][4] = {};

    int srow = w * 32 + (lane >> 2);
    int sslot = (lane & 3) ^ ((lane >> 3) & 3);          // slot ^ ((row>>1)&3)
    long arow0 = m0 + srow, arow1 = m0 + srow + 16;
    const char* agp0 = (const char*)(A + arow0 * (long)lda) + sslot * 16;
    const char* agp1 = (const char*)(A + arow1 * (long)lda) + sslot * 16;
    long wr0 = n0 + srow;      if (wr0 >= Nn) wr0 = Nn - 1;
    long wr1 = n0 + srow + 16; if (wr1 >= Nn) wr1 = Nn - 1;
    const char* wgp0 = (const char*)(W + wr0 * (long)K) + sslot * 16;
    const char* wgp1 = (const char*)(W + wr1 * (long)K) + sslot * 16;

    char* a0 = (char*)As[0]; char* a1 = (char*)As[1];
    char* b0 = (char*)Bs[0]; char* b1 = (char*)Bs[1];
    int dA0 = (w * 32) * 64, dA1 = (w * 32 + 16) * 64;

    int lrow = lane & 15;
    int salt = ((lane >> 4) ^ ((lane >> 1) & 3)) * 16;

    const int nk = K >> 5;
#define STG128(pa, pb, ko) do { \
        GLL16(agp0 + (size_t)(ko) * 64, pa + dA0); \
        GLL16(agp1 + (size_t)(ko) * 64, pa + dA1); \
        GLL16(wgp0 + (size_t)(ko) * 64, pb + dA0); \
        GLL16(wgp1 + (size_t)(ko) * 64, pb + dA1); } while (0)

    STG128(a0, b0, 0);
    __syncthreads();
    for (int t = 0; t < nk; ++t) {
        char* ac = (t & 1) ? a1 : a0;
        char* bc = (t & 1) ? b1 : b0;
        if (t + 1 < nk) {
            char* an = (t & 1) ? a0 : a1;
            char* bn = (t & 1) ? b0 : b1;
            STG128(an, bn, t + 1);
        }
        bf16x8 af[4], bfr[4];
        #pragma unroll
        for (int i = 0; i < 4; i++) {
            af[i]  = *(const bf16x8*)(ac + (wm + i * 16 + lrow) * 64 + salt);
            bfr[i] = *(const bf16x8*)(bc + (wn + i * 16 + lrow) * 64 + salt);
        }
        #pragma unroll
        for (int i = 0; i < 4; i++)
            #pragma unroll
            for (int j = 0; j < 4; j++)
                acc[i][j] = __builtin_amdgcn_mfma_f32_16x16x32_bf16(af[i], bfr[j], acc[i][j], 0, 0, 0);
        __syncthreads();
    }
#undef STG128

    #pragma unroll
    for (int i = 0; i < 4; i++) {
        #pragma unroll
        for (int j = 0; j < 4; j++) {
            int n = n0 + wn + j * 16 + (lane & 15);
            if (n >= Nn) continue;
            float bv = bias ? bias[n] : 0.f;
            #pragma unroll
            for (int r = 0; r < 4; r++) {
                long m = m0 + wm + i * 16 + (lane >> 4) * 4 + r;
                float v = acc[i][j][r] + bv;
                if (EPI == 1) {
                    float x3 = v * v * v;
                    v = 0.5f * v * (1.f + tanhf(0.7978845608028654f * (v + 0.044715f * x3)));
                }
                if (OUTBF) {
                    ((bf16*)Cv)[m * (long)ldc + n] = __float2bfloat16(v);
                } else if (ACC) {
                    ((float*)Cv)[m * (long)ldc + n] += v;
                } else {
                    ((float*)Cv)[m * (long)ldc + n] = v;
                }
            }
        }
    }
}

// ============ MFMA GEMM, MTx64 tile (MT=128 or 64), BK=64, dbuf, swizzled ============
template<int EPI, bool ACC, bool OUTBF, int MT>
__global__ __launch_bounds__(256) void gemm64(
    const bf16* __restrict__ A, int lda,
    const bf16* __restrict__ W,
    const float* __restrict__ bias,
    void* __restrict__ Cv, int ldc,
    int M, int Nn, int K) {
    constexpr int WR = MT / 4;
    constexpr int IF = MT / 64;
    constexpr int AG = WR / 8;
    __shared__ bf16 As[2][MT * 64];
    __shared__ bf16 Bs[2][64 * 64];
    int m0 = blockIdx.x * MT, n0 = blockIdx.y * 64;
    int tid = threadIdx.x;
    int w = tid >> 6, lane = tid & 63;
    int wm = w * WR;
    f32x4 acc[IF][4] = {};

    int srow = lane >> 3;
    int sslot = (lane & 7) ^ srow;
    const char* agp[AG];
    #pragma unroll
    for (int g = 0; g < AG; g++) {
        long ar = m0 + w * WR + g * 8 + srow;
        agp[g] = (const char*)(A + ar * (long)lda) + sslot * 16;
    }
    const char* wgp[2];
    #pragma unroll
    for (int g = 0; g < 2; g++) {
        long br = n0 + w * 16 + g * 8 + srow;
        if (br >= Nn) br = Nn - 1;
        wgp[g] = (const char*)(W + br * (long)K) + sslot * 16;
    }
    char* a0 = (char*)As[0]; char* a1 = (char*)As[1];
    char* b0 = (char*)Bs[0]; char* b1 = (char*)Bs[1];

    int lrow = lane & 15;
    int rk = lane & 7, hi = lane >> 4;
    int salt0 = (hi ^ rk) * 16;
    int salt1 = ((4 + hi) ^ rk) * 16;

    const int nk = K >> 6;
#define STG64(pa, pb, ko) do { \
        _Pragma("unroll") \
        for (int g = 0; g < AG; g++) \
            GLL16(agp[g] + (size_t)(ko) * 128, pa + (w * WR + g * 8) * 128); \
        _Pragma("unroll") \
        for (int g = 0; g < 2; g++) \
            GLL16(wgp[g] + (size_t)(ko) * 128, pb + (w * 16 + g * 8) * 128); } while (0)

    STG64(a0, b0, 0);
    __syncthreads();
    for (int t = 0; t < nk; ++t) {
        char* ac = (t & 1) ? a1 : a0;
        char* bc = (t & 1) ? b1 : b0;
        if (t + 1 < nk) {
            char* an = (t & 1) ? a0 : a1;
            char* bn = (t & 1) ? b0 : b1;
            STG64(an, bn, t + 1);
        }
        bf16x8 af[2][IF], bfr[2][4];
        #pragma unroll
        for (int i = 0; i < IF; i++) {
            af[0][i] = *(const bf16x8*)(ac + (wm + i * 16 + lrow) * 128 + salt0);
            af[1][i] = *(const bf16x8*)(ac + (wm + i * 16 + lrow) * 128 + salt1);
        }
        #pragma unroll
        for (int j = 0; j < 4; j++) {
            bfr[0][j] = *(const bf16x8*)(bc + (j * 16 + lrow) * 128 + salt0);
            bfr[1][j] = *(const bf16x8*)(bc + (j * 16 + lrow) * 128 + salt1);
        }
        #pragma unroll
        for (int kk = 0; kk < 2; kk++)
            #pragma unroll
            for (int i = 0; i < IF; i++)
                #pragma unroll
                for (int j = 0; j < 4; j++)
                    acc[i][j] = __builtin_amdgcn_mfma_f32_16x16x32_bf16(af[kk][i], bfr[kk][j], acc[i][j], 0, 0, 0);
        __syncthreads();
    }
#undef STG64

    #pragma unroll
    for (int i = 0; i < IF; i++) {
        #pragma unroll
        for (int j = 0; j < 4; j++) {
            int n = n0 + j * 16 + (lane & 15);
            if (n >= Nn) continue;
            float bv = bias ? bias[n] : 0.f;
            #pragma unroll
            for (int r = 0; r < 4; r++) {
                long m = m0 + wm + i * 16 + (lane >> 4) * 4 + r;
                float v = acc[i][j][r] + bv;
                if (EPI == 1) {
                    float x3 = v * v * v;
                    v = 0.5f * v * (1.f + tanhf(0.7978845608028654f * (v + 0.044715f * x3)));
                }
                if (OUTBF) {
                    ((bf16*)Cv)[m * (long)ldc + n] = __float2bfloat16(v);
                } else if (ACC) {
                    ((float*)Cv)[m * (long)ldc + n] += v;
                } else {
                    ((float*)Cv)[m * (long)ldc + n] = v;
                }
            }
        }
    }
}

// ---------------- fp32 GEMM (dt-proj, K=32) ----------------
template<int EPI, bool ACC>
__global__ __launch_bounds__(256) void gemm_awt(
    const float* __restrict__ A, int lda,
    const float* __restrict__ W,
    const float* __restrict__ bias,
    float* __restrict__ C, int ldc,
    int M, int Nn, int K) {
    __shared__ float Asm[16][68];
    __shared__ float Wsm[16][68];
    int m0 = blockIdx.x * 64;
    int n0 = blockIdx.y * 64;
    int tid = threadIdx.x;
    int tm = (tid / 16) * 4, tn = (tid % 16) * 4;
    float acc[4][4] = {};
    int lr = tid / 4;
    int lk = (tid % 4) * 4;
    const float* aptr = A + (size_t)(m0 + lr) * lda + lk;
    int wrow = n0 + lr;
    bool wok = wrow < Nn;
    const float* wptr = W + (size_t)wrow * K + lk;
    for (int k0 = 0; k0 < K; k0 += 16) {
        float4 av = *(const float4*)(aptr + k0);
        float4 wv = wok ? *(const float4*)(wptr + k0) : make_float4(0.f, 0.f, 0.f, 0.f);
        Asm[lk + 0][lr] = av.x; Asm[lk + 1][lr] = av.y; Asm[lk + 2][lr] = av.z; Asm[lk + 3][lr] = av.w;
        Wsm[lk + 0][lr] = wv.x; Wsm[lk + 1][lr] = wv.y; Wsm[lk + 2][lr] = wv.z; Wsm[lk + 3][lr] = wv.w;
        __syncthreads();
        #pragma unroll
        for (int kk = 0; kk < 16; kk++) {
            float4 a = *(const float4*)&Asm[kk][tm];
            float4 wv2 = *(const float4*)&Wsm[kk][tn];
            float ar[4] = {a.x, a.y, a.z, a.w};
            float wr[4] = {wv2.x, wv2.y, wv2.z, wv2.w};
            #pragma unroll
            for (int i = 0; i < 4; i++)
                #pragma unroll
                for (int j = 0; j < 4; j++)
                    acc[i][j] = fmaf(ar[i], wr[j], acc[i][j]);
        }
        __syncthreads();
    }
    #pragma unroll
    for (int i = 0; i < 4; i++) {
        int m = m0 + tm + i;
        #pragma unroll
        for (int j = 0; j < 4; j++) {
            int n = n0 + tn + j;
            if (n < Nn) {
                float r = acc[i][j];
                if (bias) r += bias[n];
                if (EPI == 2) r = fast_softplus(r);
                if (ACC) C[(size_t)m * ldc + n] += r;
                else     C[(size_t)m * ldc + n] = r;
            }
        }
    }
}

// ---------- causal/anticausal depthwise conv (k=4) + silu, both dirs, bf16 in/out ----------
// XZb: [MROWS, 4096] = [u0|z0|u1|z1]; Ub: [MROWS, 2048] = [u0|u1]
__global__ void conv_both(const bf16* __restrict__ xz, const float* __restrict__ cw_l,
                          const float* __restrict__ cb_l, bf16* __restrict__ ub) {
    int c2 = blockIdx.x * 256 + threadIdx.x;   // 0..2047
    int dir = c2 >> 10, c = c2 & 1023;
    int s0 = blockIdx.y * 16;
    int b = blockIdx.z;
    const bf16* src = xz + (size_t)b * Ss * 4096 + (size_t)dir * 2048 + c;
    const float* cw = cw_l + (dir * DI + c) * 4;
    float w0 = cw[0], w1 = cw[1], w2 = cw[2], w3 = cw[3];
    float bias = cb_l[dir * DI + c];
    bf16* dst = ub + (size_t)b * Ss * 2048 + (size_t)dir * 1024 + c;
    if (dir == 0) {   // causal: window [s-3, s]
        float r0 = (s0 - 3 >= 0) ? b2f(src[(size_t)(s0 - 3) * 4096]) : 0.f;
        float r1 = (s0 - 2 >= 0) ? b2f(src[(size_t)(s0 - 2) * 4096]) : 0.f;
        float r2 = (s0 - 1 >= 0) ? b2f(src[(size_t)(s0 - 1) * 4096]) : 0.f;
        for (int i = 0; i < 16; i++) {
            int s = s0 + i;
            float r3 = b2f(src[(size_t)s * 4096]);
            float a = fmaf(r0, w0, fmaf(r1, w1, fmaf(r2, w2, fmaf(r3, w3, bias))));
            dst[(size_t)s * 2048] = __float2bfloat16(a * fast_sig(a));
            r0 = r1; r1 = r2; r2 = r3;
        }
    } else {          // reverse: window [s, s+3], flipped kernel
        float f0 = b2f(src[(size_t)s0 * 4096]);
        float f1 = (s0 + 1 < Ss) ? b2f(src[(size_t)(s0 + 1) * 4096]) : 0.f;
        float f2 = (s0 + 2 < Ss) ? b2f(src[(size_t)(s0 + 2) * 4096]) : 0.f;
        float f3 = (s0 + 3 < Ss) ? b2f(src[(size_t)(s0 + 3) * 4096]) : 0.f;
        for (int i = 0; i < 16; i++) {
            int s = s0 + i;
            float a = fmaf(f0, w3, fmaf(f1, w2, fmaf(f2, w1, fmaf(f3, w0, bias))));
            dst[(size_t)s * 2048] = __float2bfloat16(a * fast_sig(a));
            f0 = f1; f1 = f2; f2 = f3;
            f3 = (s + 4 < Ss) ? b2f(src[(size_t)(s + 4) * 4096]) : 0.f;
        }
    }
}

// ======== chunked parallel selective scan (REV = backward over original order) ========
template<bool REV>
__global__ __launch_bounds__(256) void scan_pass1(
    const float* __restrict__ delta,   // [MROWS, DI]
    const bf16* __restrict__ ub,       // Ub + dir*1024, stride 2048
    const float* __restrict__ xdbl,    // XD, stride 64 (B at +32)
    const float* __restrict__ A_log,
    float* __restrict__ PB, float* __restrict__ HB) {
    int d = blockIdx.x * 256 + threadIdx.x;
    int c = blockIdx.y;
    int b = blockIdx.z;
    float Aj[DS], h[DS];
    #pragma unroll
    for (int j = 0; j < DS; j++) { Aj[j] = -fast_exp(A_log[(size_t)d * DS + j]); h[j] = 0.f; }
    float dlsum = 0.f;
    for (int i = 0; i < CH; i++) {
        int t = c * CH + i;
        int p = REV ? (Ss - 1 - t) : t;
        size_t row = (size_t)b * Ss + p;
        float dl = delta[row * DI + d];
        float ut = b2f(ub[row * 2048 + d]);
        float du = dl * ut;
        dlsum += dl;
        const float4* q4 = (const float4*)(xdbl + row * 64 + DTR);
        float4 B0 = q4[0], B1 = q4[1], B2 = q4[2], B3 = q4[3];
        float Bv[DS] = {B0.x, B0.y, B0.z, B0.w, B1.x, B1.y, B1.z, B1.w,
                        B2.x, B2.y, B2.z, B2.w, B3.x, B3.y, B3.z, B3.w};
        #pragma unroll
        for (int j = 0; j < DS; j++) {
            float a = fast_exp(dl * Aj[j]);
            h[j] = fmaf(a, h[j], du * Bv[j]);
        }
    }
    size_t base = ((size_t)(b * NCH + c)) * DS * DI + d;
    #pragma unroll
    for (int j = 0; j < DS; j++) {
        PB[base + (size_t)j * DI] = fast_exp(dlsum * Aj[j]);
        HB[base + (size_t)j * DI] = h[j];
    }
}

// NOTE: HIN may alias PB (each element read before written) -> no __restrict__
__global__ __launch_bounds__(256) void scan_pass2(
    const float* PB, const float* HB, float* HIN) {
    int idx = blockIdx.x * 256 + threadIdx.x;
    int b = idx >> 14;
    int rem = idx & 16383;
    float h = 0.f;
    #pragma unroll
    for (int c = 0; c < NCH; c++) {
        size_t o = ((size_t)(b * NCH + c)) * (DS * DI) + rem;
        float p = PB[o];
        float hl = HB[o];
        HIN[o] = h;
        h = fmaf(p, h, hl);
    }
}

template<bool REV>
__global__ __launch_bounds__(256) void scan_pass3(
    const float* __restrict__ delta,
    const bf16* __restrict__ ub,       // Ub + dir*1024, stride 2048
    const float* __restrict__ xdbl,    // XD, stride 64
    const bf16* __restrict__ zb,       // XZb + dir*2048 + 1024, stride 4096
    const float* __restrict__ A_log, const float* __restrict__ Dp,
    const float* __restrict__ HIN,
    bf16* __restrict__ yb) {           // Yb + dir*1024, stride 2048
    int d = blockIdx.x * 256 + threadIdx.x;
    int c = blockIdx.y;
    int b = blockIdx.z;
    float Aj[DS], h[DS];
    size_t hbase = ((size_t)(b * NCH + c)) * DS * DI + d;
    #pragma unroll
    for (int j = 0; j < DS; j++) {
        Aj[j] = -fast_exp(A_log[(size_t)d * DS + j]);
        h[j] = HIN[hbase + (size_t)j * DI];
    }
    float Dd = Dp[d];
    for (int i = 0; i < CH; i++) {
        int t = c * CH + i;
        int p = REV ? (Ss - 1 - t) : t;
        size_t row = (size_t)b * Ss + p;
        float dl = delta[row * DI + d];
        float ut = b2f(ub[row * 2048 + d]);
        float zz = b2f(zb[row * 4096 + d]);
        float du = dl * ut;
        const float4* q4 = (const float4*)(xdbl + row * 64 + DTR);
        float4 B0 = q4[0], B1 = q4[1], B2 = q4[2], B3 = q4[3];
        float4 C0 = q4[4], C1 = q4[5], C2 = q4[6], C3 = q4[7];
        float Bv[DS] = {B0.x, B0.y, B0.z, B0.w, B1.x, B1.y, B1.z, B1.w,
                        B2.x, B2.y, B2.z, B2.w, B3.x, B3.y, B3.z, B3.w};
        float Cv[DS] = {C0.x, C0.y, C0.z, C0.w, C1.x, C1.y, C1.z, C1.w,
                        C2.x, C2.y, C2.z, C2.w, C3.x, C3.y, C3.z, C3.w};
        float acc = 0.f;
        #pragma unroll
        for (int j = 0; j < DS; j++) {
            float a = fast_exp(dl * Aj[j]);
            h[j] = fmaf(a, h[j], du * Bv[j]);
            acc = fmaf(h[j], Cv[j], acc);
        }
        float sg = fast_sig(zz);
        yb[row * 2048 + d] = __float2bfloat16((acc + ut * Dd) * (zz * sg));
    }
}

// ---------------- final: out[b,h,n] = pred[b,n,h]*sd + mu ----------------
__global__ void finalize_out(const float* __restrict__ pred, const float* __restrict__ mu,
                             const float* __restrict__ sd, float* __restrict__ out) {
    int n = threadIdx.x;
    int h = blockIdx.x;
    int b = blockIdx.y;
    out[((size_t)b * Hh + h) * NV + n] =
        pred[((size_t)b * NV + n) * Hh + h] * sd[b * NV + n] + mu[b * NV + n];
}

extern "C" void kernel_launch(void* const* d_in, const int* in_sizes, int n_in,
                              void* d_out, int out_size, void* d_ws, size_t ws_size,
                              hipStream_t stream) {
    const float* x     = (const float*)d_in[0];
    const float* tokw  = (const float*)d_in[1];
    const float* tokb  = (const float*)d_in[2];
    const float* in_w  = (const float*)d_in[3];
    const float* in_b  = (const float*)d_in[4];
    const float* convw = (const float*)d_in[5];
    const float* convb = (const float*)d_in[6];
    const float* xpw   = (const float*)d_in[7];
    const float* dtw   = (const float*)d_in[8];
    const float* dtb   = (const float*)d_in[9];
    const float* Alog  = (const float*)d_in[10];
    const float* Dm    = (const float*)d_in[11];
    const float* outw  = (const float*)d_in[12];
    const float* outb  = (const float*)d_in[13];
    const float* mnw   = (const float*)d_in[14];
    const float* mnb   = (const float*)d_in[15];
    const float* fnw   = (const float*)d_in[16];
    const float* fnb   = (const float*)d_in[17];
    const float* fw1   = (const float*)d_in[18];
    const float* fb1   = (const float*)d_in[19];
    const float* fw2   = (const float*)d_in[20];
    const float* fb2   = (const float*)d_in[21];
    const float* nw    = (const float*)d_in[22];
    const float* nb    = (const float*)d_in[23];
    const float* hw    = (const float*)d_in[24];
    const float* hb    = (const float*)d_in[25];

    float* ws = (float*)d_ws;
    float* MU   = ws;                              // 8K
    float* SD   = MU + Bb * NV;                    // 8K
    float* R1   = SD + Bb * NV;                    // 2M region: XNTb bf16 / XD fp32
    float* T    = R1 + 2 * 1024 * 1024;            // 4M fp32
    float* YNR  = T + 4 * 1024 * 1024;             // 2M region: YNb bf16
    float* XZR  = YNR + 2 * 1024 * 1024;           // 16M region: XZb bf16 [MROWS,4096]
    float* UBR  = XZR + 16 * 1024 * 1024;          // 8M region: Ub bf16 [MROWS,2048]
    float* DEL  = UBR + 8 * 1024 * 1024;           // 8M fp32 [MROWS,DI] (PRED at end)
    float* PB   = DEL + 8 * 1024 * 1024;           // 4M (also HIN)
    float* HB   = PB + 4 * 1024 * 1024;            // 4M
    float* YBR  = HB + 4 * 1024 * 1024;            // 8M region: Yb bf16 [MROWS,2048]
    float* WBF  = YBR + 8 * 1024 * 1024;

    bf16* XNTb = (bf16*)R1;
    float* XD  = R1;                               // fp32 [MROWS,64], after tokenize
    bf16* YNb  = (bf16*)YNR;
    bf16* XZb  = (bf16*)XZR;
    bf16* Ub   = (bf16*)UBR;
    bf16* Yb   = (bf16*)YBR;
    float* HIN = PB;                               // aliases PB (safe, see scan_pass2)
    float* PRED = DEL;                             // DEL dead after last scan

    bf16* wb = (bf16*)WBF;
    bf16* tokwb  = wb;  wb += (size_t)DM * Ll;
    bf16* inwb   = wb;  wb += (size_t)NLAY * 2 * 2 * DI * DM;
    bf16* xpwb   = wb;  wb += (size_t)NLAY * 2 * 64 * DI;
    bf16* outwc  = wb;  wb += (size_t)NLAY * DM * 2 * DI;
    bf16* fw1b   = wb;  wb += (size_t)NLAY * DFF * DM;
    bf16* fw2b   = wb;  wb += (size_t)NLAY * DM * DFF;
    bf16* hwb    = wb;  wb += (size_t)Hh * DM;
    float* outbsum = (float*)wb;
    float* PS1   = outbsum + NLAY * DM;
    float* PS2   = PS1 + Bb * 8 * NV;

    f2bf<<<(DM * Ll) / 1024, 256, 0, stream>>>(tokw, tokwb, DM * Ll);
    f2bf<<<(NLAY * 2 * 2 * DI * DM) / 1024, 256, 0, stream>>>(in_w, inwb, NLAY * 2 * 2 * DI * DM);
    f2bf<<<(NLAY * 2 * 64 * DI) / 1024, 256, 0, stream>>>(xpw, xpwb, NLAY * 2 * 64 * DI);
    repack_outw<<<(NLAY * DM * 2 * DI) / 1024, 256, 0, stream>>>(outw, outwc);
    sum_outb<<<(NLAY * DM) / 256, 256, 0, stream>>>(outb, outbsum);
    f2bf<<<(NLAY * DFF * DM) / 1024, 256, 0, stream>>>(fw1, fw1b, NLAY * DFF * DM);
    f2bf<<<(NLAY * DM * DFF) / 1024, 256, 0, stream>>>(fw2, fw2b, NLAY * DM * DFF);
    f2bf<<<(Hh * DM) / 1024, 256, 0, stream>>>(hw, hwb, Hh * DM);

    revin_partial<<<dim3(Bb, 8), NV, 0, stream>>>(x, PS1, PS2);
    revin_final<<<Bb, NV, 0, stream>>>(PS1, PS2, MU, SD);
    transpose_norm<<<dim3(Ll / 32, NV / 32, Bb), dim3(32, 8), 0, stream>>>(x, MU, SD, XNTb);
    gemm64<0, false, false, 128><<<dim3(MROWS / 128, DM / 64), 256, 0, stream>>>(
        XNTb, Ll, tokwb, tokb, T, DM, MROWS, DM, Ll);

    for (int l = 0; l < NLAY; l++) {
        ln_rows<<<MROWS, DM, 0, stream>>>(T, mnw + l * DM, mnb + l * DM, YNb);
        // fused bidirectional in_proj: N = 4096, bf16 out
        gemm128<0, false, true><<<dim3(MROWS / 128, 4096 / 128), 256, 0, stream>>>(
            YNb, DM, inwb + (size_t)l * 2 * 2 * DI * DM, in_b + (size_t)l * 2 * 2 * DI,
            XZb, 4096, MROWS, 4096, DM);
        // both-direction conv+silu -> Ub
        conv_both<<<dim3(8, Ss / 16, Bb), 256, 0, stream>>>(
            XZb, convw + (size_t)l * 2 * DI * DCONV, convb + (size_t)l * 2 * DI, Ub);
        for (int dir = 0; dir < 2; dir++) {
            int pd = l * 2 + dir;
            // xp-proj: x_dbl = u_dir @ xpw^T  (fp32 out, [MROWS,64])
            gemm64<0, false, false, 64><<<dim3(MROWS / 64, 1), 256, 0, stream>>>(
                Ub + dir * 1024, 2 * DI, xpwb + (size_t)pd * 64 * DI, nullptr,
                XD, 64, MROWS, 64, DI);
            // dt-proj + softplus (fp32)
            gemm_awt<2, false><<<dim3(MROWS / 64, DI / 64), 256, 0, stream>>>(
                XD, 64, dtw + (size_t)pd * DI * DTR, dtb + (size_t)pd * DI, DEL, DI,
                MROWS, DI, DTR);
            if (dir == 0) {
                scan_pass1<false><<<dim3(DI / 256, NCH, Bb), 256, 0, stream>>>(
                    DEL, Ub, XD, Alog + (size_t)pd * DI * DS, PB, HB);
                scan_pass2<<<(Bb * DS * DI) / 256, 256, 0, stream>>>(PB, HB, HIN);
                scan_pass3<false><<<dim3(DI / 256, NCH, Bb), 256, 0, stream>>>(
                    DEL, Ub, XD, XZb + 1024, Alog + (size_t)pd * DI * DS,
                    Dm + (size_t)pd * DI, HIN, Yb);
            } else {
                scan_pass1<true><<<dim3(DI / 256, NCH, Bb), 256, 0, stream>>>(
                    DEL, Ub + 1024, XD, Alog + (size_t)pd * DI * DS, PB, HB);
                scan_pass2<<<(Bb * DS * DI) / 256, 256, 0, stream>>>(PB, HB, HIN);
                scan_pass3<true><<<dim3(DI / 256, NCH, Bb), 256, 0, stream>>>(
                    DEL, Ub + 1024, XD, XZb + 2048 + 1024, Alog + (size_t)pd * DI * DS,
                    Dm + (size_t)pd * DI, HIN, Yb + 1024);
            }
        }
        // fused bidirectional out_proj: K = 2048, accumulate into T
        gemm64<0, true, false, 128><<<dim3(MROWS / 128, DM / 64), 256, 0, stream>>>(
            Yb, 2 * DI, outwc + (size_t)l * DM * 2 * DI, outbsum + l * DM,
            T, DM, MROWS, DM, 2 * DI);
        // FFN
        ln_rows<<<MROWS, DM, 0, stream>>>(T, fnw + l * DM, fnb + l * DM, YNb);
        gemm128<1, false, true><<<dim3(MROWS / 128, DFF / 128), 256, 0, stream>>>(
            YNb, DM, fw1b + (size_t)l * DFF * DM, fb1 + l * DFF, XZb, DFF, MROWS, DFF, DM);
        gemm64<0, true, false, 128><<<dim3(MROWS / 128, DM / 64), 256, 0, stream>>>(
            XZb, DFF, fw2b + (size_t)l * DM * DFF, fb2 + l * DM, T, DM, MROWS, DM, DFF);
    }
    ln_rows<<<MROWS, DM, 0, stream>>>(T, nw, nb, YNb);
    gemm64<0, false, false, 64><<<dim3(MROWS / 64, 2), 256, 0, stream>>>(
        YNb, DM, hwb, hb, PRED, Hh, MROWS, Hh, DM);
    finalize_out<<<dim3(Hh, Bb), NV, 0, stream>>>(PRED, MU, SD, (float*)d_out);
}

// Round 9
// 931.717 us; speedup vs baseline: 5.2123x; 1.0113x over previous
//
#include <hip/hip_runtime.h>
#include <hip/hip_bf16.h>

#define Bb 16
#define Ll 512
#define NV 512
#define DM 512
#define DS 16
#define NLAY 2
#define DFF 2048
#define DI 1024
#define DCONV 4
#define DTR 32
#define Hh 96
#define Ss NV
#define MROWS (Bb*Ss)
#define EPSf 1e-5f
#define CH 64
#define NCH (Ss/CH)

typedef __hip_bfloat16 bf16;
typedef __attribute__((ext_vector_type(8))) short bf16x8;
typedef __attribute__((ext_vector_type(4))) float f32x4;

#define GLL16(g, l) __builtin_amdgcn_global_load_lds( \
    (const __attribute__((address_space(1))) unsigned int*)(g), \
    (__attribute__((address_space(3))) unsigned int*)(l), 16, 0, 0)

__device__ __forceinline__ float fast_exp(float x) { return __expf(x); }
__device__ __forceinline__ float fast_sig(float x) {
    return __builtin_amdgcn_rcpf(1.f + __expf(-x));
}
__device__ __forceinline__ float fast_softplus(float r) {
    float e = __expf(-fabsf(r));
    return fmaxf(r, 0.f) + __logf(1.f + e);
}
__device__ __forceinline__ float b2f(bf16 v) { return __bfloat162float(v); }

// ---------------- fp32 -> bf16 convert ----------------
__global__ void f2bf(const float* __restrict__ in, bf16* __restrict__ out, int n) {
    int i = (blockIdx.x * 256 + threadIdx.x) * 4;
    if (i < n) {
        float4 v = *(const float4*)(in + i);
        out[i + 0] = __float2bfloat16(v.x);
        out[i + 1] = __float2bfloat16(v.y);
        out[i + 2] = __float2bfloat16(v.z);
        out[i + 3] = __float2bfloat16(v.w);
    }
}

// repack out_w (NL,2,DM,DI) -> outwcat (NL, DM, 2*DI) bf16 with K = [dir0 | dir1]
__global__ void repack_outw(const float* __restrict__ outw, bf16* __restrict__ outwcat) {
    int idx = (blockIdx.x * 256 + threadIdx.x) * 4;
    int k2 = idx & 2047;
    int rest = idx >> 11;           // l*DM + n
    int l = rest >> 9, n = rest & 511;
    int dirk = k2 >> 10, k = k2 & 1023;
    const float* s = outw + (((size_t)(l * 2 + dirk) * DM + n) * DI + k);
    float4 v = *(const float4*)s;
    bf16* dpt = outwcat + (size_t)idx;
    dpt[0] = __float2bfloat16(v.x);
    dpt[1] = __float2bfloat16(v.y);
    dpt[2] = __float2bfloat16(v.z);
    dpt[3] = __float2bfloat16(v.w);
}

__global__ void sum_outb(const float* __restrict__ outb, float* __restrict__ outbsum) {
    int i = blockIdx.x * 256 + threadIdx.x;
    int l = i >> 9, n = i & 511;
    outbsum[i] = outb[(l * 2 + 0) * DM + n] + outb[(l * 2 + 1) * DM + n];
}

// build block-diag xp weight: xpw2[l][n:128][k:2048], n=dir*64+nn, live k in [dir*1024,+1024)
__global__ void build_xpw2(const float* __restrict__ xpw, bf16* __restrict__ out) {
    int idx = blockIdx.x * 256 + threadIdx.x;      // NLAY*128*2048
    int l = idx >> 18;
    int rest = idx & 262143;
    int n = rest >> 11, k = rest & 2047;
    int dir = n >> 6, nn = n & 63;
    float v = ((k >> 10) == dir) ? xpw[((size_t)(l * 2 + dir) * 64 + nn) * DI + (k & 1023)] : 0.f;
    out[idx] = __float2bfloat16(v);
}

// build block-diag dt weight: dtw2[l][n:2048][k:128], n=dir*1024+nn, live k in [dir*64, dir*64+32)
__global__ void build_dtw2(const float* __restrict__ dtw, bf16* __restrict__ out) {
    int idx = blockIdx.x * 256 + threadIdx.x;      // NLAY*2048*128
    int l = idx >> 18;
    int rest = idx & 262143;
    int n = rest >> 7, k = rest & 127;
    int dir = n >> 10, nn = n & 1023;
    int r = k - dir * 64;
    float v = (r >= 0 && r < DTR) ? dtw[((size_t)(l * 2 + dir) * DI + nn) * DTR + r] : 0.f;
    out[idx] = __float2bfloat16(v);
}

// ---------------- RevIN stats (two-stage) ----------------
__global__ void revin_partial(const float* __restrict__ x, float* __restrict__ ps1,
                              float* __restrict__ ps2) {
    int b = blockIdx.x, c = blockIdx.y, n = threadIdx.x;
    const float* xp = x + (size_t)b * Ll * NV + (size_t)c * (Ll / 8) * NV + n;
    float s1 = 0.f, s2 = 0.f;
    #pragma unroll 4
    for (int l = 0; l < Ll / 8; l++) { float v = xp[(size_t)l * NV]; s1 += v; s2 += v * v; }
    ps1[((size_t)b * 8 + c) * NV + n] = s1;
    ps2[((size_t)b * 8 + c) * NV + n] = s2;
}

__global__ void revin_final(const float* __restrict__ ps1, const float* __restrict__ ps2,
                            float* __restrict__ mu, float* __restrict__ sd) {
    int b = blockIdx.x, n = threadIdx.x;
    float s1 = 0.f, s2 = 0.f;
    #pragma unroll
    for (int c = 0; c < 8; c++) {
        s1 += ps1[((size_t)b * 8 + c) * NV + n];
        s2 += ps2[((size_t)b * 8 + c) * NV + n];
    }
    float m = s1 / Ll;
    float var = s2 / Ll - m * m;
    mu[b * NV + n] = m;
    sd[b * NV + n] = sqrtf(var + EPSf);
}

// ------------- normalize + transpose -> bf16: xnT[b,n,l] -------------
__global__ void transpose_norm(const float* __restrict__ x, const float* __restrict__ mu,
                               const float* __restrict__ sd, bf16* __restrict__ xnT) {
    __shared__ float t[32][33];
    int b = blockIdx.z;
    int l0 = blockIdx.x * 32, n0 = blockIdx.y * 32;
    int tx = threadIdx.x, ty = threadIdx.y; // 32x8
    #pragma unroll
    for (int q = 0; q < 4; q++)
        t[ty + q * 8][tx] = x[(size_t)b * Ll * NV + (size_t)(l0 + ty + q * 8) * NV + n0 + tx];
    __syncthreads();
    #pragma unroll
    for (int q = 0; q < 4; q++) {
        int n = n0 + ty + q * 8;
        float m = mu[b * NV + n], s = sd[b * NV + n];
        xnT[(size_t)b * NV * Ll + (size_t)n * Ll + l0 + tx] = __float2bfloat16((t[tx][ty + q * 8] - m) / s);
    }
}

// ---------------- LayerNorm over rows of DM -> bf16 ----------------
__global__ void ln_rows(const float* __restrict__ in, const float* __restrict__ w,
                        const float* __restrict__ bvec, bf16* __restrict__ out) {
    int row = blockIdx.x;
    int tid = threadIdx.x;
    float v = in[(size_t)row * DM + tid];
    float s1 = v, s2 = v * v;
    #pragma unroll
    for (int o = 32; o > 0; o >>= 1) { s1 += __shfl_down(s1, o, 64); s2 += __shfl_down(s2, o, 64); }
    __shared__ float l1[8], l2[8];
    int wv = tid >> 6, ln = tid & 63;
    if (ln == 0) { l1[wv] = s1; l2[wv] = s2; }
    __syncthreads();
    if (tid == 0) {
        float a = 0.f, c = 0.f;
        #pragma unroll
        for (int i = 0; i < DM / 64; i++) { a += l1[i]; c += l2[i]; }
        l1[0] = a; l2[0] = c;
    }
    __syncthreads();
    float mean = l1[0] / DM;
    float var = l2[0] / DM - mean * mean;
    float inv = rsqrtf(var + EPSf);
    out[(size_t)row * DM + tid] = __float2bfloat16((v - mean) * inv * w[tid] + bvec[tid]);
}

// ============ MFMA GEMM, 128x128 tile, BK=32, double-buffered, swizzled ============
template<int EPI, bool ACC, bool OUTBF>
__global__ __launch_bounds__(256) void gemm128(
    const bf16* __restrict__ A, int lda,
    const bf16* __restrict__ W,
    const float* __restrict__ bias,
    void* __restrict__ Cv, int ldc,
    int M, int Nn, int K) {
    __shared__ bf16 As[2][128 * 32];
    __shared__ bf16 Bs[2][128 * 32];
    int m0 = blockIdx.x * 128, n0 = blockIdx.y * 128;
    int tid = threadIdx.x;
    int w = tid >> 6, lane = tid & 63;
    int wm = (w >> 1) * 64, wn = (w & 1) * 64;
    f32x4 acc[4][4] = {};

    int srow = w * 32 + (lane >> 2);
    int sslot = (lane & 3) ^ ((lane >> 3) & 3);
    long arow0 = m0 + srow, arow1 = m0 + srow + 16;
    const char* agp0 = (const char*)(A + arow0 * (long)lda) + sslot * 16;
    const char* agp1 = (const char*)(A + arow1 * (long)lda) + sslot * 16;
    long wr0 = n0 + srow;      if (wr0 >= Nn) wr0 = Nn - 1;
    long wr1 = n0 + srow + 16; if (wr1 >= Nn) wr1 = Nn - 1;
    const char* wgp0 = (const char*)(W + wr0 * (long)K) + sslot * 16;
    const char* wgp1 = (const char*)(W + wr1 * (long)K) + sslot * 16;

    char* a0 = (char*)As[0]; char* a1 = (char*)As[1];
    char* b0 = (char*)Bs[0]; char* b1 = (char*)Bs[1];
    int dA0 = (w * 32) * 64, dA1 = (w * 32 + 16) * 64;

    int lrow = lane & 15;
    int salt = ((lane >> 4) ^ ((lane >> 1) & 3)) * 16;

    const int nk = K >> 5;
#define STG128(pa, pb, ko) do { \
        GLL16(agp0 + (size_t)(ko) * 64, pa + dA0); \
        GLL16(agp1 + (size_t)(ko) * 64, pa + dA1); \
        GLL16(wgp0 + (size_t)(ko) * 64, pb + dA0); \
        GLL16(wgp1 + (size_t)(ko) * 64, pb + dA1); } while (0)

    STG128(a0, b0, 0);
    __syncthreads();
    for (int t = 0; t < nk; ++t) {
        char* ac = (t & 1) ? a1 : a0;
        char* bc = (t & 1) ? b1 : b0;
        if (t + 1 < nk) {
            char* an = (t & 1) ? a0 : a1;
            char* bn = (t & 1) ? b0 : b1;
            STG128(an, bn, t + 1);
        }
        bf16x8 af[4], bfr[4];
        #pragma unroll
        for (int i = 0; i < 4; i++) {
            af[i]  = *(const bf16x8*)(ac + (wm + i * 16 + lrow) * 64 + salt);
            bfr[i] = *(const bf16x8*)(bc + (wn + i * 16 + lrow) * 64 + salt);
        }
        #pragma unroll
        for (int i = 0; i < 4; i++)
            #pragma unroll
            for (int j = 0; j < 4; j++)
                acc[i][j] = __builtin_amdgcn_mfma_f32_16x16x32_bf16(af[i], bfr[j], acc[i][j], 0, 0, 0);
        __syncthreads();
    }
#undef STG128

    #pragma unroll
    for (int i = 0; i < 4; i++) {
        #pragma unroll
        for (int j = 0; j < 4; j++) {
            int n = n0 + wn + j * 16 + (lane & 15);
            if (n >= Nn) continue;
            float bv = bias ? bias[n] : 0.f;
            #pragma unroll
            for (int r = 0; r < 4; r++) {
                long m = m0 + wm + i * 16 + (lane >> 4) * 4 + r;
                float v = acc[i][j][r] + bv;
                if (EPI == 1) {
                    float x3 = v * v * v;
                    v = 0.5f * v * (1.f + tanhf(0.7978845608028654f * (v + 0.044715f * x3)));
                }
                if (OUTBF) {
                    ((bf16*)Cv)[m * (long)ldc + n] = __float2bfloat16(v);
                } else if (ACC) {
                    ((float*)Cv)[m * (long)ldc + n] += v;
                } else {
                    ((float*)Cv)[m * (long)ldc + n] = v;
                }
            }
        }
    }
}

// ============ MFMA GEMM, MTx64 tile (MT=128 or 64), BK=64, dbuf, swizzled ============
template<int EPI, bool ACC, bool OUTBF, int MT>
__global__ __launch_bounds__(256) void gemm64(
    const bf16* __restrict__ A, int lda,
    const bf16* __restrict__ W,
    const float* __restrict__ bias,
    void* __restrict__ Cv, int ldc,
    int M, int Nn, int K) {
    constexpr int WR = MT / 4;
    constexpr int IF = MT / 64;
    constexpr int AG = WR / 8;
    __shared__ bf16 As[2][MT * 64];
    __shared__ bf16 Bs[2][64 * 64];
    int m0 = blockIdx.x * MT, n0 = blockIdx.y * 64;
    int tid = threadIdx.x;
    int w = tid >> 6, lane = tid & 63;
    int wm = w * WR;
    f32x4 acc[IF][4] = {};

    int srow = lane >> 3;
    int sslot = (lane & 7) ^ srow;
    const char* agp[AG];
    #pragma unroll
    for (int g = 0; g < AG; g++) {
        long ar = m0 + w * WR + g * 8 + srow;
        agp[g] = (const char*)(A + ar * (long)lda) + sslot * 16;
    }
    const char* wgp[2];
    #pragma unroll
    for (int g = 0; g < 2; g++) {
        long br = n0 + w * 16 + g * 8 + srow;
        if (br >= Nn) br = Nn - 1;
        wgp[g] = (const char*)(W + br * (long)K) + sslot * 16;
    }
    char* a0 = (char*)As[0]; char* a1 = (char*)As[1];
    char* b0 = (char*)Bs[0]; char* b1 = (char*)Bs[1];

    int lrow = lane & 15;
    int rk = lane & 7, hi = lane >> 4;
    int salt0 = (hi ^ rk) * 16;
    int salt1 = ((4 + hi) ^ rk) * 16;

    const int nk = K >> 6;
#define STG64(pa, pb, ko) do { \
        _Pragma("unroll") \
        for (int g = 0; g < AG; g++) \
            GLL16(agp[g] + (size_t)(ko) * 128, pa + (w * WR + g * 8) * 128); \
        _Pragma("unroll") \
        for (int g = 0; g < 2; g++) \
            GLL16(wgp[g] + (size_t)(ko) * 128, pb + (w * 16 + g * 8) * 128); } while (0)

    STG64(a0, b0, 0);
    __syncthreads();
    for (int t = 0; t < nk; ++t) {
        char* ac = (t & 1) ? a1 : a0;
        char* bc = (t & 1) ? b1 : b0;
        if (t + 1 < nk) {
            char* an = (t & 1) ? a0 : a1;
            char* bn = (t & 1) ? b0 : b1;
            STG64(an, bn, t + 1);
        }
        bf16x8 af[2][IF], bfr[2][4];
        #pragma unroll
        for (int i = 0; i < IF; i++) {
            af[0][i] = *(const bf16x8*)(ac + (wm + i * 16 + lrow) * 128 + salt0);
            af[1][i] = *(const bf16x8*)(ac + (wm + i * 16 + lrow) * 128 + salt1);
        }
        #pragma unroll
        for (int j = 0; j < 4; j++) {
            bfr[0][j] = *(const bf16x8*)(bc + (j * 16 + lrow) * 128 + salt0);
            bfr[1][j] = *(const bf16x8*)(bc + (j * 16 + lrow) * 128 + salt1);
        }
        #pragma unroll
        for (int kk = 0; kk < 2; kk++)
            #pragma unroll
            for (int i = 0; i < IF; i++)
                #pragma unroll
                for (int j = 0; j < 4; j++)
                    acc[i][j] = __builtin_amdgcn_mfma_f32_16x16x32_bf16(af[kk][i], bfr[kk][j], acc[i][j], 0, 0, 0);
        __syncthreads();
    }
#undef STG64

    #pragma unroll
    for (int i = 0; i < IF; i++) {
        #pragma unroll
        for (int j = 0; j < 4; j++) {
            int n = n0 + j * 16 + (lane & 15);
            if (n >= Nn) continue;
            float bv = bias ? bias[n] : 0.f;
            #pragma unroll
            for (int r = 0; r < 4; r++) {
                long m = m0 + wm + i * 16 + (lane >> 4) * 4 + r;
                float v = acc[i][j][r] + bv;
                if (EPI == 1) {
                    float x3 = v * v * v;
                    v = 0.5f * v * (1.f + tanhf(0.7978845608028654f * (v + 0.044715f * x3)));
                } else if (EPI == 2) {
                    v = fast_softplus(v);
                }
                if (OUTBF) {
                    ((bf16*)Cv)[m * (long)ldc + n] = __float2bfloat16(v);
                } else if (ACC) {
                    ((float*)Cv)[m * (long)ldc + n] += v;
                } else {
                    ((float*)Cv)[m * (long)ldc + n] = v;
                }
            }
        }
    }
}

// ---------- causal/anticausal depthwise conv (k=4) + silu, both dirs, bf16 in/out ----------
// XZb: [MROWS, 4096] = [u0|z0|u1|z1]; Ub: [MROWS, 2048] = [u0|u1]
__global__ void conv_both(const bf16* __restrict__ xz, const float* __restrict__ cw_l,
                          const float* __restrict__ cb_l, bf16* __restrict__ ub) {
    int c2 = blockIdx.x * 256 + threadIdx.x;   // 0..2047
    int dir = c2 >> 10, c = c2 & 1023;
    int s0 = blockIdx.y * 16;
    int b = blockIdx.z;
    const bf16* src = xz + (size_t)b * Ss * 4096 + (size_t)dir * 2048 + c;
    const float* cw = cw_l + (dir * DI + c) * 4;
    float w0 = cw[0], w1 = cw[1], w2 = cw[2], w3 = cw[3];
    float bias = cb_l[dir * DI + c];
    bf16* dst = ub + (size_t)b * Ss * 2048 + (size_t)dir * 1024 + c;
    if (dir == 0) {
        float r0 = (s0 - 3 >= 0) ? b2f(src[(size_t)(s0 - 3) * 4096]) : 0.f;
        float r1 = (s0 - 2 >= 0) ? b2f(src[(size_t)(s0 - 2) * 4096]) : 0.f;
        float r2 = (s0 - 1 >= 0) ? b2f(src[(size_t)(s0 - 1) * 4096]) : 0.f;
        for (int i = 0; i < 16; i++) {
            int s = s0 + i;
            float r3 = b2f(src[(size_t)s * 4096]);
            float a = fmaf(r0, w0, fmaf(r1, w1, fmaf(r2, w2, fmaf(r3, w3, bias))));
            dst[(size_t)s * 2048] = __float2bfloat16(a * fast_sig(a));
            r0 = r1; r1 = r2; r2 = r3;
        }
    } else {
        float f0 = b2f(src[(size_t)s0 * 4096]);
        float f1 = (s0 + 1 < Ss) ? b2f(src[(size_t)(s0 + 1) * 4096]) : 0.f;
        float f2 = (s0 + 2 < Ss) ? b2f(src[(size_t)(s0 + 2) * 4096]) : 0.f;
        float f3 = (s0 + 3 < Ss) ? b2f(src[(size_t)(s0 + 3) * 4096]) : 0.f;
        for (int i = 0; i < 16; i++) {
            int s = s0 + i;
            float a = fmaf(f0, w3, fmaf(f1, w2, fmaf(f2, w1, fmaf(f3, w0, bias))));
            dst[(size_t)s * 2048] = __float2bfloat16(a * fast_sig(a));
            f0 = f1; f1 = f2; f2 = f3;
            f3 = (s + 4 < Ss) ? b2f(src[(size_t)(s + 4) * 4096]) : 0.f;
        }
    }
}

// ======== merged-direction chunked parallel selective scan ========
// width 2048: d2 = dir*1024 + d; dir1 runs time-reversed over original storage order.
__global__ __launch_bounds__(256) void scan_pass1(
    const bf16* __restrict__ delb,     // [MROWS, 2048]
    const bf16* __restrict__ ub,       // [MROWS, 2048]
    const float* __restrict__ xd,      // [MROWS, 128] fp32
    const float* __restrict__ Alog_l,  // [2, DI, DS]
    float* __restrict__ PB, float* __restrict__ HB) {
    int d2 = blockIdx.x * 256 + threadIdx.x;
    int dir = d2 >> 10, d = d2 & 1023;
    int c = blockIdx.y;
    int b = blockIdx.z;
    float Aj[DS], h[DS];
    const float* al = Alog_l + ((size_t)dir * DI + d) * DS;
    #pragma unroll
    for (int j = 0; j < DS; j++) { Aj[j] = -fast_exp(al[j]); h[j] = 0.f; }
    float dlsum = 0.f;
    for (int i = 0; i < CH; i++) {
        int t = c * CH + i;
        int p = dir ? (Ss - 1 - t) : t;
        size_t row = (size_t)b * Ss + p;
        float dl = b2f(delb[row * 2048 + d2]);
        float ut = b2f(ub[row * 2048 + d2]);
        float du = dl * ut;
        dlsum += dl;
        const float4* q4 = (const float4*)(xd + row * 128 + dir * 64 + DTR);
        float4 B0 = q4[0], B1 = q4[1], B2 = q4[2], B3 = q4[3];
        float Bv[DS] = {B0.x, B0.y, B0.z, B0.w, B1.x, B1.y, B1.z, B1.w,
                        B2.x, B2.y, B2.z, B2.w, B3.x, B3.y, B3.z, B3.w};
        #pragma unroll
        for (int j = 0; j < DS; j++) {
            float a = fast_exp(dl * Aj[j]);
            h[j] = fmaf(a, h[j], du * Bv[j]);
        }
    }
    size_t base = ((size_t)(b * NCH + c) * DS) * 2048 + d2;
    #pragma unroll
    for (int j = 0; j < DS; j++) {
        PB[base + (size_t)j * 2048] = fast_exp(dlsum * Aj[j]);
        HB[base + (size_t)j * 2048] = h[j];
    }
}

// NOTE: HIN may alias PB (each element read before written) -> no __restrict__
__global__ __launch_bounds__(256) void scan_pass2(
    const float* PB, const float* HB, float* HIN) {
    int idx = blockIdx.x * 256 + threadIdx.x;   // Bb * DS*2048
    int b = idx >> 15;                          // DS*2048 = 32768
    int rem = idx & 32767;
    float h = 0.f;
    #pragma unroll
    for (int c = 0; c < NCH; c++) {
        size_t o = ((size_t)(b * NCH + c)) * 32768 + rem;
        float p = PB[o];
        float hl = HB[o];
        HIN[o] = h;
        h = fmaf(p, h, hl);
    }
}

__global__ __launch_bounds__(256) void scan_pass3(
    const bf16* __restrict__ delb,
    const bf16* __restrict__ ub,
    const float* __restrict__ xd,
    const bf16* __restrict__ xzb,      // [MROWS, 4096], z at dir*2048+1024+d
    const float* __restrict__ Alog_l, const float* __restrict__ Dm_l,
    const float* __restrict__ HIN,
    bf16* __restrict__ yb) {           // [MROWS, 2048]
    int d2 = blockIdx.x * 256 + threadIdx.x;
    int dir = d2 >> 10, d = d2 & 1023;
    int c = blockIdx.y;
    int b = blockIdx.z;
    float Aj[DS], h[DS];
    const float* al = Alog_l + ((size_t)dir * DI + d) * DS;
    size_t hbase = ((size_t)(b * NCH + c) * DS) * 2048 + d2;
    #pragma unroll
    for (int j = 0; j < DS; j++) {
        Aj[j] = -fast_exp(al[j]);
        h[j] = HIN[hbase + (size_t)j * 2048];
    }
    float Dd = Dm_l[dir * DI + d];
    for (int i = 0; i < CH; i++) {
        int t = c * CH + i;
        int p = dir ? (Ss - 1 - t) : t;
        size_t row = (size_t)b * Ss + p;
        float dl = b2f(delb[row * 2048 + d2]);
        float ut = b2f(ub[row * 2048 + d2]);
        float zz = b2f(xzb[row * 4096 + dir * 2048 + 1024 + d]);
        float du = dl * ut;
        const float4* q4 = (const float4*)(xd + row * 128 + dir * 64 + DTR);
        float4 B0 = q4[0], B1 = q4[1], B2 = q4[2], B3 = q4[3];
        float4 C0 = q4[4], C1 = q4[5], C2 = q4[6], C3 = q4[7];
        float Bv[DS] = {B0.x, B0.y, B0.z, B0.w, B1.x, B1.y, B1.z, B1.w,
                        B2.x, B2.y, B2.z, B2.w, B3.x, B3.y, B3.z, B3.w};
        float Cv[DS] = {C0.x, C0.y, C0.z, C0.w, C1.x, C1.y, C1.z, C1.w,
                        C2.x, C2.y, C2.z, C2.w, C3.x, C3.y, C3.z, C3.w};
        float acc = 0.f;
        #pragma unroll
        for (int j = 0; j < DS; j++) {
            float a = fast_exp(dl * Aj[j]);
            h[j] = fmaf(a, h[j], du * Bv[j]);
            acc = fmaf(h[j], Cv[j], acc);
        }
        float sg = fast_sig(zz);
        yb[row * 2048 + d2] = __float2bfloat16((acc + ut * Dd) * (zz * sg));
    }
}

// ---------------- final: out[b,h,n] = pred[b,n,h]*sd + mu ----------------
__global__ void finalize_out(const float* __restrict__ pred, const float* __restrict__ mu,
                             const float* __restrict__ sd, float* __restrict__ out) {
    int n = threadIdx.x;
    int h = blockIdx.x;
    int b = blockIdx.y;
    out[((size_t)b * Hh + h) * NV + n] =
        pred[((size_t)b * NV + n) * Hh + h] * sd[b * NV + n] + mu[b * NV + n];
}

extern "C" void kernel_launch(void* const* d_in, const int* in_sizes, int n_in,
                              void* d_out, int out_size, void* d_ws, size_t ws_size,
                              hipStream_t stream) {
    const float* x     = (const float*)d_in[0];
    const float* tokw  = (const float*)d_in[1];
    const float* tokb  = (const float*)d_in[2];
    const float* in_w  = (const float*)d_in[3];
    const float* in_b  = (const float*)d_in[4];
    const float* convw = (const float*)d_in[5];
    const float* convb = (const float*)d_in[6];
    const float* xpw   = (const float*)d_in[7];
    const float* dtw   = (const float*)d_in[8];
    const float* dtb   = (const float*)d_in[9];
    const float* Alog  = (const float*)d_in[10];
    const float* Dm    = (const float*)d_in[11];
    const float* outw  = (const float*)d_in[12];
    const float* outb  = (const float*)d_in[13];
    const float* mnw   = (const float*)d_in[14];
    const float* mnb   = (const float*)d_in[15];
    const float* fnw   = (const float*)d_in[16];
    const float* fnb   = (const float*)d_in[17];
    const float* fw1   = (const float*)d_in[18];
    const float* fb1   = (const float*)d_in[19];
    const float* fw2   = (const float*)d_in[20];
    const float* fb2   = (const float*)d_in[21];
    const float* nw    = (const float*)d_in[22];
    const float* nb    = (const float*)d_in[23];
    const float* hw    = (const float*)d_in[24];
    const float* hb    = (const float*)d_in[25];

    float* ws = (float*)d_ws;
    float* MU   = ws;
    float* SD   = MU + Bb * NV;
    float* R1   = SD + Bb * NV;                    // 2M floats: XNTb bf16 / XD fp32 + XDb bf16
    float* T    = R1 + 2 * 1024 * 1024;            // 4M fp32
    float* YNR  = T + 4 * 1024 * 1024;             // 2M: YNb bf16
    float* XZR  = YNR + 2 * 1024 * 1024;           // 16M: XZb bf16 [MROWS,4096]
    float* UBR  = XZR + 16 * 1024 * 1024;          // 8M: Ub bf16 [MROWS,2048]
    float* DELR = UBR + 8 * 1024 * 1024;           // 8M: DELb bf16 [MROWS,2048]; PRED fp32 at end
    float* PB   = DELR + 8 * 1024 * 1024;          // 4M fp32 (also HIN)
    float* HB   = PB + 4 * 1024 * 1024;            // 4M fp32
    float* YBR  = HB + 4 * 1024 * 1024;            // 8M: Yb bf16 [MROWS,2048]
    float* WBF  = YBR + 8 * 1024 * 1024;

    bf16* XNTb = (bf16*)R1;
    float* XD  = R1;                               // [MROWS,128] fp32 (1M floats)
    bf16* XDb  = (bf16*)(R1 + 1024 * 1024);        // [MROWS,128] bf16
    bf16* YNb  = (bf16*)YNR;
    bf16* XZb  = (bf16*)XZR;
    bf16* Ub   = (bf16*)UBR;
    bf16* DELb = (bf16*)DELR;
    bf16* Yb   = (bf16*)YBR;
    float* HIN = PB;
    float* PRED = DELR;                            // DELb dead after last scan

    bf16* wb = (bf16*)WBF;
    bf16* tokwb  = wb;  wb += (size_t)DM * Ll;
    bf16* inwb   = wb;  wb += (size_t)NLAY * 2 * 2 * DI * DM;
    bf16* xpw2b  = wb;  wb += (size_t)NLAY * 128 * 2048;
    bf16* dtw2b  = wb;  wb += (size_t)NLAY * 2048 * 128;
    bf16* outwc  = wb;  wb += (size_t)NLAY * DM * 2 * DI;
    bf16* fw1b   = wb;  wb += (size_t)NLAY * DFF * DM;
    bf16* fw2b   = wb;  wb += (size_t)NLAY * DM * DFF;
    bf16* hwb    = wb;  wb += (size_t)Hh * DM;
    float* outbsum = (float*)wb;
    float* PS1   = outbsum + NLAY * DM;
    float* PS2   = PS1 + Bb * 8 * NV;

    f2bf<<<(DM * Ll) / 1024, 256, 0, stream>>>(tokw, tokwb, DM * Ll);
    f2bf<<<(NLAY * 2 * 2 * DI * DM) / 1024, 256, 0, stream>>>(in_w, inwb, NLAY * 2 * 2 * DI * DM);
    build_xpw2<<<(NLAY * 128 * 2048) / 256, 256, 0, stream>>>(xpw, xpw2b);
    build_dtw2<<<(NLAY * 2048 * 128) / 256, 256, 0, stream>>>(dtw, dtw2b);
    repack_outw<<<(NLAY * DM * 2 * DI) / 1024, 256, 0, stream>>>(outw, outwc);
    sum_outb<<<(NLAY * DM) / 256, 256, 0, stream>>>(outb, outbsum);
    f2bf<<<(NLAY * DFF * DM) / 1024, 256, 0, stream>>>(fw1, fw1b, NLAY * DFF * DM);
    f2bf<<<(NLAY * DM * DFF) / 1024, 256, 0, stream>>>(fw2, fw2b, NLAY * DM * DFF);
    f2bf<<<(Hh * DM) / 1024, 256, 0, stream>>>(hw, hwb, Hh * DM);

    revin_partial<<<dim3(Bb, 8), NV, 0, stream>>>(x, PS1, PS2);
    revin_final<<<Bb, NV, 0, stream>>>(PS1, PS2, MU, SD);
    transpose_norm<<<dim3(Ll / 32, NV / 32, Bb), dim3(32, 8), 0, stream>>>(x, MU, SD, XNTb);
    gemm64<0, false, false, 128><<<dim3(MROWS / 128, DM / 64), 256, 0, stream>>>(
        XNTb, Ll, tokwb, tokb, T, DM, MROWS, DM, Ll);

    for (int l = 0; l < NLAY; l++) {
        ln_rows<<<MROWS, DM, 0, stream>>>(T, mnw + l * DM, mnb + l * DM, YNb);
        // fused bidirectional in_proj: N = 4096, bf16 out
        gemm128<0, false, true><<<dim3(MROWS / 128, 4096 / 128), 256, 0, stream>>>(
            YNb, DM, inwb + (size_t)l * 2 * 2 * DI * DM, in_b + (size_t)l * 2 * 2 * DI,
            XZb, 4096, MROWS, 4096, DM);
        // both-direction conv+silu -> Ub
        conv_both<<<dim3(8, Ss / 16, Bb), 256, 0, stream>>>(
            XZb, convw + (size_t)l * 2 * DI * DCONV, convb + (size_t)l * 2 * DI, Ub);
        // merged xp-proj (both dirs): XD[MROWS,128] fp32
        gemm64<0, false, false, 64><<<dim3(MROWS / 64, 2), 256, 0, stream>>>(
            Ub, 2048, xpw2b + (size_t)l * 128 * 2048, nullptr, XD, 128, MROWS, 128, 2048);
        f2bf<<<(MROWS * 128) / 1024, 256, 0, stream>>>(XD, XDb, MROWS * 128);
        // merged dt-proj (both dirs) + softplus: DELb[MROWS,2048] bf16
        gemm64<2, false, true, 128><<<dim3(MROWS / 128, 2048 / 64), 256, 0, stream>>>(
            XDb, 128, dtw2b + (size_t)l * 2048 * 128, dtb + (size_t)l * 2 * DI,
            DELb, 2048, MROWS, 2048, 128);
        // merged-direction scans
        scan_pass1<<<dim3(2048 / 256, NCH, Bb), 256, 0, stream>>>(
            DELb, Ub, XD, Alog + (size_t)l * 2 * DI * DS, PB, HB);
        scan_pass2<<<(Bb * DS * 2048) / 256, 256, 0, stream>>>(PB, HB, HIN);
        scan_pass3<<<dim3(2048 / 256, NCH, Bb), 256, 0, stream>>>(
            DELb, Ub, XD, XZb, Alog + (size_t)l * 2 * DI * DS, Dm + (size_t)l * 2 * DI,
            HIN, Yb);
        // fused bidirectional out_proj: K = 2048, accumulate into T
        gemm64<0, true, false, 128><<<dim3(MROWS / 128, DM / 64), 256, 0, stream>>>(
            Yb, 2 * DI, outwc + (size_t)l * DM * 2 * DI, outbsum + l * DM,
            T, DM, MROWS, DM, 2 * DI);
        // FFN
        ln_rows<<<MROWS, DM, 0, stream>>>(T, fnw + l * DM, fnb + l * DM, YNb);
        gemm128<1, false, true><<<dim3(MROWS / 128, DFF / 128), 256, 0, stream>>>(
            YNb, DM, fw1b + (size_t)l * DFF * DM, fb1 + l * DFF, XZb, DFF, MROWS, DFF, DM);
        gemm64<0, true, false, 128><<<dim3(MROWS / 128, DM / 64), 256, 0, stream>>>(
            XZb, DFF, fw2b + (size_t)l * DM * DFF, fb2 + l * DM, T, DM, MROWS, DM, DFF);
    }
    ln_rows<<<MROWS, DM, 0, stream>>>(T, nw, nb, YNb);
    gemm64<0, false, false, 64><<<dim3(MROWS / 64, 2), 256, 0, stream>>>(
        YNb, DM, hwb, hb, PRED, Hh, MROWS, Hh, DM);
    finalize_out<<<dim3(Hh, Bb), NV, 0, stream>>>(PRED, MU, SD, (float*)d_out);
}